// Round 4
// baseline (12939.323 us; speedup 1.0000x reference)
//
#include <hip/hip_runtime.h>
#include <hip/hip_bf16.h>
#include <cstdint>
#include <cstddef>

// ---- Model constants ----
#define Dm   768
#define NHm  12
#define Lm   4
#define Em   8
#define Vm   50257
#define Hm   3072
#define Tm   512
#define Bm   2
#define NT   (Bm*Tm)      // 1024 tokens

__device__ __forceinline__ float gelu_exact(float x) {
    return 0.5f * x * (1.0f + erff(x * 0.70710678118654752440f));
}

// ---------------- Embedding + sinusoidal PE ----------------
__global__ __launch_bounds__(256) void embed_kernel(const int* __restrict__ x,
                                                    const float* __restrict__ emb,
                                                    float* __restrict__ h) {
    int g = blockIdx.x;            // token 0..1023
    int tid = threadIdx.x;
    int tok = x[g];
    int pos = g % Tm;
    const float* erow = emb + (size_t)tok * Dm;
    for (int d = tid; d < Dm; d += 256) {
        int i2 = (d >> 1) * 2;     // "2i" term
        float div = expf(-logf(10000.0f) * (float)i2 / (float)Dm);
        float a = (float)pos * div;
        float pe = (d & 1) ? cosf(a) : sinf(a);
        h[(size_t)g * Dm + d] = erow[d] + pe;
    }
}

// ---------------- LayerNorm (768 = 256*3), LDS tree reduction ----------------
__global__ __launch_bounds__(256) void ln_kernel(const float* __restrict__ in,
                                                 const float* __restrict__ g,
                                                 const float* __restrict__ b,
                                                 float* __restrict__ out) {
    int t = blockIdx.x, tid = threadIdx.x;
    const float* x = in + (size_t)t * Dm;
    float v0 = x[tid], v1 = x[tid + 256], v2 = x[tid + 512];
    __shared__ float red[256];
    red[tid] = v0 + v1 + v2;
    __syncthreads();
    for (int off = 128; off > 0; off >>= 1) {
        if (tid < off) red[tid] += red[tid + off];
        __syncthreads();
    }
    float mean = red[0] * (1.0f / Dm);
    __syncthreads();                       // everyone has read red[0]
    float d0 = v0 - mean, d1 = v1 - mean, d2 = v2 - mean;
    red[tid] = d0 * d0 + d1 * d1 + d2 * d2;
    __syncthreads();
    for (int off = 128; off > 0; off >>= 1) {
        if (tid < off) red[tid] += red[tid + off];
        __syncthreads();
    }
    float inv = rsqrtf(red[0] * (1.0f / Dm) + 1e-5f);
    float* o = out + (size_t)t * Dm;
    o[tid]       = d0 * inv * g[tid]       + b[tid];
    o[tid + 256] = d1 * inv * g[tid + 256] + b[tid + 256];
    o[tid + 512] = d2 * inv * g[tid + 512] + b[tid + 512];
}

// ---------------- Generic GEMM: C[M,N] = act(A[M,K] * B[N,K]^T + bias + res) ----------------
// All fp32. ACT: 0 none, 1 gelu. RES: add residual (may alias Cout elementwise).
#define BMt 64
#define BNt 64
#define BKt 16
template<int ACT, int RES>
__global__ __launch_bounds__(256) void gemm_bt(const float* __restrict__ A,
                                               const float* __restrict__ B,
                                               const float* __restrict__ bias,
                                               const float* __restrict__ res,
                                               float* __restrict__ Cout,
                                               int M, int N, int K) {
    __shared__ float As[BKt][BMt];
    __shared__ float Bs[BKt][BNt];
    int tid = threadIdx.x;
    int bm = blockIdx.y * BMt;
    int bn = blockIdx.x * BNt;
    int tx = tid & 15, ty = tid >> 4;
    float acc[4][4] = {};
    int lrow = tid >> 2;          // 0..63
    int lk4  = (tid & 3) * 4;     // 0,4,8,12

    for (int kk = 0; kk < K; kk += BKt) {
        #pragma unroll
        for (int q = 0; q < 4; ++q)
            As[lk4 + q][lrow] = A[(size_t)(bm + lrow) * K + kk + lk4 + q];
        #pragma unroll
        for (int q = 0; q < 4; ++q) {
            float v = 0.f;
            if (bn + lrow < N)
                v = B[(size_t)(bn + lrow) * K + kk + lk4 + q];
            Bs[lk4 + q][lrow] = v;
        }
        __syncthreads();
        #pragma unroll
        for (int k = 0; k < BKt; ++k) {
            float a[4], bb[4];
            #pragma unroll
            for (int i = 0; i < 4; ++i) a[i] = As[k][ty * 4 + i];
            #pragma unroll
            for (int j = 0; j < 4; ++j) bb[j] = Bs[k][tx * 4 + j];
            #pragma unroll
            for (int i = 0; i < 4; ++i)
                #pragma unroll
                for (int j = 0; j < 4; ++j)
                    acc[i][j] += a[i] * bb[j];
        }
        __syncthreads();
    }

    #pragma unroll
    for (int i = 0; i < 4; ++i) {
        int m = bm + ty * 4 + i;
        #pragma unroll
        for (int j = 0; j < 4; ++j) {
            int n = bn + tx * 4 + j;
            if (n < N) {
                float v = acc[i][j];
                if (bias) v += bias[n];
                if (RES)  v += res[(size_t)m * N + n];
                if (ACT == 1) v = gelu_exact(v);
                Cout[(size_t)m * N + n] = v;
            }
        }
    }
}

// ---------------- Causal attention, one block per (b, head, q-row) ----------------
// qkv fp32 [NT][2304]: q at +0, k at +768, v at +1536, per-head offset h*64.
__global__ __launch_bounds__(256) void attn_kernel(const float* __restrict__ qkv,
                                                   float* __restrict__ o) {
    int idx = blockIdx.x;
    int tq = idx % Tm; idx /= Tm;
    int hh = idx % NHm;
    int b  = idx / NHm;
    int tid = threadIdx.x;
    const int g0 = b * Tm;
    __shared__ float qs[64];
    __shared__ float s[Tm];
    __shared__ float red[256];
    __shared__ float part[4][64];

    const float* qrow = qkv + (size_t)(g0 + tq) * (3 * Dm) + hh * 64;
    if (tid < 64) qs[tid] = qrow[tid];
    __syncthreads();

    int nk = tq + 1;
    float lmax = -1e30f;
    for (int k = tid; k < nk; k += 256) {
        const float* krow = qkv + (size_t)(g0 + k) * (3 * Dm) + Dm + hh * 64;
        float dot = 0.f;
        for (int d = 0; d < 64; ++d) dot += qs[d] * krow[d];
        dot *= 0.125f;   // 1/sqrt(64)
        s[k] = dot;
        lmax = fmaxf(lmax, dot);
    }
    red[tid] = lmax;
    __syncthreads();
    for (int off = 128; off > 0; off >>= 1) {
        if (tid < off) red[tid] = fmaxf(red[tid], red[tid + off]);
        __syncthreads();
    }
    float mx = red[0];

    float lsum = 0.f;
    for (int k = tid; k < nk; k += 256) {
        float e = expf(s[k] - mx);
        s[k] = e;
        lsum += e;
    }
    __syncthreads();               // mx reads done; s writes done
    red[tid] = lsum;
    __syncthreads();
    for (int off = 128; off > 0; off >>= 1) {
        if (tid < off) red[tid] += red[tid + off];
        __syncthreads();
    }
    float inv = 1.0f / red[0];

    int grp = tid >> 6;            // 0..3
    int d = tid & 63;
    float acc = 0.f;
    for (int k = grp; k < nk; k += 4) {
        acc += s[k] * qkv[(size_t)(g0 + k) * (3 * Dm) + 2 * Dm + hh * 64 + d];
    }
    part[grp][d] = acc;
    __syncthreads();
    if (tid < 64) {
        float r = (part[0][tid] + part[1][tid] + part[2][tid] + part[3][tid]) * inv;
        o[(size_t)(g0 + tq) * Dm + hh * 64 + tid] = r;
    }
}

// ---------------- MoE router: top-2 of softmax over 8 experts ----------------
__global__ __launch_bounds__(256) void router_kernel(const float* __restrict__ xn,
                                                     const float* __restrict__ gw,
                                                     int* __restrict__ topi,
                                                     float* __restrict__ topw) {
    int t = blockIdx.x * 256 + threadIdx.x;
    if (t >= NT) return;
    const float* x = xn + (size_t)t * Dm;
    float l[Em];
    #pragma unroll
    for (int e = 0; e < Em; ++e) {
        const float* w = gw + (size_t)e * Dm;
        float dot = 0.f;
        for (int d = 0; d < Dm; ++d) dot += w[d] * x[d];
        l[e] = dot;
    }
    int i1 = 0;
    #pragma unroll
    for (int e = 1; e < Em; ++e) if (l[e] > l[i1]) i1 = e;
    int i2 = (i1 == 0) ? 1 : 0;
    #pragma unroll
    for (int e = 0; e < Em; ++e) if (e != i1 && l[e] > l[i2]) i2 = e;
    // renormalized top-2 gates == 2-way softmax over the two logits
    float w1 = 1.0f / (1.0f + expf(l[i2] - l[i1]));
    topi[t * 2] = i1; topi[t * 2 + 1] = i2;
    topw[t * 2] = w1; topw[t * 2 + 1] = 1.0f - w1;
}

// ---------------- Expert FFN: one block per (token, slot) ----------------
__global__ __launch_bounds__(256) void expert_kernel(const float* __restrict__ xn,
                                                     const float* __restrict__ mw1,
                                                     const float* __restrict__ mb1,
                                                     const float* __restrict__ mw2,
                                                     const float* __restrict__ mb2,
                                                     const int* __restrict__ topi,
                                                     const float* __restrict__ topw,
                                                     float* __restrict__ ye) {
    int ts = blockIdx.x;
    int t = ts >> 1, slot = ts & 1;
    int e = topi[t * 2 + slot];
    float w = topw[t * 2 + slot];
    int tid = threadIdx.x;
    __shared__ float xs[Dm];
    __shared__ float hid[Hm];
    for (int d = tid; d < Dm; d += 256) xs[d] = xn[(size_t)t * Dm + d];
    __syncthreads();

    const float* W1 = mw1 + (size_t)e * Hm * Dm;
    const float* B1 = mb1 + (size_t)e * Hm;
    for (int j = tid; j < Hm; j += 256) {
        const float* row = W1 + (size_t)j * Dm;
        float dot = 0.f;
        for (int d = 0; d < Dm; ++d) dot += row[d] * xs[d];
        hid[j] = gelu_exact(dot + B1[j]);
    }
    __syncthreads();

    const float* W2 = mw2 + (size_t)e * Dm * Hm;
    const float* B2 = mb2 + (size_t)e * Dm;
    for (int d = tid; d < Dm; d += 256) {
        const float* row = W2 + (size_t)d * Hm;
        float dot = 0.f;
        for (int j = 0; j < Hm; ++j) dot += row[j] * hid[j];
        ye[((size_t)t * 2 + slot) * Dm + d] = w * (dot + B2[d]);
    }
}

__global__ __launch_bounds__(256) void combine_kernel(float* __restrict__ h,
                                                      const float* __restrict__ ye) {
    int i = blockIdx.x * 256 + threadIdx.x;
    if (i < NT * Dm) {
        int t = i / Dm, d = i - t * Dm;
        h[i] += ye[(size_t)(t * 2) * Dm + d] + ye[(size_t)(t * 2 + 1) * Dm + d];
    }
}

// ---------------- Launch ----------------
extern "C" void kernel_launch(void* const* d_in, const int* in_sizes, int n_in,
                              void* d_out, int out_size, void* d_ws, size_t ws_size,
                              hipStream_t stream) {
    const int*   x    = (const int*)d_in[0];
    const float* emb  = (const float*)d_in[1];
    const float* wqkv = (const float*)d_in[2];
    const float* bqkv = (const float*)d_in[3];
    const float* wo   = (const float*)d_in[4];
    const float* bo   = (const float*)d_in[5];
    const float* ln1g = (const float*)d_in[6];
    const float* ln1b = (const float*)d_in[7];
    const float* ln2g = (const float*)d_in[8];
    const float* ln2b = (const float*)d_in[9];
    const float* sw1  = (const float*)d_in[10];
    const float* sb1  = (const float*)d_in[11];
    const float* sw2  = (const float*)d_in[12];
    const float* sb2  = (const float*)d_in[13];
    const float* gw   = (const float*)d_in[14];
    const float* mw1  = (const float*)d_in[15];
    const float* mb1  = (const float*)d_in[16];
    const float* mw2  = (const float*)d_in[17];
    const float* mb2  = (const float*)d_in[18];
    const float* lnfg = (const float*)d_in[19];
    const float* lnfb = (const float*)d_in[20];

    // Buffer sizes (floats)
    const size_t n_h   = (size_t)NT * Dm;
    const size_t n_qkv = (size_t)NT * 3 * Dm;
    const size_t n_ffh = (size_t)NT * Hm;
    const size_t n_ye  = (size_t)NT * 2 * Dm;
    const size_t n_xn  = (size_t)NT * Dm;
    const size_t n_small = n_xn + NT * 2 /*topw*/ + NT * 2 /*topi as float slots*/;
    const size_t n_total = n_h + n_qkv + n_h /*attno*/ + n_ffh + n_ye + n_small;

    float *h, *qkv, *attno, *ffh, *ye, *xn, *topw;
    int *topi;
    if (ws_size >= n_total * sizeof(float)) {
        // Everything in d_ws; d_out only written by the final GEMM.
        float* w = (float*)d_ws;
        h = w;              w += n_h;
        qkv = w;            w += n_qkv;
        attno = w;          w += n_h;
        ffh = w;            w += n_ffh;
        ye = w;             w += n_ye;
        xn = w;             w += n_xn;
        topw = w;           w += NT * 2;
        topi = (int*)w;
    } else {
        // Big intermediates in the front of d_out (fp32, 205.8 MB total);
        // final logits GEMM overwrites all of d_out, reading only xn (d_ws)
        // and emb (input).
        float* a = (float*)d_out;
        h = a;              a += n_h;
        qkv = a;            a += n_qkv;
        attno = a;          a += n_h;
        ffh = a;            a += n_ffh;
        ye = a;
        float* w = (float*)d_ws;
        xn = w;             w += n_xn;
        topw = w;           w += NT * 2;
        topi = (int*)w;
    }

    embed_kernel<<<NT, 256, 0, stream>>>(x, emb, h);

    int std_i = 0, moe_i = 0;
    for (int l = 0; l < Lm; ++l) {
        ln_kernel<<<NT, 256, 0, stream>>>(h, ln1g + l * Dm, ln1b + l * Dm, xn);
        gemm_bt<0,0><<<dim3((3 * Dm) / BNt, NT / BMt), 256, 0, stream>>>(
            xn, wqkv + (size_t)l * 3 * Dm * Dm, bqkv + (size_t)l * 3 * Dm,
            nullptr, qkv, NT, 3 * Dm, Dm);
        attn_kernel<<<Bm * NHm * Tm, 256, 0, stream>>>(qkv, attno);
        gemm_bt<0,1><<<dim3(Dm / BNt, NT / BMt), 256, 0, stream>>>(
            attno, wo + (size_t)l * Dm * Dm, bo + (size_t)l * Dm, h, h, NT, Dm, Dm);

        ln_kernel<<<NT, 256, 0, stream>>>(h, ln2g + l * Dm, ln2b + l * Dm, xn);
        if (l == 1 || l == 3) {
            router_kernel<<<(NT + 255) / 256, 256, 0, stream>>>(
                xn, gw + (size_t)moe_i * Em * Dm, topi, topw);
            expert_kernel<<<NT * 2, 256, 0, stream>>>(
                xn,
                mw1 + (size_t)moe_i * Em * Hm * Dm, mb1 + (size_t)moe_i * Em * Hm,
                mw2 + (size_t)moe_i * Em * Dm * Hm, mb2 + (size_t)moe_i * Em * Dm,
                topi, topw, ye);
            combine_kernel<<<(NT * Dm) / 256, 256, 0, stream>>>(h, ye);
            moe_i++;
        } else {
            gemm_bt<1,0><<<dim3(Hm / BNt, NT / BMt), 256, 0, stream>>>(
                xn, sw1 + (size_t)std_i * Hm * Dm, sb1 + (size_t)std_i * Hm,
                nullptr, ffh, NT, Hm, Dm);
            gemm_bt<0,1><<<dim3(Dm / BNt, NT / BMt), 256, 0, stream>>>(
                ffh, sw2 + (size_t)std_i * Dm * Hm, sb2 + (size_t)std_i * Dm,
                h, h, NT, Dm, Hm);
            std_i++;
        }
    }

    ln_kernel<<<NT, 256, 0, stream>>>(h, lnfg, lnfb, xn);
    // Final logits GEMM (fp32 out): reads xn + emb, writes ALL of d_out.
    gemm_bt<0,0><<<dim3((Vm + BNt - 1) / BNt, NT / BMt), 256, 0, stream>>>(
        xn, emb, nullptr, nullptr, (float*)d_out, NT, Vm, Dm);
}

// Round 5
// 4752.346 us; speedup vs baseline: 2.7227x; 2.7227x over previous
//
#include <hip/hip_runtime.h>
#include <hip/hip_bf16.h>
#include <cstdint>
#include <cstddef>

// ---- Model constants ----
#define Dm   768
#define NHm  12
#define Lm   4
#define Em   8
#define Vm   50257
#define Hm   3072
#define Tm   512
#define Bm   2
#define NT   (Bm*Tm)      // 1024 tokens
#define NAS  (NT*2)       // 2048 expert assignments

__device__ __forceinline__ float gelu_exact(float x) {
    return 0.5f * x * (1.0f + erff(x * 0.70710678118654752440f));
}

// ---------------- Embedding + sinusoidal PE ----------------
__global__ __launch_bounds__(256) void embed_kernel(const int* __restrict__ x,
                                                    const float* __restrict__ emb,
                                                    float* __restrict__ h) {
    int g = blockIdx.x;            // token 0..1023
    int tid = threadIdx.x;
    int tok = x[g];
    int pos = g % Tm;
    const float* erow = emb + (size_t)tok * Dm;
    for (int d = tid; d < Dm; d += 256) {
        int i2 = (d >> 1) * 2;     // "2i" term
        float div = expf(-logf(10000.0f) * (float)i2 / (float)Dm);
        float a = (float)pos * div;
        float pe = (d & 1) ? cosf(a) : sinf(a);
        h[(size_t)g * Dm + d] = erow[d] + pe;
    }
}

// ---------------- LayerNorm (768 = 256*3), LDS tree reduction ----------------
__global__ __launch_bounds__(256) void ln_kernel(const float* __restrict__ in,
                                                 const float* __restrict__ g,
                                                 const float* __restrict__ b,
                                                 float* __restrict__ out) {
    int t = blockIdx.x, tid = threadIdx.x;
    const float* x = in + (size_t)t * Dm;
    float v0 = x[tid], v1 = x[tid + 256], v2 = x[tid + 512];
    __shared__ float red[256];
    red[tid] = v0 + v1 + v2;
    __syncthreads();
    for (int off = 128; off > 0; off >>= 1) {
        if (tid < off) red[tid] += red[tid + off];
        __syncthreads();
    }
    float mean = red[0] * (1.0f / Dm);
    __syncthreads();
    float d0 = v0 - mean, d1 = v1 - mean, d2 = v2 - mean;
    red[tid] = d0 * d0 + d1 * d1 + d2 * d2;
    __syncthreads();
    for (int off = 128; off > 0; off >>= 1) {
        if (tid < off) red[tid] += red[tid + off];
        __syncthreads();
    }
    float inv = rsqrtf(red[0] * (1.0f / Dm) + 1e-5f);
    float* o = out + (size_t)t * Dm;
    o[tid]       = d0 * inv * g[tid]       + b[tid];
    o[tid + 256] = d1 * inv * g[tid + 256] + b[tid + 256];
    o[tid + 512] = d2 * inv * g[tid + 512] + b[tid + 512];
}

// ---------------- Generic GEMM: C[M,N] = act(A[M,K] * B[N,K]^T + bias + res) ----------------
// All fp32. float4 staging loads (K multiple of 16, rows 16B-aligned).
#define BMt 64
#define BNt 64
#define BKt 16
template<int ACT, int RES>
__global__ __launch_bounds__(256) void gemm_bt(const float* __restrict__ A,
                                               const float* __restrict__ B,
                                               const float* __restrict__ bias,
                                               const float* __restrict__ res,
                                               float* __restrict__ Cout,
                                               int M, int N, int K) {
    __shared__ float As[BKt][BMt];
    __shared__ float Bs[BKt][BNt];
    int tid = threadIdx.x;
    int bm = blockIdx.y * BMt;
    int bn = blockIdx.x * BNt;
    int tx = tid & 15, ty = tid >> 4;
    float acc[4][4] = {};
    int lrow = tid >> 2;          // 0..63
    int lk4  = (tid & 3) * 4;     // 0,4,8,12

    for (int kk = 0; kk < K; kk += BKt) {
        {
            float4 v = *reinterpret_cast<const float4*>(A + (size_t)(bm + lrow) * K + kk + lk4);
            As[lk4 + 0][lrow] = v.x; As[lk4 + 1][lrow] = v.y;
            As[lk4 + 2][lrow] = v.z; As[lk4 + 3][lrow] = v.w;
        }
        {
            float4 v = make_float4(0.f, 0.f, 0.f, 0.f);
            if (bn + lrow < N)
                v = *reinterpret_cast<const float4*>(B + (size_t)(bn + lrow) * K + kk + lk4);
            Bs[lk4 + 0][lrow] = v.x; Bs[lk4 + 1][lrow] = v.y;
            Bs[lk4 + 2][lrow] = v.z; Bs[lk4 + 3][lrow] = v.w;
        }
        __syncthreads();
        #pragma unroll
        for (int k = 0; k < BKt; ++k) {
            float a[4], bb[4];
            #pragma unroll
            for (int i = 0; i < 4; ++i) a[i] = As[k][ty * 4 + i];
            #pragma unroll
            for (int j = 0; j < 4; ++j) bb[j] = Bs[k][tx * 4 + j];
            #pragma unroll
            for (int i = 0; i < 4; ++i)
                #pragma unroll
                for (int j = 0; j < 4; ++j)
                    acc[i][j] += a[i] * bb[j];
        }
        __syncthreads();
    }

    #pragma unroll
    for (int i = 0; i < 4; ++i) {
        int m = bm + ty * 4 + i;
        #pragma unroll
        for (int j = 0; j < 4; ++j) {
            int n = bn + tx * 4 + j;
            if (n < N) {
                float v = acc[i][j];
                if (bias) v += bias[n];
                if (RES)  v += res[(size_t)m * N + n];
                if (ACT == 1) v = gelu_exact(v);
                Cout[(size_t)m * N + n] = v;
            }
        }
    }
}

// ---------------- Causal attention, one block per (b, head, q-row) ----------------
__global__ __launch_bounds__(256) void attn_kernel(const float* __restrict__ qkv,
                                                   float* __restrict__ o) {
    int idx = blockIdx.x;
    int tq = idx % Tm; idx /= Tm;
    int hh = idx % NHm;
    int b  = idx / NHm;
    int tid = threadIdx.x;
    const int g0 = b * Tm;
    __shared__ float qs[64];
    __shared__ float s[Tm];
    __shared__ float red[256];
    __shared__ float part[4][64];

    const float* qrow = qkv + (size_t)(g0 + tq) * (3 * Dm) + hh * 64;
    if (tid < 64) qs[tid] = qrow[tid];
    __syncthreads();

    int nk = tq + 1;
    float lmax = -1e30f;
    for (int k = tid; k < nk; k += 256) {
        const float* krow = qkv + (size_t)(g0 + k) * (3 * Dm) + Dm + hh * 64;
        float dot = 0.f;
        for (int d = 0; d < 64; ++d) dot += qs[d] * krow[d];
        dot *= 0.125f;   // 1/sqrt(64)
        s[k] = dot;
        lmax = fmaxf(lmax, dot);
    }
    red[tid] = lmax;
    __syncthreads();
    for (int off = 128; off > 0; off >>= 1) {
        if (tid < off) red[tid] = fmaxf(red[tid], red[tid + off]);
        __syncthreads();
    }
    float mx = red[0];

    float lsum = 0.f;
    for (int k = tid; k < nk; k += 256) {
        float e = expf(s[k] - mx);
        s[k] = e;
        lsum += e;
    }
    __syncthreads();
    red[tid] = lsum;
    __syncthreads();
    for (int off = 128; off > 0; off >>= 1) {
        if (tid < off) red[tid] += red[tid + off];
        __syncthreads();
    }
    float inv = 1.0f / red[0];

    int grp = tid >> 6;
    int d = tid & 63;
    float acc = 0.f;
    for (int k = grp; k < nk; k += 4) {
        acc += s[k] * qkv[(size_t)(g0 + k) * (3 * Dm) + 2 * Dm + hh * 64 + d];
    }
    part[grp][d] = acc;
    __syncthreads();
    if (tid < 64) {
        float r = (part[0][tid] + part[1][tid] + part[2][tid] + part[3][tid]) * inv;
        o[(size_t)(g0 + tq) * Dm + hh * 64 + tid] = r;
    }
}

// ---------------- MoE router: top-2 of softmax over 8 experts ----------------
__global__ __launch_bounds__(256) void router_kernel(const float* __restrict__ xn,
                                                     const float* __restrict__ gw,
                                                     int* __restrict__ topi,
                                                     float* __restrict__ topw) {
    int t = blockIdx.x * 256 + threadIdx.x;
    if (t >= NT) return;
    const float* x = xn + (size_t)t * Dm;
    float l[Em];
    #pragma unroll
    for (int e = 0; e < Em; ++e) {
        const float* w = gw + (size_t)e * Dm;
        float dot = 0.f;
        for (int d = 0; d < Dm; ++d) dot += w[d] * x[d];
        l[e] = dot;
    }
    int i1 = 0;
    #pragma unroll
    for (int e = 1; e < Em; ++e) if (l[e] > l[i1]) i1 = e;
    int i2 = (i1 == 0) ? 1 : 0;
    #pragma unroll
    for (int e = 0; e < Em; ++e) if (e != i1 && l[e] > l[i2]) i2 = e;
    float w1 = 1.0f / (1.0f + expf(l[i2] - l[i1]));
    topi[t * 2] = i1; topi[t * 2 + 1] = i2;
    topw[t * 2] = w1; topw[t * 2 + 1] = 1.0f - w1;
}

// ---------------- Route build: bucket assignments by expert ----------------
// One block. cnt/off -> global; bucket[p] = ts (t*2+slot) in expert order.
__global__ __launch_bounds__(256) void route_build_kernel(const int* __restrict__ topi,
                                                          int* __restrict__ g_cnt,
                                                          int* __restrict__ g_off,
                                                          int* __restrict__ bucket) {
    __shared__ int cnt[Em], off[Em], pos[Em];
    int tid = threadIdx.x;
    if (tid < Em) cnt[tid] = 0;
    __syncthreads();
    for (int ts = tid; ts < NAS; ts += 256) atomicAdd(&cnt[topi[ts]], 1);
    __syncthreads();
    if (tid == 0) {
        int acc = 0;
        for (int e = 0; e < Em; ++e) { off[e] = acc; pos[e] = acc; acc += cnt[e]; }
    }
    __syncthreads();
    for (int ts = tid; ts < NAS; ts += 256) {
        int e = topi[ts];
        int p = atomicAdd(&pos[e], 1);
        bucket[p] = ts;
    }
    if (tid < Em) { g_cnt[tid] = cnt[tid]; g_off[tid] = off[tid]; }
}

// ---------------- Grouped expert GEMM1: heg[p][j] = gelu(xn[tok(p)] . W1[e][j] + b1[e][j]) ----
// grid: (Hm/BNt, 32, Em). Rows gathered via bucket.
__global__ __launch_bounds__(256) void moe_gemm1_kernel(const float* __restrict__ xn,
                                                        const float* __restrict__ W1all,
                                                        const float* __restrict__ B1all,
                                                        const int* __restrict__ bucket,
                                                        const int* __restrict__ cnt,
                                                        const int* __restrict__ off,
                                                        float* __restrict__ heg) {
    int e = blockIdx.z;
    int count = cnt[e];
    int mbase = blockIdx.y * BMt;
    if (mbase >= count) return;
    int base = off[e];

    __shared__ float As[BKt][BMt];
    __shared__ float Bs[BKt][BNt];
    __shared__ int toks[BMt];
    int tid = threadIdx.x;
    int bn = blockIdx.x * BNt;
    int tx = tid & 15, ty = tid >> 4;
    int lrow = tid >> 2, lk4 = (tid & 3) * 4;
    if (tid < BMt) {
        int p = mbase + tid;
        toks[tid] = (p < count) ? (bucket[base + p] >> 1) : -1;
    }
    __syncthreads();

    float acc[4][4] = {};
    const float* W = W1all + (size_t)e * Hm * Dm;
    for (int kk = 0; kk < Dm; kk += BKt) {
        int t = toks[lrow];
        float4 av = make_float4(0.f, 0.f, 0.f, 0.f);
        if (t >= 0)
            av = *reinterpret_cast<const float4*>(xn + (size_t)t * Dm + kk + lk4);
        As[lk4 + 0][lrow] = av.x; As[lk4 + 1][lrow] = av.y;
        As[lk4 + 2][lrow] = av.z; As[lk4 + 3][lrow] = av.w;
        float4 bv = *reinterpret_cast<const float4*>(W + (size_t)(bn + lrow) * Dm + kk + lk4);
        Bs[lk4 + 0][lrow] = bv.x; Bs[lk4 + 1][lrow] = bv.y;
        Bs[lk4 + 2][lrow] = bv.z; Bs[lk4 + 3][lrow] = bv.w;
        __syncthreads();
        #pragma unroll
        for (int k = 0; k < BKt; ++k) {
            float a[4], bb[4];
            #pragma unroll
            for (int i = 0; i < 4; ++i) a[i] = As[k][ty * 4 + i];
            #pragma unroll
            for (int j = 0; j < 4; ++j) bb[j] = Bs[k][tx * 4 + j];
            #pragma unroll
            for (int i = 0; i < 4; ++i)
                #pragma unroll
                for (int j = 0; j < 4; ++j)
                    acc[i][j] += a[i] * bb[j];
        }
        __syncthreads();
    }

    const float* b1 = B1all + (size_t)e * Hm;
    #pragma unroll
    for (int i = 0; i < 4; ++i) {
        int p = mbase + ty * 4 + i;
        if (p < count) {
            #pragma unroll
            for (int j = 0; j < 4; ++j) {
                int n = bn + tx * 4 + j;
                heg[(size_t)(base + p) * Hm + n] = gelu_exact(acc[i][j] + b1[n]);
            }
        }
    }
}

// ---------------- Grouped expert GEMM2: ye[ts][d] = w_ts * (heg[p] . W2[e][d] + b2[e][d]) ----
// grid: (Dm/BNt, 32, Em). heg already in bucket order (contiguous A).
__global__ __launch_bounds__(256) void moe_gemm2_kernel(const float* __restrict__ heg,
                                                        const float* __restrict__ W2all,
                                                        const float* __restrict__ B2all,
                                                        const int* __restrict__ bucket,
                                                        const int* __restrict__ cnt,
                                                        const int* __restrict__ off,
                                                        const float* __restrict__ topw,
                                                        float* __restrict__ ye) {
    int e = blockIdx.z;
    int count = cnt[e];
    int mbase = blockIdx.y * BMt;
    if (mbase >= count) return;
    int base = off[e];

    __shared__ float As[BKt][BMt];
    __shared__ float Bs[BKt][BNt];
    int tid = threadIdx.x;
    int bn = blockIdx.x * BNt;
    int tx = tid & 15, ty = tid >> 4;
    int lrow = tid >> 2, lk4 = (tid & 3) * 4;

    float acc[4][4] = {};
    const float* W = W2all + (size_t)e * Dm * Hm;
    for (int kk = 0; kk < Hm; kk += BKt) {
        int p = mbase + lrow;
        float4 av = make_float4(0.f, 0.f, 0.f, 0.f);
        if (p < count)
            av = *reinterpret_cast<const float4*>(heg + (size_t)(base + p) * Hm + kk + lk4);
        As[lk4 + 0][lrow] = av.x; As[lk4 + 1][lrow] = av.y;
        As[lk4 + 2][lrow] = av.z; As[lk4 + 3][lrow] = av.w;
        float4 bv = *reinterpret_cast<const float4*>(W + (size_t)(bn + lrow) * Hm + kk + lk4);
        Bs[lk4 + 0][lrow] = bv.x; Bs[lk4 + 1][lrow] = bv.y;
        Bs[lk4 + 2][lrow] = bv.z; Bs[lk4 + 3][lrow] = bv.w;
        __syncthreads();
        #pragma unroll
        for (int k = 0; k < BKt; ++k) {
            float a[4], bb[4];
            #pragma unroll
            for (int i = 0; i < 4; ++i) a[i] = As[k][ty * 4 + i];
            #pragma unroll
            for (int j = 0; j < 4; ++j) bb[j] = Bs[k][tx * 4 + j];
            #pragma unroll
            for (int i = 0; i < 4; ++i)
                #pragma unroll
                for (int j = 0; j < 4; ++j)
                    acc[i][j] += a[i] * bb[j];
        }
        __syncthreads();
    }

    const float* b2 = B2all + (size_t)e * Dm;
    #pragma unroll
    for (int i = 0; i < 4; ++i) {
        int p = mbase + ty * 4 + i;
        if (p < count) {
            int ts = bucket[base + p];
            float w = topw[ts];
            #pragma unroll
            for (int j = 0; j < 4; ++j) {
                int n = bn + tx * 4 + j;
                ye[(size_t)ts * Dm + n] = w * (acc[i][j] + b2[n]);
            }
        }
    }
}

__global__ __launch_bounds__(256) void combine_kernel(float* __restrict__ h,
                                                      const float* __restrict__ ye) {
    int i = blockIdx.x * 256 + threadIdx.x;
    if (i < NT * Dm) {
        int t = i / Dm, d = i - t * Dm;
        h[i] += ye[(size_t)(t * 2) * Dm + d] + ye[(size_t)(t * 2 + 1) * Dm + d];
    }
}

// ---------------- Launch ----------------
extern "C" void kernel_launch(void* const* d_in, const int* in_sizes, int n_in,
                              void* d_out, int out_size, void* d_ws, size_t ws_size,
                              hipStream_t stream) {
    const int*   x    = (const int*)d_in[0];
    const float* emb  = (const float*)d_in[1];
    const float* wqkv = (const float*)d_in[2];
    const float* bqkv = (const float*)d_in[3];
    const float* wo   = (const float*)d_in[4];
    const float* bo   = (const float*)d_in[5];
    const float* ln1g = (const float*)d_in[6];
    const float* ln1b = (const float*)d_in[7];
    const float* ln2g = (const float*)d_in[8];
    const float* ln2b = (const float*)d_in[9];
    const float* sw1  = (const float*)d_in[10];
    const float* sb1  = (const float*)d_in[11];
    const float* sw2  = (const float*)d_in[12];
    const float* sb2  = (const float*)d_in[13];
    const float* gw   = (const float*)d_in[14];
    const float* mw1  = (const float*)d_in[15];
    const float* mb1  = (const float*)d_in[16];
    const float* mw2  = (const float*)d_in[17];
    const float* mb2  = (const float*)d_in[18];
    const float* lnfg = (const float*)d_in[19];
    const float* lnfb = (const float*)d_in[20];

    // Buffer sizes (floats)
    const size_t n_h   = (size_t)NT * Dm;
    const size_t n_qkv = (size_t)NT * 3 * Dm;
    const size_t n_ffh = (size_t)NT * Hm;
    const size_t n_ye  = (size_t)NAS * Dm;
    const size_t n_heg = (size_t)NAS * Hm;       // gathered expert hidden, 25.2 MB
    const size_t n_xn  = (size_t)NT * Dm;
    const size_t n_small = n_xn + NAS /*topw*/ + NAS /*topi*/ + NAS /*bucket*/ + 32;
    const size_t n_big   = n_h + n_qkv + n_h /*attno*/ + n_ffh + n_ye + n_heg;

    // Small stuff always in d_ws.
    float* w = (float*)d_ws;
    float* xn   = w;            w += n_xn;
    float* topw = w;            w += NAS;
    int*   topi = (int*)w;      w += NAS;
    int*   bucket = (int*)w;    w += NAS;
    int*   e_cnt = (int*)w;     w += 8;
    int*   e_off = (int*)w;     w += 8;

    float *h, *qkv, *attno, *ffh, *ye, *heg;
    if (ws_size >= (n_small + n_big + 64) * sizeof(float)) {
        float* a = w;
        h = a;      a += n_h;
        qkv = a;    a += n_qkv;
        attno = a;  a += n_h;
        ffh = a;    a += n_ffh;
        ye = a;     a += n_ye;
        heg = a;
    } else {
        // Big intermediates in the front of d_out (59.5 MB used of 205.8 MB);
        // final logits GEMM overwrites all of d_out, reading only xn + emb.
        float* a = (float*)d_out;
        h = a;      a += n_h;
        qkv = a;    a += n_qkv;
        attno = a;  a += n_h;
        ffh = a;    a += n_ffh;
        ye = a;     a += n_ye;
        heg = a;
    }

    embed_kernel<<<NT, 256, 0, stream>>>(x, emb, h);

    int std_i = 0, moe_i = 0;
    for (int l = 0; l < Lm; ++l) {
        ln_kernel<<<NT, 256, 0, stream>>>(h, ln1g + l * Dm, ln1b + l * Dm, xn);
        gemm_bt<0,0><<<dim3((3 * Dm) / BNt, NT / BMt), 256, 0, stream>>>(
            xn, wqkv + (size_t)l * 3 * Dm * Dm, bqkv + (size_t)l * 3 * Dm,
            nullptr, qkv, NT, 3 * Dm, Dm);
        attn_kernel<<<Bm * NHm * Tm, 256, 0, stream>>>(qkv, attno);
        gemm_bt<0,1><<<dim3(Dm / BNt, NT / BMt), 256, 0, stream>>>(
            attno, wo + (size_t)l * Dm * Dm, bo + (size_t)l * Dm, h, h, NT, Dm, Dm);

        ln_kernel<<<NT, 256, 0, stream>>>(h, ln2g + l * Dm, ln2b + l * Dm, xn);
        if (l == 1 || l == 3) {
            router_kernel<<<(NT + 255) / 256, 256, 0, stream>>>(
                xn, gw + (size_t)moe_i * Em * Dm, topi, topw);
            route_build_kernel<<<1, 256, 0, stream>>>(topi, e_cnt, e_off, bucket);
            moe_gemm1_kernel<<<dim3(Hm / BNt, NAS / BMt, Em), 256, 0, stream>>>(
                xn, mw1 + (size_t)moe_i * Em * Hm * Dm, mb1 + (size_t)moe_i * Em * Hm,
                bucket, e_cnt, e_off, heg);
            moe_gemm2_kernel<<<dim3(Dm / BNt, NAS / BMt, Em), 256, 0, stream>>>(
                heg, mw2 + (size_t)moe_i * Em * Dm * Hm, mb2 + (size_t)moe_i * Em * Dm,
                bucket, e_cnt, e_off, topw, ye);
            combine_kernel<<<(NT * Dm) / 256, 256, 0, stream>>>(h, ye);
            moe_i++;
        } else {
            gemm_bt<1,0><<<dim3(Hm / BNt, NT / BMt), 256, 0, stream>>>(
                xn, sw1 + (size_t)std_i * Hm * Dm, sb1 + (size_t)std_i * Hm,
                nullptr, ffh, NT, Hm, Dm);
            gemm_bt<0,1><<<dim3(Dm / BNt, NT / BMt), 256, 0, stream>>>(
                ffh, sw2 + (size_t)std_i * Dm * Hm, sb2 + (size_t)std_i * Dm,
                h, h, NT, Dm, Hm);
            std_i++;
        }
    }

    ln_kernel<<<NT, 256, 0, stream>>>(h, lnfg, lnfb, xn);
    // Final logits GEMM (fp32 out): reads xn + emb, writes ALL of d_out.
    gemm_bt<0,0><<<dim3((Vm + BNt - 1) / BNt, NT / BMt), 256, 0, stream>>>(
        xn, emb, nullptr, nullptr, (float*)d_out, NT, Vm, Dm);
}

// Round 7
// 3610.719 us; speedup vs baseline: 3.5836x; 1.3162x over previous
//
#include <hip/hip_runtime.h>
#include <cstdint>
#include <cstddef>

// ---- Model constants ----
#define Dm   768
#define NHm  12
#define Lm   4
#define Em   8
#define Vm   50257
#define Hm   3072
#define Tm   512
#define Bm   2
#define NT   (Bm*Tm)      // 1024 tokens
#define NAS  (NT*2)       // 2048 expert assignments

typedef float f32x4 __attribute__((ext_vector_type(4)));
typedef short bf16x8 __attribute__((ext_vector_type(8)));

__device__ __forceinline__ float gelu_exact(float x) {
    return 0.5f * x * (1.0f + erff(x * 0.70710678118654752440f));
}

__device__ __forceinline__ unsigned short f2bf(float f) {
    union { float f; unsigned u; } c; c.f = f;
    unsigned u = c.u + 0x7FFFu + ((c.u >> 16) & 1u);
    return (unsigned short)(u >> 16);
}

// ---------------- Embedding + sinusoidal PE ----------------
__global__ __launch_bounds__(256) void embed_kernel(const int* __restrict__ x,
                                                    const float* __restrict__ emb,
                                                    float* __restrict__ h) {
    int g = blockIdx.x;
    int tid = threadIdx.x;
    int tok = x[g];
    int pos = g % Tm;
    const float* erow = emb + (size_t)tok * Dm;
    for (int d = tid; d < Dm; d += 256) {
        int i2 = (d >> 1) * 2;
        float div = expf(-logf(10000.0f) * (float)i2 / (float)Dm);
        float a = (float)pos * div;
        float pe = (d & 1) ? cosf(a) : sinf(a);
        h[(size_t)g * Dm + d] = erow[d] + pe;
    }
}

// ---------------- LayerNorm ----------------
__global__ __launch_bounds__(256) void ln_kernel(const float* __restrict__ in,
                                                 const float* __restrict__ g,
                                                 const float* __restrict__ b,
                                                 float* __restrict__ out) {
    int t = blockIdx.x, tid = threadIdx.x;
    const float* x = in + (size_t)t * Dm;
    float v0 = x[tid], v1 = x[tid + 256], v2 = x[tid + 512];
    __shared__ float red[256];
    red[tid] = v0 + v1 + v2;
    __syncthreads();
    for (int off = 128; off > 0; off >>= 1) {
        if (tid < off) red[tid] += red[tid + off];
        __syncthreads();
    }
    float mean = red[0] * (1.0f / Dm);
    __syncthreads();
    float d0 = v0 - mean, d1 = v1 - mean, d2 = v2 - mean;
    red[tid] = d0 * d0 + d1 * d1 + d2 * d2;
    __syncthreads();
    for (int off = 128; off > 0; off >>= 1) {
        if (tid < off) red[tid] += red[tid + off];
        __syncthreads();
    }
    float inv = rsqrtf(red[0] * (1.0f / Dm) + 1e-5f);
    float* o = out + (size_t)t * Dm;
    o[tid]       = d0 * inv * g[tid]       + b[tid];
    o[tid + 256] = d1 * inv * g[tid + 256] + b[tid + 256];
    o[tid + 512] = d2 * inv * g[tid + 512] + b[tid + 512];
}

// ============ fp32 VALU GEMM (precision-critical, upstream of routers) ============
#define BMt 64
#define BNt 64
#define BKt 16
template<int ACT, int RES>
__global__ __launch_bounds__(256) void gemm_bt(const float* __restrict__ A,
                                               const float* __restrict__ B,
                                               const float* __restrict__ bias,
                                               const float* __restrict__ res,
                                               float* __restrict__ Cout,
                                               int M, int N, int K) {
    __shared__ float As[BKt][BMt];
    __shared__ float Bs[BKt][BNt];
    int tid = threadIdx.x;
    int bm = blockIdx.y * BMt;
    int bn = blockIdx.x * BNt;
    int tx = tid & 15, ty = tid >> 4;
    float acc[4][4] = {};
    int lrow = tid >> 2;
    int lk4  = (tid & 3) * 4;

    for (int kk = 0; kk < K; kk += BKt) {
        {
            float4 v = *reinterpret_cast<const float4*>(A + (size_t)(bm + lrow) * K + kk + lk4);
            As[lk4 + 0][lrow] = v.x; As[lk4 + 1][lrow] = v.y;
            As[lk4 + 2][lrow] = v.z; As[lk4 + 3][lrow] = v.w;
        }
        {
            float4 v = make_float4(0.f, 0.f, 0.f, 0.f);
            if (bn + lrow < N)
                v = *reinterpret_cast<const float4*>(B + (size_t)(bn + lrow) * K + kk + lk4);
            Bs[lk4 + 0][lrow] = v.x; Bs[lk4 + 1][lrow] = v.y;
            Bs[lk4 + 2][lrow] = v.z; Bs[lk4 + 3][lrow] = v.w;
        }
        __syncthreads();
        #pragma unroll
        for (int k = 0; k < BKt; ++k) {
            float a[4], bb[4];
            #pragma unroll
            for (int i = 0; i < 4; ++i) a[i] = As[k][ty * 4 + i];
            #pragma unroll
            for (int j = 0; j < 4; ++j) bb[j] = Bs[k][tx * 4 + j];
            #pragma unroll
            for (int i = 0; i < 4; ++i)
                #pragma unroll
                for (int j = 0; j < 4; ++j)
                    acc[i][j] += a[i] * bb[j];
        }
        __syncthreads();
    }

    #pragma unroll
    for (int i = 0; i < 4; ++i) {
        int m = bm + ty * 4 + i;
        #pragma unroll
        for (int j = 0; j < 4; ++j) {
            int n = bn + tx * 4 + j;
            if (n < N) {
                float v = acc[i][j];
                if (bias) v += bias[n];
                if (RES)  v += res[(size_t)m * N + n];
                if (ACT == 1) v = gelu_exact(v);
                Cout[(size_t)m * N + n] = v;
            }
        }
    }
}

// ============ bf16 MFMA GEMM (downstream of all routers only) ============
// 128x128x32 tile, 4 waves 2x2, 4x4 16x16x32 fragments. LDS stride 40.
#define MB 128
#define NB 128
#define KB 32
#define LDT 40

__device__ __forceinline__ void stage_tile(unsigned short* lds, const float* src,
                                           bool valid, int srow, int shalf) {
    union { unsigned short s[8]; uint4 v; } p0, p1;
    if (valid) {
        const float4* s4 = reinterpret_cast<const float4*>(src);
        float4 f0 = s4[0], f1 = s4[1], f2 = s4[2], f3 = s4[3];
        p0.s[0] = f2bf(f0.x); p0.s[1] = f2bf(f0.y); p0.s[2] = f2bf(f0.z); p0.s[3] = f2bf(f0.w);
        p0.s[4] = f2bf(f1.x); p0.s[5] = f2bf(f1.y); p0.s[6] = f2bf(f1.z); p0.s[7] = f2bf(f1.w);
        p1.s[0] = f2bf(f2.x); p1.s[1] = f2bf(f2.y); p1.s[2] = f2bf(f2.z); p1.s[3] = f2bf(f2.w);
        p1.s[4] = f2bf(f3.x); p1.s[5] = f2bf(f3.y); p1.s[6] = f2bf(f3.z); p1.s[7] = f2bf(f3.w);
    } else {
        p0.v = make_uint4(0, 0, 0, 0);
        p1.v = make_uint4(0, 0, 0, 0);
    }
    uint4* dst = reinterpret_cast<uint4*>(&lds[srow * LDT + shalf * 16]);
    dst[0] = p0.v; dst[1] = p1.v;
}

template<int ACT, int RES>
__global__ __launch_bounds__(256) void mfma_gemm(const float* __restrict__ A,
                                                 const float* __restrict__ B,
                                                 const float* __restrict__ bias,
                                                 const float* __restrict__ res,
                                                 float* __restrict__ C,
                                                 int M, int N, int K) {
    __shared__ __align__(16) unsigned short As[MB * LDT];
    __shared__ __align__(16) unsigned short Bs[NB * LDT];
    int tid = threadIdx.x;
    int bm = blockIdx.y * MB, bn = blockIdx.x * NB;
    int srow = tid >> 1, shalf = tid & 1;
    int lane = tid & 63, w = tid >> 6;
    int wr = w >> 1, wc = w & 1;
    int r0 = (lane >> 4) * 4, c0 = lane & 15;
    int kb = (lane >> 4) * 8;

    f32x4 acc[4][4] = {};

    for (int kk = 0; kk < K; kk += KB) {
        stage_tile(As, A + (size_t)(bm + srow) * K + kk + shalf * 16, true, srow, shalf);
        bool bval = (bn + srow) < N;
        stage_tile(Bs, B + (size_t)(bn + srow) * K + kk + shalf * 16, bval, srow, shalf);
        __syncthreads();
        bf16x8 af[4], bf[4];
        #pragma unroll
        for (int m = 0; m < 4; ++m)
            af[m] = *reinterpret_cast<const bf16x8*>(&As[(wr * 64 + m * 16 + c0) * LDT + kb]);
        #pragma unroll
        for (int n = 0; n < 4; ++n)
            bf[n] = *reinterpret_cast<const bf16x8*>(&Bs[(wc * 64 + n * 16 + c0) * LDT + kb]);
        #pragma unroll
        for (int m = 0; m < 4; ++m)
            #pragma unroll
            for (int n = 0; n < 4; ++n)
                acc[m][n] = __builtin_amdgcn_mfma_f32_16x16x32_bf16(af[m], bf[n], acc[m][n], 0, 0, 0);
        __syncthreads();
    }

    #pragma unroll
    for (int n = 0; n < 4; ++n) {
        int col = bn + wc * 64 + n * 16 + c0;
        if (col < N) {
            float bv = bias ? bias[col] : 0.f;
            #pragma unroll
            for (int m = 0; m < 4; ++m) {
                #pragma unroll
                for (int r = 0; r < 4; ++r) {
                    int row = bm + wr * 64 + m * 16 + r0 + r;
                    float v = acc[m][n][r] + bv;
                    if (RES) v += res[(size_t)row * N + col];
                    if (ACT == 1) v = gelu_exact(v);
                    C[(size_t)row * N + col] = v;
                }
            }
        }
    }
}

// ---------------- Causal attention (fp32) ----------------
__global__ __launch_bounds__(256) void attn_kernel(const float* __restrict__ qkv,
                                                   float* __restrict__ o) {
    int idx = blockIdx.x;
    int tq = idx % Tm; idx /= Tm;
    int hh = idx % NHm;
    int b  = idx / NHm;
    int tid = threadIdx.x;
    const int g0 = b * Tm;
    __shared__ float qs[64];
    __shared__ float s[Tm];
    __shared__ float red[256];
    __shared__ float part[4][64];

    const float* qrow = qkv + (size_t)(g0 + tq) * (3 * Dm) + hh * 64;
    if (tid < 64) qs[tid] = qrow[tid];
    __syncthreads();

    int nk = tq + 1;
    float lmax = -1e30f;
    for (int k = tid; k < nk; k += 256) {
        const float* krow = qkv + (size_t)(g0 + k) * (3 * Dm) + Dm + hh * 64;
        float dot = 0.f;
        for (int d = 0; d < 64; ++d) dot += qs[d] * krow[d];
        dot *= 0.125f;
        s[k] = dot;
        lmax = fmaxf(lmax, dot);
    }
    red[tid] = lmax;
    __syncthreads();
    for (int off = 128; off > 0; off >>= 1) {
        if (tid < off) red[tid] = fmaxf(red[tid], red[tid + off]);
        __syncthreads();
    }
    float mx = red[0];

    float lsum = 0.f;
    for (int k = tid; k < nk; k += 256) {
        float e = expf(s[k] - mx);
        s[k] = e;
        lsum += e;
    }
    __syncthreads();
    red[tid] = lsum;
    __syncthreads();
    for (int off = 128; off > 0; off >>= 1) {
        if (tid < off) red[tid] += red[tid + off];
        __syncthreads();
    }
    float inv = 1.0f / red[0];

    int grp = tid >> 6;
    int d = tid & 63;
    float acc = 0.f;
    for (int k = grp; k < nk; k += 4) {
        acc += s[k] * qkv[(size_t)(g0 + k) * (3 * Dm) + 2 * Dm + hh * 64 + d];
    }
    part[grp][d] = acc;
    __syncthreads();
    if (tid < 64) {
        float r = (part[0][tid] + part[1][tid] + part[2][tid] + part[3][tid]) * inv;
        o[(size_t)(g0 + tq) * Dm + hh * 64 + tid] = r;
    }
}

// ---------------- MoE router (fp32 exact) ----------------
__global__ __launch_bounds__(256) void router_kernel(const float* __restrict__ xn,
                                                     const float* __restrict__ gw,
                                                     int* __restrict__ topi,
                                                     float* __restrict__ topw) {
    int t = blockIdx.x * 256 + threadIdx.x;
    if (t >= NT) return;
    const float* x = xn + (size_t)t * Dm;
    float l[Em];
    #pragma unroll
    for (int e = 0; e < Em; ++e) {
        const float* w = gw + (size_t)e * Dm;
        float dot = 0.f;
        for (int d = 0; d < Dm; ++d) dot += w[d] * x[d];
        l[e] = dot;
    }
    int i1 = 0;
    #pragma unroll
    for (int e = 1; e < Em; ++e) if (l[e] > l[i1]) i1 = e;
    int i2 = (i1 == 0) ? 1 : 0;
    #pragma unroll
    for (int e = 0; e < Em; ++e) if (e != i1 && l[e] > l[i2]) i2 = e;
    float w1 = 1.0f / (1.0f + expf(l[i2] - l[i1]));
    topi[t * 2] = i1; topi[t * 2 + 1] = i2;
    topw[t * 2] = w1; topw[t * 2 + 1] = 1.0f - w1;
}

// ---------------- Route build ----------------
__global__ __launch_bounds__(256) void route_build_kernel(const int* __restrict__ topi,
                                                          int* __restrict__ g_cnt,
                                                          int* __restrict__ g_off,
                                                          int* __restrict__ bucket) {
    __shared__ int cnt[Em], off[Em], pos[Em];
    int tid = threadIdx.x;
    if (tid < Em) cnt[tid] = 0;
    __syncthreads();
    for (int ts = tid; ts < NAS; ts += 256) atomicAdd(&cnt[topi[ts]], 1);
    __syncthreads();
    if (tid == 0) {
        int acc = 0;
        for (int e = 0; e < Em; ++e) { off[e] = acc; pos[e] = acc; acc += cnt[e]; }
    }
    __syncthreads();
    for (int ts = tid; ts < NAS; ts += 256) {
        int e = topi[ts];
        int p = atomicAdd(&pos[e], 1);
        bucket[p] = ts;
    }
    if (tid < Em) { g_cnt[tid] = cnt[tid]; g_off[tid] = off[tid]; }
}

// ---------------- fp32 grouped MoE GEMMs (layer-1: upstream of layer-3 router) ----------------
__global__ __launch_bounds__(256) void moe_gemm1_kernel(const float* __restrict__ xn,
                                                        const float* __restrict__ W1all,
                                                        const float* __restrict__ B1all,
                                                        const int* __restrict__ bucket,
                                                        const int* __restrict__ cnt,
                                                        const int* __restrict__ off,
                                                        float* __restrict__ heg) {
    int e = blockIdx.z;
    int count = cnt[e];
    int mbase = blockIdx.y * BMt;
    if (mbase >= count) return;
    int base = off[e];

    __shared__ float As[BKt][BMt];
    __shared__ float Bs[BKt][BNt];
    __shared__ int toks[BMt];
    int tid = threadIdx.x;
    int bn = blockIdx.x * BNt;
    int tx = tid & 15, ty = tid >> 4;
    int lrow = tid >> 2, lk4 = (tid & 3) * 4;
    if (tid < BMt) {
        int p = mbase + tid;
        toks[tid] = (p < count) ? (bucket[base + p] >> 1) : -1;
    }
    __syncthreads();

    float acc[4][4] = {};
    const float* W = W1all + (size_t)e * Hm * Dm;
    for (int kk = 0; kk < Dm; kk += BKt) {
        int t = toks[lrow];
        float4 av = make_float4(0.f, 0.f, 0.f, 0.f);
        if (t >= 0)
            av = *reinterpret_cast<const float4*>(xn + (size_t)t * Dm + kk + lk4);
        As[lk4 + 0][lrow] = av.x; As[lk4 + 1][lrow] = av.y;
        As[lk4 + 2][lrow] = av.z; As[lk4 + 3][lrow] = av.w;
        float4 bv = *reinterpret_cast<const float4*>(W + (size_t)(bn + lrow) * Dm + kk + lk4);
        Bs[lk4 + 0][lrow] = bv.x; Bs[lk4 + 1][lrow] = bv.y;
        Bs[lk4 + 2][lrow] = bv.z; Bs[lk4 + 3][lrow] = bv.w;
        __syncthreads();
        #pragma unroll
        for (int k = 0; k < BKt; ++k) {
            float a[4], bb[4];
            #pragma unroll
            for (int i = 0; i < 4; ++i) a[i] = As[k][ty * 4 + i];
            #pragma unroll
            for (int j = 0; j < 4; ++j) bb[j] = Bs[k][tx * 4 + j];
            #pragma unroll
            for (int i = 0; i < 4; ++i)
                #pragma unroll
                for (int j = 0; j < 4; ++j)
                    acc[i][j] += a[i] * bb[j];
        }
        __syncthreads();
    }

    const float* b1 = B1all + (size_t)e * Hm;
    #pragma unroll
    for (int i = 0; i < 4; ++i) {
        int p = mbase + ty * 4 + i;
        if (p < count) {
            #pragma unroll
            for (int j = 0; j < 4; ++j) {
                int n = bn + tx * 4 + j;
                heg[(size_t)(base + p) * Hm + n] = gelu_exact(acc[i][j] + b1[n]);
            }
        }
    }
}

__global__ __launch_bounds__(256) void moe_gemm2_kernel(const float* __restrict__ heg,
                                                        const float* __restrict__ W2all,
                                                        const float* __restrict__ B2all,
                                                        const int* __restrict__ bucket,
                                                        const int* __restrict__ cnt,
                                                        const int* __restrict__ off,
                                                        const float* __restrict__ topw,
                                                        float* __restrict__ ye) {
    int e = blockIdx.z;
    int count = cnt[e];
    int mbase = blockIdx.y * BMt;
    if (mbase >= count) return;
    int base = off[e];

    __shared__ float As[BKt][BMt];
    __shared__ float Bs[BKt][BNt];
    int tid = threadIdx.x;
    int bn = blockIdx.x * BNt;
    int tx = tid & 15, ty = tid >> 4;
    int lrow = tid >> 2, lk4 = (tid & 3) * 4;

    float acc[4][4] = {};
    const float* W = W2all + (size_t)e * Dm * Hm;
    for (int kk = 0; kk < Hm; kk += BKt) {
        int p = mbase + lrow;
        float4 av = make_float4(0.f, 0.f, 0.f, 0.f);
        if (p < count)
            av = *reinterpret_cast<const float4*>(heg + (size_t)(base + p) * Hm + kk + lk4);
        As[lk4 + 0][lrow] = av.x; As[lk4 + 1][lrow] = av.y;
        As[lk4 + 2][lrow] = av.z; As[lk4 + 3][lrow] = av.w;
        float4 bv = *reinterpret_cast<const float4*>(W + (size_t)(bn + lrow) * Hm + kk + lk4);
        Bs[lk4 + 0][lrow] = bv.x; Bs[lk4 + 1][lrow] = bv.y;
        Bs[lk4 + 2][lrow] = bv.z; Bs[lk4 + 3][lrow] = bv.w;
        __syncthreads();
        #pragma unroll
        for (int k = 0; k < BKt; ++k) {
            float a[4], bb[4];
            #pragma unroll
            for (int i = 0; i < 4; ++i) a[i] = As[k][ty * 4 + i];
            #pragma unroll
            for (int j = 0; j < 4; ++j) bb[j] = Bs[k][tx * 4 + j];
            #pragma unroll
            for (int i = 0; i < 4; ++i)
                #pragma unroll
                for (int j = 0; j < 4; ++j)
                    acc[i][j] += a[i] * bb[j];
        }
        __syncthreads();
    }

    const float* b2 = B2all + (size_t)e * Dm;
    #pragma unroll
    for (int i = 0; i < 4; ++i) {
        int p = mbase + ty * 4 + i;
        if (p < count) {
            int ts = bucket[base + p];
            float w = topw[ts];
            #pragma unroll
            for (int j = 0; j < 4; ++j) {
                int n = bn + tx * 4 + j;
                ye[(size_t)ts * Dm + n] = w * (acc[i][j] + b2[n]);
            }
        }
    }
}

// ---------------- bf16 MFMA grouped MoE GEMMs (layer-3 only: downstream of all routers) ----
__global__ __launch_bounds__(256) void moe_mfma_gemm1(const float* __restrict__ xn,
                                                      const float* __restrict__ W1all,
                                                      const float* __restrict__ B1all,
                                                      const int* __restrict__ bucket,
                                                      const int* __restrict__ cnt,
                                                      const int* __restrict__ off,
                                                      float* __restrict__ heg) {
    int e = blockIdx.z;
    int count = cnt[e];
    int mbase = blockIdx.y * MB;
    if (mbase >= count) return;
    int base = off[e];

    __shared__ __align__(16) unsigned short As[MB * LDT];
    __shared__ __align__(16) unsigned short Bs[NB * LDT];
    __shared__ int toks[MB];
    int tid = threadIdx.x;
    int bn = blockIdx.x * NB;
    int srow = tid >> 1, shalf = tid & 1;
    int lane = tid & 63, w = tid >> 6;
    int wr = w >> 1, wc = w & 1;
    int r0 = (lane >> 4) * 4, c0 = lane & 15;
    int kb = (lane >> 4) * 8;
    if (tid < MB) {
        int p = mbase + tid;
        toks[tid] = (p < count) ? (bucket[base + p] >> 1) : -1;
    }
    __syncthreads();

    f32x4 acc[4][4] = {};
    const float* W = W1all + (size_t)e * Hm * Dm;
    int t = toks[srow];
    for (int kk = 0; kk < Dm; kk += KB) {
        stage_tile(As, xn + (size_t)t * Dm + kk + shalf * 16, t >= 0, srow, shalf);
        stage_tile(Bs, W + (size_t)(bn + srow) * Dm + kk + shalf * 16, true, srow, shalf);
        __syncthreads();
        bf16x8 af[4], bf[4];
        #pragma unroll
        for (int m = 0; m < 4; ++m)
            af[m] = *reinterpret_cast<const bf16x8*>(&As[(wr * 64 + m * 16 + c0) * LDT + kb]);
        #pragma unroll
        for (int n = 0; n < 4; ++n)
            bf[n] = *reinterpret_cast<const bf16x8*>(&Bs[(wc * 64 + n * 16 + c0) * LDT + kb]);
        #pragma unroll
        for (int m = 0; m < 4; ++m)
            #pragma unroll
            for (int n = 0; n < 4; ++n)
                acc[m][n] = __builtin_amdgcn_mfma_f32_16x16x32_bf16(af[m], bf[n], acc[m][n], 0, 0, 0);
        __syncthreads();
    }

    const float* b1 = B1all + (size_t)e * Hm;
    #pragma unroll
    for (int n = 0; n < 4; ++n) {
        int col = bn + wc * 64 + n * 16 + c0;
        float bv = b1[col];
        #pragma unroll
        for (int m = 0; m < 4; ++m) {
            #pragma unroll
            for (int r = 0; r < 4; ++r) {
                int p = mbase + wr * 64 + m * 16 + r0 + r;
                if (p < count)
                    heg[(size_t)(base + p) * Hm + col] = gelu_exact(acc[m][n][r] + bv);
            }
        }
    }
}

__global__ __launch_bounds__(256) void moe_mfma_gemm2(const float* __restrict__ heg,
                                                      const float* __restrict__ W2all,
                                                      const float* __restrict__ B2all,
                                                      const int* __restrict__ bucket,
                                                      const int* __restrict__ cnt,
                                                      const int* __restrict__ off,
                                                      const float* __restrict__ topw,
                                                      float* __restrict__ ye) {
    int e = blockIdx.z;
    int count = cnt[e];
    int mbase = blockIdx.y * MB;
    if (mbase >= count) return;
    int base = off[e];

    __shared__ __align__(16) unsigned short As[MB * LDT];
    __shared__ __align__(16) unsigned short Bs[NB * LDT];
    int tid = threadIdx.x;
    int bn = blockIdx.x * NB;
    int srow = tid >> 1, shalf = tid & 1;
    int lane = tid & 63, w = tid >> 6;
    int wr = w >> 1, wc = w & 1;
    int r0 = (lane >> 4) * 4, c0 = lane & 15;
    int kb = (lane >> 4) * 8;

    f32x4 acc[4][4] = {};
    const float* W = W2all + (size_t)e * Dm * Hm;
    bool aval = (mbase + srow) < count;
    for (int kk = 0; kk < Hm; kk += KB) {
        stage_tile(As, heg + (size_t)(base + mbase + srow) * Hm + kk + shalf * 16, aval, srow, shalf);
        stage_tile(Bs, W + (size_t)(bn + srow) * Hm + kk + shalf * 16, true, srow, shalf);
        __syncthreads();
        bf16x8 af[4], bf[4];
        #pragma unroll
        for (int m = 0; m < 4; ++m)
            af[m] = *reinterpret_cast<const bf16x8*>(&As[(wr * 64 + m * 16 + c0) * LDT + kb]);
        #pragma unroll
        for (int n = 0; n < 4; ++n)
            bf[n] = *reinterpret_cast<const bf16x8*>(&Bs[(wc * 64 + n * 16 + c0) * LDT + kb]);
        #pragma unroll
        for (int m = 0; m < 4; ++m)
            #pragma unroll
            for (int n = 0; n < 4; ++n)
                acc[m][n] = __builtin_amdgcn_mfma_f32_16x16x32_bf16(af[m], bf[n], acc[m][n], 0, 0, 0);
        __syncthreads();
    }

    const float* b2 = B2all + (size_t)e * Dm;
    #pragma unroll
    for (int n = 0; n < 4; ++n) {
        int col = bn + wc * 64 + n * 16 + c0;
        float bv = b2[col];
        #pragma unroll
        for (int m = 0; m < 4; ++m) {
            #pragma unroll
            for (int r = 0; r < 4; ++r) {
                int p = mbase + wr * 64 + m * 16 + r0 + r;
                if (p < count) {
                    int ts = bucket[base + p];
                    ye[(size_t)ts * Dm + col] = topw[ts] * (acc[m][n][r] + bv);
                }
            }
        }
    }
}

__global__ __launch_bounds__(256) void combine_kernel(float* __restrict__ h,
                                                      const float* __restrict__ ye) {
    int i = blockIdx.x * 256 + threadIdx.x;
    if (i < NT * Dm) {
        int t = i / Dm, d = i - t * Dm;
        h[i] += ye[(size_t)(t * 2) * Dm + d] + ye[(size_t)(t * 2 + 1) * Dm + d];
    }
}

// ---------------- Launch ----------------
extern "C" void kernel_launch(void* const* d_in, const int* in_sizes, int n_in,
                              void* d_out, int out_size, void* d_ws, size_t ws_size,
                              hipStream_t stream) {
    const int*   x    = (const int*)d_in[0];
    const float* emb  = (const float*)d_in[1];
    const float* wqkv = (const float*)d_in[2];
    const float* bqkv = (const float*)d_in[3];
    const float* wo   = (const float*)d_in[4];
    const float* bo   = (const float*)d_in[5];
    const float* ln1g = (const float*)d_in[6];
    const float* ln1b = (const float*)d_in[7];
    const float* ln2g = (const float*)d_in[8];
    const float* ln2b = (const float*)d_in[9];
    const float* sw1  = (const float*)d_in[10];
    const float* sb1  = (const float*)d_in[11];
    const float* sw2  = (const float*)d_in[12];
    const float* sb2  = (const float*)d_in[13];
    const float* gw   = (const float*)d_in[14];
    const float* mw1  = (const float*)d_in[15];
    const float* mb1  = (const float*)d_in[16];
    const float* mw2  = (const float*)d_in[17];
    const float* mb2  = (const float*)d_in[18];
    const float* lnfg = (const float*)d_in[19];
    const float* lnfb = (const float*)d_in[20];

    const size_t n_h   = (size_t)NT * Dm;
    const size_t n_qkv = (size_t)NT * 3 * Dm;
    const size_t n_ffh = (size_t)NT * Hm;
    const size_t n_ye  = (size_t)NAS * Dm;
    const size_t n_heg = (size_t)NAS * Hm;
    const size_t n_xn  = (size_t)NT * Dm;
    const size_t n_small = n_xn + NAS + NAS + NAS + 32;
    const size_t n_big   = n_h + n_qkv + n_h + n_ffh + n_ye + n_heg;

    float* w = (float*)d_ws;
    float* xn   = w;            w += n_xn;
    float* topw = w;            w += NAS;
    int*   topi = (int*)w;      w += NAS;
    int*   bucket = (int*)w;    w += NAS;
    int*   e_cnt = (int*)w;     w += 8;
    int*   e_off = (int*)w;     w += 8;

    float *h, *qkv, *attno, *ffh, *ye, *heg;
    if (ws_size >= (n_small + n_big + 64) * sizeof(float)) {
        float* a = w;
        h = a;      a += n_h;
        qkv = a;    a += n_qkv;
        attno = a;  a += n_h;
        ffh = a;    a += n_ffh;
        ye = a;     a += n_ye;
        heg = a;
    } else {
        float* a = (float*)d_out;
        h = a;      a += n_h;
        qkv = a;    a += n_qkv;
        attno = a;  a += n_h;
        ffh = a;    a += n_ffh;
        ye = a;     a += n_ye;
        heg = a;
    }

    embed_kernel<<<NT, 256, 0, stream>>>(x, emb, h);

    int std_i = 0, moe_i = 0;
    for (int l = 0; l < Lm; ++l) {
        ln_kernel<<<NT, 256, 0, stream>>>(h, ln1g + l * Dm, ln1b + l * Dm, xn);
        gemm_bt<0,0><<<dim3((3 * Dm) / BNt, NT / BMt), 256, 0, stream>>>(
            xn, wqkv + (size_t)l * 3 * Dm * Dm, bqkv + (size_t)l * 3 * Dm,
            nullptr, qkv, NT, 3 * Dm, Dm);
        attn_kernel<<<Bm * NHm * Tm, 256, 0, stream>>>(qkv, attno);
        gemm_bt<0,1><<<dim3(Dm / BNt, NT / BMt), 256, 0, stream>>>(
            attno, wo + (size_t)l * Dm * Dm, bo + (size_t)l * Dm, h, h, NT, Dm, Dm);

        ln_kernel<<<NT, 256, 0, stream>>>(h, ln2g + l * Dm, ln2b + l * Dm, xn);
        if (l == 1 || l == 3) {
            router_kernel<<<(NT + 255) / 256, 256, 0, stream>>>(
                xn, gw + (size_t)moe_i * Em * Dm, topi, topw);
            route_build_kernel<<<1, 256, 0, stream>>>(topi, e_cnt, e_off, bucket);
            if (l == 3) {
                // downstream of all routers: bf16 MFMA safe
                moe_mfma_gemm1<<<dim3(Hm / NB, NAS / MB, Em), 256, 0, stream>>>(
                    xn, mw1 + (size_t)moe_i * Em * Hm * Dm, mb1 + (size_t)moe_i * Em * Hm,
                    bucket, e_cnt, e_off, heg);
                moe_mfma_gemm2<<<dim3(Dm / NB, NAS / MB, Em), 256, 0, stream>>>(
                    heg, mw2 + (size_t)moe_i * Em * Dm * Hm, mb2 + (size_t)moe_i * Em * Dm,
                    bucket, e_cnt, e_off, topw, ye);
            } else {
                // feeds layer-3 router: must stay fp32
                moe_gemm1_kernel<<<dim3(Hm / BNt, NAS / BMt, Em), 256, 0, stream>>>(
                    xn, mw1 + (size_t)moe_i * Em * Hm * Dm, mb1 + (size_t)moe_i * Em * Hm,
                    bucket, e_cnt, e_off, heg);
                moe_gemm2_kernel<<<dim3(Dm / BNt, NAS / BMt, Em), 256, 0, stream>>>(
                    heg, mw2 + (size_t)moe_i * Em * Dm * Hm, mb2 + (size_t)moe_i * Em * Dm,
                    bucket, e_cnt, e_off, topw, ye);
            }
            combine_kernel<<<(NT * Dm) / 256, 256, 0, stream>>>(h, ye);
            moe_i++;
        } else {
            gemm_bt<1,0><<<dim3(Hm / BNt, NT / BMt), 256, 0, stream>>>(
                xn, sw1 + (size_t)std_i * Hm * Dm, sb1 + (size_t)std_i * Hm,
                nullptr, ffh, NT, Hm, Dm);
            gemm_bt<0,1><<<dim3(Dm / BNt, NT / BMt), 256, 0, stream>>>(
                ffh, sw2 + (size_t)std_i * Dm * Hm, sb2 + (size_t)std_i * Dm,
                h, h, NT, Dm, Hm);
            std_i++;
        }
    }

    ln_kernel<<<NT, 256, 0, stream>>>(h, lnfg, lnfb, xn);
    // Final logits GEMM: bf16 MFMA (downstream of everything).
    mfma_gemm<0,0><<<dim3((Vm + NB - 1) / NB, NT / MB), 256, 0, stream>>>(
        xn, emb, nullptr, nullptr, (float*)d_out, NT, Vm, Dm);
}

// Round 8
// 3138.646 us; speedup vs baseline: 4.1226x; 1.1504x over previous
//
#include <hip/hip_runtime.h>
#include <cstdint>
#include <cstddef>

// ---- Model constants ----
#define Dm   768
#define NHm  12
#define Lm   4
#define Em   8
#define Vm   50257
#define Hm   3072
#define Tm   512
#define Bm   2
#define NT   (Bm*Tm)      // 1024 tokens
#define NAS  (NT*2)       // 2048 expert assignments

typedef float f32x4 __attribute__((ext_vector_type(4)));
typedef short bf16x8 __attribute__((ext_vector_type(8)));

__device__ __forceinline__ float gelu_exact(float x) {
    return 0.5f * x * (1.0f + erff(x * 0.70710678118654752440f));
}

__device__ __forceinline__ unsigned short f2bf(float f) {
    union { float f; unsigned u; } c; c.f = f;
    unsigned u = c.u + 0x7FFFu + ((c.u >> 16) & 1u);
    return (unsigned short)(u >> 16);
}
__device__ __forceinline__ float bf2f_bits(unsigned short b) {
    union { unsigned u; float f; } c; c.u = ((unsigned)b) << 16; return c.f;
}

// ---------------- Embedding + sinusoidal PE ----------------
__global__ __launch_bounds__(256) void embed_kernel(const int* __restrict__ x,
                                                    const float* __restrict__ emb,
                                                    float* __restrict__ h) {
    int g = blockIdx.x;
    int tid = threadIdx.x;
    int tok = x[g];
    int pos = g % Tm;
    const float* erow = emb + (size_t)tok * Dm;
    for (int d = tid; d < Dm; d += 256) {
        int i2 = (d >> 1) * 2;
        float div = expf(-logf(10000.0f) * (float)i2 / (float)Dm);
        float a = (float)pos * div;
        float pe = (d & 1) ? cosf(a) : sinf(a);
        h[(size_t)g * Dm + d] = erow[d] + pe;
    }
}

// ---------------- LayerNorm ----------------
__global__ __launch_bounds__(256) void ln_kernel(const float* __restrict__ in,
                                                 const float* __restrict__ g,
                                                 const float* __restrict__ b,
                                                 float* __restrict__ out) {
    int t = blockIdx.x, tid = threadIdx.x;
    const float* x = in + (size_t)t * Dm;
    float v0 = x[tid], v1 = x[tid + 256], v2 = x[tid + 512];
    __shared__ float red[256];
    red[tid] = v0 + v1 + v2;
    __syncthreads();
    for (int off = 128; off > 0; off >>= 1) {
        if (tid < off) red[tid] += red[tid + off];
        __syncthreads();
    }
    float mean = red[0] * (1.0f / Dm);
    __syncthreads();
    float d0 = v0 - mean, d1 = v1 - mean, d2 = v2 - mean;
    red[tid] = d0 * d0 + d1 * d1 + d2 * d2;
    __syncthreads();
    for (int off = 128; off > 0; off >>= 1) {
        if (tid < off) red[tid] += red[tid + off];
        __syncthreads();
    }
    float inv = rsqrtf(red[0] * (1.0f / Dm) + 1e-5f);
    float* o = out + (size_t)t * Dm;
    o[tid]       = d0 * inv * g[tid]       + b[tid];
    o[tid + 256] = d1 * inv * g[tid + 256] + b[tid + 256];
    o[tid + 512] = d2 * inv * g[tid + 512] + b[tid + 512];
}

// ============ MFMA GEMM machinery ============
// 128x128x32 tile, 4 waves 2x2, 4x4 16x16x32 fragments. LDS row stride 40
// ushort (80 B -> 20 banks -> 2-way aliasing = free).
#define MB 128
#define NB 128
#define KB 32
#define LDT 40

// Plain bf16 staging: one 128x32 fp32 tile -> bf16 LDS.
__device__ __forceinline__ void stage_tile(unsigned short* lds, const float* src,
                                           bool valid, int srow, int shalf) {
    union { unsigned short s[8]; uint4 v; } p0, p1;
    if (valid) {
        const float4* s4 = reinterpret_cast<const float4*>(src);
        #pragma unroll
        for (int q = 0; q < 4; ++q) {
            float4 f = s4[q];
            float vv[4] = {f.x, f.y, f.z, f.w};
            #pragma unroll
            for (int j = 0; j < 4; ++j) {
                int idx = q * 4 + j;
                unsigned short hb = f2bf(vv[j]);
                if (idx < 8) p0.s[idx] = hb; else p1.s[idx - 8] = hb;
            }
        }
    } else {
        p0.v = make_uint4(0, 0, 0, 0);
        p1.v = make_uint4(0, 0, 0, 0);
    }
    uint4* dst = reinterpret_cast<uint4*>(&lds[srow * LDT + shalf * 16]);
    dst[0] = p0.v; dst[1] = p1.v;
}

// Split staging: hi = bf16(x), lo = bf16(x - hi). Two LDS tiles.
__device__ __forceinline__ void stage_tile_split(unsigned short* lds_hi,
                                                 unsigned short* lds_lo,
                                                 const float* src,
                                                 bool valid, int srow, int shalf) {
    union { unsigned short s[8]; uint4 v; } h0, h1, l0, l1;
    if (valid) {
        const float4* s4 = reinterpret_cast<const float4*>(src);
        #pragma unroll
        for (int q = 0; q < 4; ++q) {
            float4 f = s4[q];
            float vv[4] = {f.x, f.y, f.z, f.w};
            #pragma unroll
            for (int j = 0; j < 4; ++j) {
                int idx = q * 4 + j;
                unsigned short hb = f2bf(vv[j]);
                unsigned short lb = f2bf(vv[j] - bf2f_bits(hb));
                if (idx < 8) { h0.s[idx] = hb; l0.s[idx] = lb; }
                else         { h1.s[idx - 8] = hb; l1.s[idx - 8] = lb; }
            }
        }
    } else {
        h0.v = make_uint4(0,0,0,0); h1.v = make_uint4(0,0,0,0);
        l0.v = make_uint4(0,0,0,0); l1.v = make_uint4(0,0,0,0);
    }
    uint4* dh = reinterpret_cast<uint4*>(&lds_hi[srow * LDT + shalf * 16]);
    dh[0] = h0.v; dh[1] = h1.v;
    uint4* dl = reinterpret_cast<uint4*>(&lds_lo[srow * LDT + shalf * 16]);
    dl[0] = l0.v; dl[1] = l1.v;
}

// ---- Plain bf16 MFMA GEMM (downstream of all routers) ----
template<int ACT, int RES>
__global__ __launch_bounds__(256) void mfma_gemm(const float* __restrict__ A,
                                                 const float* __restrict__ B,
                                                 const float* __restrict__ bias,
                                                 const float* __restrict__ res,
                                                 float* __restrict__ C,
                                                 int M, int N, int K) {
    __shared__ __align__(16) unsigned short As[MB * LDT];
    __shared__ __align__(16) unsigned short Bs[NB * LDT];
    int tid = threadIdx.x;
    int bm = blockIdx.y * MB, bn = blockIdx.x * NB;
    int srow = tid >> 1, shalf = tid & 1;
    int lane = tid & 63, w = tid >> 6;
    int wr = w >> 1, wc = w & 1;
    int r0 = (lane >> 4) * 4, c0 = lane & 15;
    int kb = (lane >> 4) * 8;

    f32x4 acc[4][4] = {};

    for (int kk = 0; kk < K; kk += KB) {
        stage_tile(As, A + (size_t)(bm + srow) * K + kk + shalf * 16, true, srow, shalf);
        bool bval = (bn + srow) < N;
        stage_tile(Bs, B + (size_t)(bn + srow) * K + kk + shalf * 16, bval, srow, shalf);
        __syncthreads();
        bf16x8 af[4], bf[4];
        #pragma unroll
        for (int m = 0; m < 4; ++m)
            af[m] = *reinterpret_cast<const bf16x8*>(&As[(wr * 64 + m * 16 + c0) * LDT + kb]);
        #pragma unroll
        for (int n = 0; n < 4; ++n)
            bf[n] = *reinterpret_cast<const bf16x8*>(&Bs[(wc * 64 + n * 16 + c0) * LDT + kb]);
        #pragma unroll
        for (int m = 0; m < 4; ++m)
            #pragma unroll
            for (int n = 0; n < 4; ++n)
                acc[m][n] = __builtin_amdgcn_mfma_f32_16x16x32_bf16(af[m], bf[n], acc[m][n], 0, 0, 0);
        __syncthreads();
    }

    #pragma unroll
    for (int n = 0; n < 4; ++n) {
        int col = bn + wc * 64 + n * 16 + c0;
        if (col < N) {
            float bv = bias ? bias[col] : 0.f;
            #pragma unroll
            for (int m = 0; m < 4; ++m) {
                #pragma unroll
                for (int r = 0; r < 4; ++r) {
                    int row = bm + wr * 64 + m * 16 + r0 + r;
                    float v = acc[m][n][r] + bv;
                    if (RES) v += res[(size_t)row * N + col];
                    if (ACT == 1) v = gelu_exact(v);
                    C[(size_t)row * N + col] = v;
                }
            }
        }
    }
}

// ---- Split-bf16 MFMA GEMM (fp32-class accuracy; safe upstream of routers) ----
template<int ACT, int RES>
__global__ __launch_bounds__(256) void mfma_gemm_sp(const float* __restrict__ A,
                                                    const float* __restrict__ B,
                                                    const float* __restrict__ bias,
                                                    const float* __restrict__ res,
                                                    float* __restrict__ C,
                                                    int M, int N, int K) {
    __shared__ __align__(16) unsigned short Ah[MB * LDT];
    __shared__ __align__(16) unsigned short Al[MB * LDT];
    __shared__ __align__(16) unsigned short Bh[NB * LDT];
    __shared__ __align__(16) unsigned short Bl[NB * LDT];
    int tid = threadIdx.x;
    int bm = blockIdx.y * MB, bn = blockIdx.x * NB;
    int srow = tid >> 1, shalf = tid & 1;
    int lane = tid & 63, w = tid >> 6;
    int wr = w >> 1, wc = w & 1;
    int r0 = (lane >> 4) * 4, c0 = lane & 15;
    int kb = (lane >> 4) * 8;

    f32x4 acc[4][4] = {};

    for (int kk = 0; kk < K; kk += KB) {
        stage_tile_split(Ah, Al, A + (size_t)(bm + srow) * K + kk + shalf * 16, true, srow, shalf);
        bool bval = (bn + srow) < N;
        stage_tile_split(Bh, Bl, B + (size_t)(bn + srow) * K + kk + shalf * 16, bval, srow, shalf);
        __syncthreads();
        bf16x8 ah[4], al[4], bh[4], bl[4];
        #pragma unroll
        for (int m = 0; m < 4; ++m) {
            int o = (wr * 64 + m * 16 + c0) * LDT + kb;
            ah[m] = *reinterpret_cast<const bf16x8*>(&Ah[o]);
            al[m] = *reinterpret_cast<const bf16x8*>(&Al[o]);
        }
        #pragma unroll
        for (int n = 0; n < 4; ++n) {
            int o = (wc * 64 + n * 16 + c0) * LDT + kb;
            bh[n] = *reinterpret_cast<const bf16x8*>(&Bh[o]);
            bl[n] = *reinterpret_cast<const bf16x8*>(&Bl[o]);
        }
        #pragma unroll
        for (int m = 0; m < 4; ++m)
            #pragma unroll
            for (int n = 0; n < 4; ++n) {
                acc[m][n] = __builtin_amdgcn_mfma_f32_16x16x32_bf16(al[m], bh[n], acc[m][n], 0, 0, 0);
                acc[m][n] = __builtin_amdgcn_mfma_f32_16x16x32_bf16(ah[m], bl[n], acc[m][n], 0, 0, 0);
                acc[m][n] = __builtin_amdgcn_mfma_f32_16x16x32_bf16(ah[m], bh[n], acc[m][n], 0, 0, 0);
            }
        __syncthreads();
    }

    #pragma unroll
    for (int n = 0; n < 4; ++n) {
        int col = bn + wc * 64 + n * 16 + c0;
        if (col < N) {
            float bv = bias ? bias[col] : 0.f;
            #pragma unroll
            for (int m = 0; m < 4; ++m) {
                #pragma unroll
                for (int r = 0; r < 4; ++r) {
                    int row = bm + wr * 64 + m * 16 + r0 + r;
                    float v = acc[m][n][r] + bv;
                    if (RES) v += res[(size_t)row * N + col];
                    if (ACT == 1) v = gelu_exact(v);
                    C[(size_t)row * N + col] = v;
                }
            }
        }
    }
}

// ---------------- Causal attention (fp32) ----------------
__global__ __launch_bounds__(256) void attn_kernel(const float* __restrict__ qkv,
                                                   float* __restrict__ o) {
    int idx = blockIdx.x;
    int tq = idx % Tm; idx /= Tm;
    int hh = idx % NHm;
    int b  = idx / NHm;
    int tid = threadIdx.x;
    const int g0 = b * Tm;
    __shared__ float qs[64];
    __shared__ float s[Tm];
    __shared__ float red[256];
    __shared__ float part[4][64];

    const float* qrow = qkv + (size_t)(g0 + tq) * (3 * Dm) + hh * 64;
    if (tid < 64) qs[tid] = qrow[tid];
    __syncthreads();

    int nk = tq + 1;
    float lmax = -1e30f;
    for (int k = tid; k < nk; k += 256) {
        const float* krow = qkv + (size_t)(g0 + k) * (3 * Dm) + Dm + hh * 64;
        float dot = 0.f;
        for (int d = 0; d < 64; ++d) dot += qs[d] * krow[d];
        dot *= 0.125f;
        s[k] = dot;
        lmax = fmaxf(lmax, dot);
    }
    red[tid] = lmax;
    __syncthreads();
    for (int off = 128; off > 0; off >>= 1) {
        if (tid < off) red[tid] = fmaxf(red[tid], red[tid + off]);
        __syncthreads();
    }
    float mx = red[0];

    float lsum = 0.f;
    for (int k = tid; k < nk; k += 256) {
        float e = expf(s[k] - mx);
        s[k] = e;
        lsum += e;
    }
    __syncthreads();
    red[tid] = lsum;
    __syncthreads();
    for (int off = 128; off > 0; off >>= 1) {
        if (tid < off) red[tid] += red[tid + off];
        __syncthreads();
    }
    float inv = 1.0f / red[0];

    int grp = tid >> 6;
    int d = tid & 63;
    float acc = 0.f;
    for (int k = grp; k < nk; k += 4) {
        acc += s[k] * qkv[(size_t)(g0 + k) * (3 * Dm) + 2 * Dm + hh * 64 + d];
    }
    part[grp][d] = acc;
    __syncthreads();
    if (tid < 64) {
        float r = (part[0][tid] + part[1][tid] + part[2][tid] + part[3][tid]) * inv;
        o[(size_t)(g0 + tq) * Dm + hh * 64 + tid] = r;
    }
}

// ---------------- MoE router (fp32 exact) ----------------
__global__ __launch_bounds__(256) void router_kernel(const float* __restrict__ xn,
                                                     const float* __restrict__ gw,
                                                     int* __restrict__ topi,
                                                     float* __restrict__ topw) {
    int t = blockIdx.x * 256 + threadIdx.x;
    if (t >= NT) return;
    const float* x = xn + (size_t)t * Dm;
    float l[Em];
    #pragma unroll
    for (int e = 0; e < Em; ++e) {
        const float* w = gw + (size_t)e * Dm;
        float dot = 0.f;
        for (int d = 0; d < Dm; ++d) dot += w[d] * x[d];
        l[e] = dot;
    }
    int i1 = 0;
    #pragma unroll
    for (int e = 1; e < Em; ++e) if (l[e] > l[i1]) i1 = e;
    int i2 = (i1 == 0) ? 1 : 0;
    #pragma unroll
    for (int e = 0; e < Em; ++e) if (e != i1 && l[e] > l[i2]) i2 = e;
    float w1 = 1.0f / (1.0f + expf(l[i2] - l[i1]));
    topi[t * 2] = i1; topi[t * 2 + 1] = i2;
    topw[t * 2] = w1; topw[t * 2 + 1] = 1.0f - w1;
}

// ---------------- Route build ----------------
__global__ __launch_bounds__(256) void route_build_kernel(const int* __restrict__ topi,
                                                          int* __restrict__ g_cnt,
                                                          int* __restrict__ g_off,
                                                          int* __restrict__ bucket) {
    __shared__ int cnt[Em], off[Em], pos[Em];
    int tid = threadIdx.x;
    if (tid < Em) cnt[tid] = 0;
    __syncthreads();
    for (int ts = tid; ts < NAS; ts += 256) atomicAdd(&cnt[topi[ts]], 1);
    __syncthreads();
    if (tid == 0) {
        int acc = 0;
        for (int e = 0; e < Em; ++e) { off[e] = acc; pos[e] = acc; acc += cnt[e]; }
    }
    __syncthreads();
    for (int ts = tid; ts < NAS; ts += 256) {
        int e = topi[ts];
        int p = atomicAdd(&pos[e], 1);
        bucket[p] = ts;
    }
    if (tid < Em) { g_cnt[tid] = cnt[tid]; g_off[tid] = off[tid]; }
}

// ---------------- Grouped MoE GEMMs (MFMA). SPLIT=1 for layer-1 (router-safe),
// SPLIT=0 plain bf16 for layer-3 (downstream of all routers). ----------------
template<int SPLIT>
__global__ __launch_bounds__(256) void moe_mfma_gemm1(const float* __restrict__ xn,
                                                      const float* __restrict__ W1all,
                                                      const float* __restrict__ B1all,
                                                      const int* __restrict__ bucket,
                                                      const int* __restrict__ cnt,
                                                      const int* __restrict__ off,
                                                      float* __restrict__ heg) {
    int e = blockIdx.z;
    int count = cnt[e];
    int mbase = blockIdx.y * MB;
    if (mbase >= count) return;
    int base = off[e];

    __shared__ __align__(16) unsigned short Ah[MB * LDT];
    __shared__ __align__(16) unsigned short Bh[NB * LDT];
    __shared__ __align__(16) unsigned short Al[SPLIT ? MB * LDT : 8];
    __shared__ __align__(16) unsigned short Bl[SPLIT ? NB * LDT : 8];
    __shared__ int toks[MB];
    int tid = threadIdx.x;
    int bn = blockIdx.x * NB;
    int srow = tid >> 1, shalf = tid & 1;
    int lane = tid & 63, w = tid >> 6;
    int wr = w >> 1, wc = w & 1;
    int r0 = (lane >> 4) * 4, c0 = lane & 15;
    int kb = (lane >> 4) * 8;
    if (tid < MB) {
        int p = mbase + tid;
        toks[tid] = (p < count) ? (bucket[base + p] >> 1) : -1;
    }
    __syncthreads();

    f32x4 acc[4][4] = {};
    const float* W = W1all + (size_t)e * Hm * Dm;
    int t = toks[srow];
    for (int kk = 0; kk < Dm; kk += KB) {
        if (SPLIT) {
            stage_tile_split(Ah, Al, xn + (size_t)t * Dm + kk + shalf * 16, t >= 0, srow, shalf);
            stage_tile_split(Bh, Bl, W + (size_t)(bn + srow) * Dm + kk + shalf * 16, true, srow, shalf);
        } else {
            stage_tile(Ah, xn + (size_t)t * Dm + kk + shalf * 16, t >= 0, srow, shalf);
            stage_tile(Bh, W + (size_t)(bn + srow) * Dm + kk + shalf * 16, true, srow, shalf);
        }
        __syncthreads();
        bf16x8 ah[4], bh[4], al[4], bl[4];
        #pragma unroll
        for (int m = 0; m < 4; ++m) {
            int o = (wr * 64 + m * 16 + c0) * LDT + kb;
            ah[m] = *reinterpret_cast<const bf16x8*>(&Ah[o]);
            if (SPLIT) al[m] = *reinterpret_cast<const bf16x8*>(&Al[o]);
        }
        #pragma unroll
        for (int n = 0; n < 4; ++n) {
            int o = (wc * 64 + n * 16 + c0) * LDT + kb;
            bh[n] = *reinterpret_cast<const bf16x8*>(&Bh[o]);
            if (SPLIT) bl[n] = *reinterpret_cast<const bf16x8*>(&Bl[o]);
        }
        #pragma unroll
        for (int m = 0; m < 4; ++m)
            #pragma unroll
            for (int n = 0; n < 4; ++n) {
                if (SPLIT) {
                    acc[m][n] = __builtin_amdgcn_mfma_f32_16x16x32_bf16(al[m], bh[n], acc[m][n], 0, 0, 0);
                    acc[m][n] = __builtin_amdgcn_mfma_f32_16x16x32_bf16(ah[m], bl[n], acc[m][n], 0, 0, 0);
                }
                acc[m][n] = __builtin_amdgcn_mfma_f32_16x16x32_bf16(ah[m], bh[n], acc[m][n], 0, 0, 0);
            }
        __syncthreads();
    }

    const float* b1 = B1all + (size_t)e * Hm;
    #pragma unroll
    for (int n = 0; n < 4; ++n) {
        int col = bn + wc * 64 + n * 16 + c0;
        float bv = b1[col];
        #pragma unroll
        for (int m = 0; m < 4; ++m) {
            #pragma unroll
            for (int r = 0; r < 4; ++r) {
                int p = mbase + wr * 64 + m * 16 + r0 + r;
                if (p < count)
                    heg[(size_t)(base + p) * Hm + col] = gelu_exact(acc[m][n][r] + bv);
            }
        }
    }
}

template<int SPLIT>
__global__ __launch_bounds__(256) void moe_mfma_gemm2(const float* __restrict__ heg,
                                                      const float* __restrict__ W2all,
                                                      const float* __restrict__ B2all,
                                                      const int* __restrict__ bucket,
                                                      const int* __restrict__ cnt,
                                                      const int* __restrict__ off,
                                                      const float* __restrict__ topw,
                                                      float* __restrict__ ye) {
    int e = blockIdx.z;
    int count = cnt[e];
    int mbase = blockIdx.y * MB;
    if (mbase >= count) return;
    int base = off[e];

    __shared__ __align__(16) unsigned short Ah[MB * LDT];
    __shared__ __align__(16) unsigned short Bh[NB * LDT];
    __shared__ __align__(16) unsigned short Al[SPLIT ? MB * LDT : 8];
    __shared__ __align__(16) unsigned short Bl[SPLIT ? NB * LDT : 8];
    int tid = threadIdx.x;
    int bn = blockIdx.x * NB;
    int srow = tid >> 1, shalf = tid & 1;
    int lane = tid & 63, w = tid >> 6;
    int wr = w >> 1, wc = w & 1;
    int r0 = (lane >> 4) * 4, c0 = lane & 15;
    int kb = (lane >> 4) * 8;

    f32x4 acc[4][4] = {};
    const float* W = W2all + (size_t)e * Dm * Hm;
    bool aval = (mbase + srow) < count;
    for (int kk = 0; kk < Hm; kk += KB) {
        if (SPLIT) {
            stage_tile_split(Ah, Al, heg + (size_t)(base + mbase + srow) * Hm + kk + shalf * 16, aval, srow, shalf);
            stage_tile_split(Bh, Bl, W + (size_t)(bn + srow) * Hm + kk + shalf * 16, true, srow, shalf);
        } else {
            stage_tile(Ah, heg + (size_t)(base + mbase + srow) * Hm + kk + shalf * 16, aval, srow, shalf);
            stage_tile(Bh, W + (size_t)(bn + srow) * Hm + kk + shalf * 16, true, srow, shalf);
        }
        __syncthreads();
        bf16x8 ah[4], bh[4], al[4], bl[4];
        #pragma unroll
        for (int m = 0; m < 4; ++m) {
            int o = (wr * 64 + m * 16 + c0) * LDT + kb;
            ah[m] = *reinterpret_cast<const bf16x8*>(&Ah[o]);
            if (SPLIT) al[m] = *reinterpret_cast<const bf16x8*>(&Al[o]);
        }
        #pragma unroll
        for (int n = 0; n < 4; ++n) {
            int o = (wc * 64 + n * 16 + c0) * LDT + kb;
            bh[n] = *reinterpret_cast<const bf16x8*>(&Bh[o]);
            if (SPLIT) bl[n] = *reinterpret_cast<const bf16x8*>(&Bl[o]);
        }
        #pragma unroll
        for (int m = 0; m < 4; ++m)
            #pragma unroll
            for (int n = 0; n < 4; ++n) {
                if (SPLIT) {
                    acc[m][n] = __builtin_amdgcn_mfma_f32_16x16x32_bf16(al[m], bh[n], acc[m][n], 0, 0, 0);
                    acc[m][n] = __builtin_amdgcn_mfma_f32_16x16x32_bf16(ah[m], bl[n], acc[m][n], 0, 0, 0);
                }
                acc[m][n] = __builtin_amdgcn_mfma_f32_16x16x32_bf16(ah[m], bh[n], acc[m][n], 0, 0, 0);
            }
        __syncthreads();
    }

    const float* b2 = B2all + (size_t)e * Dm;
    #pragma unroll
    for (int n = 0; n < 4; ++n) {
        int col = bn + wc * 64 + n * 16 + c0;
        float bv = b2[col];
        #pragma unroll
        for (int m = 0; m < 4; ++m) {
            #pragma unroll
            for (int r = 0; r < 4; ++r) {
                int p = mbase + wr * 64 + m * 16 + r0 + r;
                if (p < count) {
                    int ts = bucket[base + p];
                    ye[(size_t)ts * Dm + col] = topw[ts] * (acc[m][n][r] + bv);
                }
            }
        }
    }
}

__global__ __launch_bounds__(256) void combine_kernel(float* __restrict__ h,
                                                      const float* __restrict__ ye) {
    int i = blockIdx.x * 256 + threadIdx.x;
    if (i < NT * Dm) {
        int t = i / Dm, d = i - t * Dm;
        h[i] += ye[(size_t)(t * 2) * Dm + d] + ye[(size_t)(t * 2 + 1) * Dm + d];
    }
}

// ---------------- Launch ----------------
extern "C" void kernel_launch(void* const* d_in, const int* in_sizes, int n_in,
                              void* d_out, int out_size, void* d_ws, size_t ws_size,
                              hipStream_t stream) {
    const int*   x    = (const int*)d_in[0];
    const float* emb  = (const float*)d_in[1];
    const float* wqkv = (const float*)d_in[2];
    const float* bqkv = (const float*)d_in[3];
    const float* wo   = (const float*)d_in[4];
    const float* bo   = (const float*)d_in[5];
    const float* ln1g = (const float*)d_in[6];
    const float* ln1b = (const float*)d_in[7];
    const float* ln2g = (const float*)d_in[8];
    const float* ln2b = (const float*)d_in[9];
    const float* sw1  = (const float*)d_in[10];
    const float* sb1  = (const float*)d_in[11];
    const float* sw2  = (const float*)d_in[12];
    const float* sb2  = (const float*)d_in[13];
    const float* gw   = (const float*)d_in[14];
    const float* mw1  = (const float*)d_in[15];
    const float* mb1  = (const float*)d_in[16];
    const float* mw2  = (const float*)d_in[17];
    const float* mb2  = (const float*)d_in[18];
    const float* lnfg = (const float*)d_in[19];
    const float* lnfb = (const float*)d_in[20];

    const size_t n_h   = (size_t)NT * Dm;
    const size_t n_qkv = (size_t)NT * 3 * Dm;
    const size_t n_ffh = (size_t)NT * Hm;
    const size_t n_ye  = (size_t)NAS * Dm;
    const size_t n_heg = (size_t)NAS * Hm;
    const size_t n_xn  = (size_t)NT * Dm;
    const size_t n_small = n_xn + NAS + NAS + NAS + 32;
    const size_t n_big   = n_h + n_qkv + n_h + n_ffh + n_ye + n_heg;

    float* w = (float*)d_ws;
    float* xn   = w;            w += n_xn;
    float* topw = w;            w += NAS;
    int*   topi = (int*)w;      w += NAS;
    int*   bucket = (int*)w;    w += NAS;
    int*   e_cnt = (int*)w;     w += 8;
    int*   e_off = (int*)w;     w += 8;

    float *h, *qkv, *attno, *ffh, *ye, *heg;
    if (ws_size >= (n_small + n_big + 64) * sizeof(float)) {
        float* a = w;
        h = a;      a += n_h;
        qkv = a;    a += n_qkv;
        attno = a;  a += n_h;
        ffh = a;    a += n_ffh;
        ye = a;     a += n_ye;
        heg = a;
    } else {
        float* a = (float*)d_out;
        h = a;      a += n_h;
        qkv = a;    a += n_qkv;
        attno = a;  a += n_h;
        ffh = a;    a += n_ffh;
        ye = a;     a += n_ye;
        heg = a;
    }

    embed_kernel<<<NT, 256, 0, stream>>>(x, emb, h);

    int std_i = 0, moe_i = 0;
    for (int l = 0; l < Lm; ++l) {
        ln_kernel<<<NT, 256, 0, stream>>>(h, ln1g + l * Dm, ln1b + l * Dm, xn);
        mfma_gemm_sp<0,0><<<dim3((3 * Dm) / NB, NT / MB), 256, 0, stream>>>(
            xn, wqkv + (size_t)l * 3 * Dm * Dm, bqkv + (size_t)l * 3 * Dm,
            nullptr, qkv, NT, 3 * Dm, Dm);
        attn_kernel<<<Bm * NHm * Tm, 256, 0, stream>>>(qkv, attno);
        mfma_gemm_sp<0,1><<<dim3(Dm / NB, NT / MB), 256, 0, stream>>>(
            attno, wo + (size_t)l * Dm * Dm, bo + (size_t)l * Dm, h, h, NT, Dm, Dm);

        ln_kernel<<<NT, 256, 0, stream>>>(h, ln2g + l * Dm, ln2b + l * Dm, xn);
        if (l == 1 || l == 3) {
            router_kernel<<<(NT + 255) / 256, 256, 0, stream>>>(
                xn, gw + (size_t)moe_i * Em * Dm, topi, topw);
            route_build_kernel<<<1, 256, 0, stream>>>(topi, e_cnt, e_off, bucket);
            if (l == 3) {
                moe_mfma_gemm1<0><<<dim3(Hm / NB, NAS / MB, Em), 256, 0, stream>>>(
                    xn, mw1 + (size_t)moe_i * Em * Hm * Dm, mb1 + (size_t)moe_i * Em * Hm,
                    bucket, e_cnt, e_off, heg);
                moe_mfma_gemm2<0><<<dim3(Dm / NB, NAS / MB, Em), 256, 0, stream>>>(
                    heg, mw2 + (size_t)moe_i * Em * Dm * Hm, mb2 + (size_t)moe_i * Em * Dm,
                    bucket, e_cnt, e_off, topw, ye);
            } else {
                moe_mfma_gemm1<1><<<dim3(Hm / NB, NAS / MB, Em), 256, 0, stream>>>(
                    xn, mw1 + (size_t)moe_i * Em * Hm * Dm, mb1 + (size_t)moe_i * Em * Hm,
                    bucket, e_cnt, e_off, heg);
                moe_mfma_gemm2<1><<<dim3(Dm / NB, NAS / MB, Em), 256, 0, stream>>>(
                    heg, mw2 + (size_t)moe_i * Em * Dm * Hm, mb2 + (size_t)moe_i * Em * Dm,
                    bucket, e_cnt, e_off, topw, ye);
            }
            combine_kernel<<<(NT * Dm) / 256, 256, 0, stream>>>(h, ye);
            moe_i++;
        } else {
            mfma_gemm_sp<1,0><<<dim3(Hm / NB, NT / MB), 256, 0, stream>>>(
                xn, sw1 + (size_t)std_i * Hm * Dm, sb1 + (size_t)std_i * Hm,
                nullptr, ffh, NT, Hm, Dm);
            mfma_gemm_sp<0,1><<<dim3(Dm / NB, NT / MB), 256, 0, stream>>>(
                ffh, sw2 + (size_t)std_i * Dm * Hm, sb2 + (size_t)std_i * Dm,
                h, h, NT, Dm, Hm);
            std_i++;
        }
    }

    ln_kernel<<<NT, 256, 0, stream>>>(h, lnfg, lnfb, xn);
    mfma_gemm<0,0><<<dim3((Vm + NB - 1) / NB, NT / MB), 256, 0, stream>>>(
        xn, emb, nullptr, nullptr, (float*)d_out, NT, Vm, Dm);
}

// Round 9
// 2962.313 us; speedup vs baseline: 4.3680x; 1.0595x over previous
//
#include <hip/hip_runtime.h>
#include <hip/hip_bf16.h>
#include <cstdint>
#include <cstddef>

// ---- Model constants ----
#define Dm   768
#define NHm  12
#define Lm   4
#define Em   8
#define Vm   50257
#define Hm   3072
#define Tm   512
#define Bm   2
#define NT   (Bm*Tm)      // 1024 tokens
#define NAS  (NT*2)       // 2048 expert assignments

typedef float f32x4 __attribute__((ext_vector_type(4)));
typedef short bf16x8 __attribute__((ext_vector_type(8)));

__device__ __forceinline__ float gelu_exact(float x) {
    return 0.5f * x * (1.0f + erff(x * 0.70710678118654752440f));
}

// fp32 -> bf16 bits via compiler cast (lets hipcc emit v_cvt_pk_bf16_f32)
__device__ __forceinline__ unsigned short f2bf(float f) {
    __hip_bfloat16 h = __float2bfloat16(f);
    union { __hip_bfloat16 h; unsigned short s; } c; c.h = h; return c.s;
}
__device__ __forceinline__ float bf2f_bits(unsigned short b) {
    union { unsigned u; float f; } c; c.u = ((unsigned)b) << 16; return c.f;
}

// ---------------- fp32 -> bf16 bulk convert ----------------
__global__ __launch_bounds__(256) void cvt_bf16_kernel(const float* __restrict__ in,
                                                       unsigned short* __restrict__ out,
                                                       long n) {
    long i = ((long)blockIdx.x * 256 + threadIdx.x) * 8;
    if (i + 8 <= n) {
        const float4* s4 = reinterpret_cast<const float4*>(in + i);
        float4 f0 = s4[0], f1 = s4[1];
        union { unsigned short s[8]; uint4 v; } p;
        p.s[0] = f2bf(f0.x); p.s[1] = f2bf(f0.y); p.s[2] = f2bf(f0.z); p.s[3] = f2bf(f0.w);
        p.s[4] = f2bf(f1.x); p.s[5] = f2bf(f1.y); p.s[6] = f2bf(f1.z); p.s[7] = f2bf(f1.w);
        *reinterpret_cast<uint4*>(out + i) = p.v;
    } else {
        for (long j = i; j < n; ++j) out[j] = f2bf(in[j]);
    }
}

// ---------------- Embedding + sinusoidal PE ----------------
__global__ __launch_bounds__(256) void embed_kernel(const int* __restrict__ x,
                                                    const float* __restrict__ emb,
                                                    float* __restrict__ h) {
    int g = blockIdx.x;
    int tid = threadIdx.x;
    int tok = x[g];
    int pos = g % Tm;
    const float* erow = emb + (size_t)tok * Dm;
    for (int d = tid; d < Dm; d += 256) {
        int i2 = (d >> 1) * 2;
        float div = expf(-logf(10000.0f) * (float)i2 / (float)Dm);
        float a = (float)pos * div;
        float pe = (d & 1) ? cosf(a) : sinf(a);
        h[(size_t)g * Dm + d] = erow[d] + pe;
    }
}

// ---------------- LayerNorm ----------------
__global__ __launch_bounds__(256) void ln_kernel(const float* __restrict__ in,
                                                 const float* __restrict__ g,
                                                 const float* __restrict__ b,
                                                 float* __restrict__ out) {
    int t = blockIdx.x, tid = threadIdx.x;
    const float* x = in + (size_t)t * Dm;
    float v0 = x[tid], v1 = x[tid + 256], v2 = x[tid + 512];
    __shared__ float red[256];
    red[tid] = v0 + v1 + v2;
    __syncthreads();
    for (int off = 128; off > 0; off >>= 1) {
        if (tid < off) red[tid] += red[tid + off];
        __syncthreads();
    }
    float mean = red[0] * (1.0f / Dm);
    __syncthreads();
    float d0 = v0 - mean, d1 = v1 - mean, d2 = v2 - mean;
    red[tid] = d0 * d0 + d1 * d1 + d2 * d2;
    __syncthreads();
    for (int off = 128; off > 0; off >>= 1) {
        if (tid < off) red[tid] += red[tid + off];
        __syncthreads();
    }
    float inv = rsqrtf(red[0] * (1.0f / Dm) + 1e-5f);
    float* o = out + (size_t)t * Dm;
    o[tid]       = d0 * inv * g[tid]       + b[tid];
    o[tid + 256] = d1 * inv * g[tid + 256] + b[tid + 256];
    o[tid + 512] = d2 * inv * g[tid + 512] + b[tid + 512];
}

// ============ MFMA GEMM machinery ============
#define MB 128
#define NB 128
#define KB 32
#define LDT 40

__device__ __forceinline__ void stage_tile(unsigned short* lds, const float* src,
                                           bool valid, int srow, int shalf) {
    union { unsigned short s[8]; uint4 v; } p0, p1;
    if (valid) {
        const float4* s4 = reinterpret_cast<const float4*>(src);
        #pragma unroll
        for (int q = 0; q < 4; ++q) {
            float4 f = s4[q];
            float vv[4] = {f.x, f.y, f.z, f.w};
            #pragma unroll
            for (int j = 0; j < 4; ++j) {
                int idx = q * 4 + j;
                unsigned short hb = f2bf(vv[j]);
                if (idx < 8) p0.s[idx] = hb; else p1.s[idx - 8] = hb;
            }
        }
    } else {
        p0.v = make_uint4(0, 0, 0, 0);
        p1.v = make_uint4(0, 0, 0, 0);
    }
    uint4* dst = reinterpret_cast<uint4*>(&lds[srow * LDT + shalf * 16]);
    dst[0] = p0.v; dst[1] = p1.v;
}

__device__ __forceinline__ void stage_tile_split(unsigned short* lds_hi,
                                                 unsigned short* lds_lo,
                                                 const float* src,
                                                 bool valid, int srow, int shalf) {
    union { unsigned short s[8]; uint4 v; } h0, h1, l0, l1;
    if (valid) {
        const float4* s4 = reinterpret_cast<const float4*>(src);
        #pragma unroll
        for (int q = 0; q < 4; ++q) {
            float4 f = s4[q];
            float vv[4] = {f.x, f.y, f.z, f.w};
            #pragma unroll
            for (int j = 0; j < 4; ++j) {
                int idx = q * 4 + j;
                unsigned short hb = f2bf(vv[j]);
                unsigned short lb = f2bf(vv[j] - bf2f_bits(hb));
                if (idx < 8) { h0.s[idx] = hb; l0.s[idx] = lb; }
                else         { h1.s[idx - 8] = hb; l1.s[idx - 8] = lb; }
            }
        }
    } else {
        h0.v = make_uint4(0,0,0,0); h1.v = make_uint4(0,0,0,0);
        l0.v = make_uint4(0,0,0,0); l1.v = make_uint4(0,0,0,0);
    }
    uint4* dh = reinterpret_cast<uint4*>(&lds_hi[srow * LDT + shalf * 16]);
    dh[0] = h0.v; dh[1] = h1.v;
    uint4* dl = reinterpret_cast<uint4*>(&lds_lo[srow * LDT + shalf * 16]);
    dl[0] = l0.v; dl[1] = l1.v;
}

// ---- Lean all-bf16 MFMA GEMM with register prefetch (logits) ----
// A bf16 [M,K], B bf16 [N,K]; M%128==0, K%32==0; N guarded. C fp32.
__global__ __launch_bounds__(256) void mfma_gemm_bf(const unsigned short* __restrict__ A,
                                                    const unsigned short* __restrict__ B,
                                                    const float* __restrict__ bias,
                                                    float* __restrict__ C,
                                                    int M, int N, int K) {
    __shared__ __align__(16) unsigned short As[MB * LDT];
    __shared__ __align__(16) unsigned short Bs[NB * LDT];
    int tid = threadIdx.x;
    int bm = blockIdx.y * MB, bn = blockIdx.x * NB;
    int srow = tid >> 1, shalf = tid & 1;
    int lane = tid & 63, w = tid >> 6;
    int wr = w >> 1, wc = w & 1;
    int r0 = (lane >> 4) * 4, c0 = lane & 15;
    int kb = (lane >> 4) * 8;

    bool bval = (bn + srow) < N;
    const unsigned short* Ap = A + (size_t)(bm + srow) * K + shalf * 16;
    const unsigned short* Bp = B + (size_t)(bn + srow) * K + shalf * 16;

    uint4 ra0, ra1, rb0, rb1;
    ra0 = reinterpret_cast<const uint4*>(Ap)[0];
    ra1 = reinterpret_cast<const uint4*>(Ap)[1];
    rb0 = make_uint4(0,0,0,0); rb1 = make_uint4(0,0,0,0);
    if (bval) {
        rb0 = reinterpret_cast<const uint4*>(Bp)[0];
        rb1 = reinterpret_cast<const uint4*>(Bp)[1];
    }

    f32x4 acc[4][4] = {};

    for (int kk = 0; kk < K; kk += KB) {
        uint4* da = reinterpret_cast<uint4*>(&As[srow * LDT + shalf * 16]);
        da[0] = ra0; da[1] = ra1;
        uint4* db = reinterpret_cast<uint4*>(&Bs[srow * LDT + shalf * 16]);
        db[0] = rb0; db[1] = rb1;
        __syncthreads();
        if (kk + KB < K) {   // prefetch next tile while MFMA runs
            const uint4* na = reinterpret_cast<const uint4*>(Ap + kk + KB);
            ra0 = na[0]; ra1 = na[1];
            if (bval) {
                const uint4* nb = reinterpret_cast<const uint4*>(Bp + kk + KB);
                rb0 = nb[0]; rb1 = nb[1];
            }
        }
        bf16x8 af[4], bf[4];
        #pragma unroll
        for (int m = 0; m < 4; ++m)
            af[m] = *reinterpret_cast<const bf16x8*>(&As[(wr * 64 + m * 16 + c0) * LDT + kb]);
        #pragma unroll
        for (int n = 0; n < 4; ++n)
            bf[n] = *reinterpret_cast<const bf16x8*>(&Bs[(wc * 64 + n * 16 + c0) * LDT + kb]);
        #pragma unroll
        for (int m = 0; m < 4; ++m)
            #pragma unroll
            for (int n = 0; n < 4; ++n)
                acc[m][n] = __builtin_amdgcn_mfma_f32_16x16x32_bf16(af[m], bf[n], acc[m][n], 0, 0, 0);
        __syncthreads();
    }

    #pragma unroll
    for (int n = 0; n < 4; ++n) {
        int col = bn + wc * 64 + n * 16 + c0;
        if (col < N) {
            float bv = bias ? bias[col] : 0.f;
            #pragma unroll
            for (int m = 0; m < 4; ++m)
                #pragma unroll
                for (int r = 0; r < 4; ++r) {
                    int row = bm + wr * 64 + m * 16 + r0 + r;
                    C[(size_t)row * N + col] = acc[m][n][r] + bv;
                }
        }
    }
}

// ---- Plain bf16 MFMA GEMM from fp32 sources (fallback logits path) ----
template<int ACT, int RES>
__global__ __launch_bounds__(256) void mfma_gemm(const float* __restrict__ A,
                                                 const float* __restrict__ B,
                                                 const float* __restrict__ bias,
                                                 const float* __restrict__ res,
                                                 float* __restrict__ C,
                                                 int M, int N, int K) {
    __shared__ __align__(16) unsigned short As[MB * LDT];
    __shared__ __align__(16) unsigned short Bs[NB * LDT];
    int tid = threadIdx.x;
    int bm = blockIdx.y * MB, bn = blockIdx.x * NB;
    int srow = tid >> 1, shalf = tid & 1;
    int lane = tid & 63, w = tid >> 6;
    int wr = w >> 1, wc = w & 1;
    int r0 = (lane >> 4) * 4, c0 = lane & 15;
    int kb = (lane >> 4) * 8;

    f32x4 acc[4][4] = {};

    for (int kk = 0; kk < K; kk += KB) {
        stage_tile(As, A + (size_t)(bm + srow) * K + kk + shalf * 16, true, srow, shalf);
        bool bval = (bn + srow) < N;
        stage_tile(Bs, B + (size_t)(bn + srow) * K + kk + shalf * 16, bval, srow, shalf);
        __syncthreads();
        bf16x8 af[4], bf[4];
        #pragma unroll
        for (int m = 0; m < 4; ++m)
            af[m] = *reinterpret_cast<const bf16x8*>(&As[(wr * 64 + m * 16 + c0) * LDT + kb]);
        #pragma unroll
        for (int n = 0; n < 4; ++n)
            bf[n] = *reinterpret_cast<const bf16x8*>(&Bs[(wc * 64 + n * 16 + c0) * LDT + kb]);
        #pragma unroll
        for (int m = 0; m < 4; ++m)
            #pragma unroll
            for (int n = 0; n < 4; ++n)
                acc[m][n] = __builtin_amdgcn_mfma_f32_16x16x32_bf16(af[m], bf[n], acc[m][n], 0, 0, 0);
        __syncthreads();
    }

    #pragma unroll
    for (int n = 0; n < 4; ++n) {
        int col = bn + wc * 64 + n * 16 + c0;
        if (col < N) {
            float bv = bias ? bias[col] : 0.f;
            #pragma unroll
            for (int m = 0; m < 4; ++m) {
                #pragma unroll
                for (int r = 0; r < 4; ++r) {
                    int row = bm + wr * 64 + m * 16 + r0 + r;
                    float v = acc[m][n][r] + bv;
                    if (RES) v += res[(size_t)row * N + col];
                    if (ACT == 1) v = gelu_exact(v);
                    C[(size_t)row * N + col] = v;
                }
            }
        }
    }
}

// ---- Split-bf16 MFMA GEMM (fp32-class accuracy; upstream of routers) ----
template<int ACT, int RES>
__global__ __launch_bounds__(256) void mfma_gemm_sp(const float* __restrict__ A,
                                                    const float* __restrict__ B,
                                                    const float* __restrict__ bias,
                                                    const float* __restrict__ res,
                                                    float* __restrict__ C,
                                                    int M, int N, int K) {
    __shared__ __align__(16) unsigned short Ah[MB * LDT];
    __shared__ __align__(16) unsigned short Al[MB * LDT];
    __shared__ __align__(16) unsigned short Bh[NB * LDT];
    __shared__ __align__(16) unsigned short Bl[NB * LDT];
    int tid = threadIdx.x;
    int bm = blockIdx.y * MB, bn = blockIdx.x * NB;
    int srow = tid >> 1, shalf = tid & 1;
    int lane = tid & 63, w = tid >> 6;
    int wr = w >> 1, wc = w & 1;
    int r0 = (lane >> 4) * 4, c0 = lane & 15;
    int kb = (lane >> 4) * 8;

    f32x4 acc[4][4] = {};

    for (int kk = 0; kk < K; kk += KB) {
        stage_tile_split(Ah, Al, A + (size_t)(bm + srow) * K + kk + shalf * 16, true, srow, shalf);
        bool bval = (bn + srow) < N;
        stage_tile_split(Bh, Bl, B + (size_t)(bn + srow) * K + kk + shalf * 16, bval, srow, shalf);
        __syncthreads();
        bf16x8 ah[4], al[4], bh[4], bl[4];
        #pragma unroll
        for (int m = 0; m < 4; ++m) {
            int o = (wr * 64 + m * 16 + c0) * LDT + kb;
            ah[m] = *reinterpret_cast<const bf16x8*>(&Ah[o]);
            al[m] = *reinterpret_cast<const bf16x8*>(&Al[o]);
        }
        #pragma unroll
        for (int n = 0; n < 4; ++n) {
            int o = (wc * 64 + n * 16 + c0) * LDT + kb;
            bh[n] = *reinterpret_cast<const bf16x8*>(&Bh[o]);
            bl[n] = *reinterpret_cast<const bf16x8*>(&Bl[o]);
        }
        #pragma unroll
        for (int m = 0; m < 4; ++m)
            #pragma unroll
            for (int n = 0; n < 4; ++n) {
                acc[m][n] = __builtin_amdgcn_mfma_f32_16x16x32_bf16(al[m], bh[n], acc[m][n], 0, 0, 0);
                acc[m][n] = __builtin_amdgcn_mfma_f32_16x16x32_bf16(ah[m], bl[n], acc[m][n], 0, 0, 0);
                acc[m][n] = __builtin_amdgcn_mfma_f32_16x16x32_bf16(ah[m], bh[n], acc[m][n], 0, 0, 0);
            }
        __syncthreads();
    }

    #pragma unroll
    for (int n = 0; n < 4; ++n) {
        int col = bn + wc * 64 + n * 16 + c0;
        if (col < N) {
            float bv = bias ? bias[col] : 0.f;
            #pragma unroll
            for (int m = 0; m < 4; ++m) {
                #pragma unroll
                for (int r = 0; r < 4; ++r) {
                    int row = bm + wr * 64 + m * 16 + r0 + r;
                    float v = acc[m][n][r] + bv;
                    if (RES) v += res[(size_t)row * N + col];
                    if (ACT == 1) v = gelu_exact(v);
                    C[(size_t)row * N + col] = v;
                }
            }
        }
    }
}

// ---------------- Causal attention (fp32), shuffle reductions + float4 ----------------
__global__ __launch_bounds__(256) void attn_kernel(const float* __restrict__ qkv,
                                                   float* __restrict__ o) {
    int idx = blockIdx.x;
    int tq = idx % Tm; idx /= Tm;
    int hh = idx % NHm;
    int b  = idx / NHm;
    int tid = threadIdx.x;
    const int g0 = b * Tm;
    __shared__ float qs[64];
    __shared__ float s[Tm];
    __shared__ float red[4];
    __shared__ float part[4][64];

    const float* qrow = qkv + (size_t)(g0 + tq) * (3 * Dm) + hh * 64;
    if (tid < 64) qs[tid] = qrow[tid];
    __syncthreads();

    int nk = tq + 1;
    const float4* q4 = reinterpret_cast<const float4*>(qs);
    float lmax = -1e30f;
    for (int k = tid; k < nk; k += 256) {
        const float4* kr = reinterpret_cast<const float4*>(
            qkv + (size_t)(g0 + k) * (3 * Dm) + Dm + hh * 64);
        float dot = 0.f;
        #pragma unroll
        for (int d = 0; d < 16; ++d) {
            float4 kv = kr[d], qv = q4[d];
            dot += qv.x * kv.x + qv.y * kv.y + qv.z * kv.z + qv.w * kv.w;
        }
        dot *= 0.125f;
        s[k] = dot;
        lmax = fmaxf(lmax, dot);
    }
    #pragma unroll
    for (int off = 32; off > 0; off >>= 1) lmax = fmaxf(lmax, __shfl_xor(lmax, off));
    if ((tid & 63) == 0) red[tid >> 6] = lmax;
    __syncthreads();
    float mx = fmaxf(fmaxf(red[0], red[1]), fmaxf(red[2], red[3]));

    float lsum = 0.f;
    for (int k = tid; k < nk; k += 256) {
        float e = expf(s[k] - mx);
        s[k] = e;
        lsum += e;
    }
    #pragma unroll
    for (int off = 32; off > 0; off >>= 1) lsum += __shfl_xor(lsum, off);
    __syncthreads();              // mx reads done; s writes visible
    if ((tid & 63) == 0) red[tid >> 6] = lsum;
    __syncthreads();
    float inv = 1.0f / (red[0] + red[1] + red[2] + red[3]);

    int grp = tid >> 6;
    int d = tid & 63;
    float acc = 0.f;
    for (int k = grp; k < nk; k += 4) {
        acc += s[k] * qkv[(size_t)(g0 + k) * (3 * Dm) + 2 * Dm + hh * 64 + d];
    }
    part[grp][d] = acc;
    __syncthreads();
    if (tid < 64) {
        float r = (part[0][tid] + part[1][tid] + part[2][tid] + part[3][tid]) * inv;
        o[(size_t)(g0 + tq) * Dm + hh * 64 + tid] = r;
    }
}

// ---------------- MoE router (fp32 exact) ----------------
__global__ __launch_bounds__(256) void router_kernel(const float* __restrict__ xn,
                                                     const float* __restrict__ gw,
                                                     int* __restrict__ topi,
                                                     float* __restrict__ topw) {
    int t = blockIdx.x * 256 + threadIdx.x;
    if (t >= NT) return;
    const float* x = xn + (size_t)t * Dm;
    float l[Em];
    #pragma unroll
    for (int e = 0; e < Em; ++e) {
        const float* w = gw + (size_t)e * Dm;
        float dot = 0.f;
        for (int d = 0; d < Dm; ++d) dot += w[d] * x[d];
        l[e] = dot;
    }
    int i1 = 0;
    #pragma unroll
    for (int e = 1; e < Em; ++e) if (l[e] > l[i1]) i1 = e;
    int i2 = (i1 == 0) ? 1 : 0;
    #pragma unroll
    for (int e = 0; e < Em; ++e) if (e != i1 && l[e] > l[i2]) i2 = e;
    float w1 = 1.0f / (1.0f + expf(l[i2] - l[i1]));
    topi[t * 2] = i1; topi[t * 2 + 1] = i2;
    topw[t * 2] = w1; topw[t * 2 + 1] = 1.0f - w1;
}

// ---------------- Route build ----------------
__global__ __launch_bounds__(256) void route_build_kernel(const int* __restrict__ topi,
                                                          int* __restrict__ g_cnt,
                                                          int* __restrict__ g_off,
                                                          int* __restrict__ bucket) {
    __shared__ int cnt[Em], off[Em], pos[Em];
    int tid = threadIdx.x;
    if (tid < Em) cnt[tid] = 0;
    __syncthreads();
    for (int ts = tid; ts < NAS; ts += 256) atomicAdd(&cnt[topi[ts]], 1);
    __syncthreads();
    if (tid == 0) {
        int acc = 0;
        for (int e = 0; e < Em; ++e) { off[e] = acc; pos[e] = acc; acc += cnt[e]; }
    }
    __syncthreads();
    for (int ts = tid; ts < NAS; ts += 256) {
        int e = topi[ts];
        int p = atomicAdd(&pos[e], 1);
        bucket[p] = ts;
    }
    if (tid < Em) { g_cnt[tid] = cnt[tid]; g_off[tid] = off[tid]; }
}

// ---------------- Grouped MoE GEMMs (MFMA), SPLIT template ----------------
template<int SPLIT>
__global__ __launch_bounds__(256) void moe_mfma_gemm1(const float* __restrict__ xn,
                                                      const float* __restrict__ W1all,
                                                      const float* __restrict__ B1all,
                                                      const int* __restrict__ bucket,
                                                      const int* __restrict__ cnt,
                                                      const int* __restrict__ off,
                                                      float* __restrict__ heg) {
    int e = blockIdx.z;
    int count = cnt[e];
    int mbase = blockIdx.y * MB;
    if (mbase >= count) return;
    int base = off[e];

    __shared__ __align__(16) unsigned short Ah[MB * LDT];
    __shared__ __align__(16) unsigned short Bh[NB * LDT];
    __shared__ __align__(16) unsigned short Al[SPLIT ? MB * LDT : 8];
    __shared__ __align__(16) unsigned short Bl[SPLIT ? NB * LDT : 8];
    __shared__ int toks[MB];
    int tid = threadIdx.x;
    int bn = blockIdx.x * NB;
    int srow = tid >> 1, shalf = tid & 1;
    int lane = tid & 63, w = tid >> 6;
    int wr = w >> 1, wc = w & 1;
    int r0 = (lane >> 4) * 4, c0 = lane & 15;
    int kb = (lane >> 4) * 8;
    if (tid < MB) {
        int p = mbase + tid;
        toks[tid] = (p < count) ? (bucket[base + p] >> 1) : -1;
    }
    __syncthreads();

    f32x4 acc[4][4] = {};
    const float* W = W1all + (size_t)e * Hm * Dm;
    int t = toks[srow];
    for (int kk = 0; kk < Dm; kk += KB) {
        if (SPLIT) {
            stage_tile_split(Ah, Al, xn + (size_t)t * Dm + kk + shalf * 16, t >= 0, srow, shalf);
            stage_tile_split(Bh, Bl, W + (size_t)(bn + srow) * Dm + kk + shalf * 16, true, srow, shalf);
        } else {
            stage_tile(Ah, xn + (size_t)t * Dm + kk + shalf * 16, t >= 0, srow, shalf);
            stage_tile(Bh, W + (size_t)(bn + srow) * Dm + kk + shalf * 16, true, srow, shalf);
        }
        __syncthreads();
        bf16x8 ah[4], bh[4], al[4], bl[4];
        #pragma unroll
        for (int m = 0; m < 4; ++m) {
            int o = (wr * 64 + m * 16 + c0) * LDT + kb;
            ah[m] = *reinterpret_cast<const bf16x8*>(&Ah[o]);
            if (SPLIT) al[m] = *reinterpret_cast<const bf16x8*>(&Al[o]);
        }
        #pragma unroll
        for (int n = 0; n < 4; ++n) {
            int o = (wc * 64 + n * 16 + c0) * LDT + kb;
            bh[n] = *reinterpret_cast<const bf16x8*>(&Bh[o]);
            if (SPLIT) bl[n] = *reinterpret_cast<const bf16x8*>(&Bl[o]);
        }
        #pragma unroll
        for (int m = 0; m < 4; ++m)
            #pragma unroll
            for (int n = 0; n < 4; ++n) {
                if (SPLIT) {
                    acc[m][n] = __builtin_amdgcn_mfma_f32_16x16x32_bf16(al[m], bh[n], acc[m][n], 0, 0, 0);
                    acc[m][n] = __builtin_amdgcn_mfma_f32_16x16x32_bf16(ah[m], bl[n], acc[m][n], 0, 0, 0);
                }
                acc[m][n] = __builtin_amdgcn_mfma_f32_16x16x32_bf16(ah[m], bh[n], acc[m][n], 0, 0, 0);
            }
        __syncthreads();
    }

    const float* b1 = B1all + (size_t)e * Hm;
    #pragma unroll
    for (int n = 0; n < 4; ++n) {
        int col = bn + wc * 64 + n * 16 + c0;
        float bv = b1[col];
        #pragma unroll
        for (int m = 0; m < 4; ++m) {
            #pragma unroll
            for (int r = 0; r < 4; ++r) {
                int p = mbase + wr * 64 + m * 16 + r0 + r;
                if (p < count)
                    heg[(size_t)(base + p) * Hm + col] = gelu_exact(acc[m][n][r] + bv);
            }
        }
    }
}

template<int SPLIT>
__global__ __launch_bounds__(256) void moe_mfma_gemm2(const float* __restrict__ heg,
                                                      const float* __restrict__ W2all,
                                                      const float* __restrict__ B2all,
                                                      const int* __restrict__ bucket,
                                                      const int* __restrict__ cnt,
                                                      const int* __restrict__ off,
                                                      const float* __restrict__ topw,
                                                      float* __restrict__ ye) {
    int e = blockIdx.z;
    int count = cnt[e];
    int mbase = blockIdx.y * MB;
    if (mbase >= count) return;
    int base = off[e];

    __shared__ __align__(16) unsigned short Ah[MB * LDT];
    __shared__ __align__(16) unsigned short Bh[NB * LDT];
    __shared__ __align__(16) unsigned short Al[SPLIT ? MB * LDT : 8];
    __shared__ __align__(16) unsigned short Bl[SPLIT ? NB * LDT : 8];
    int tid = threadIdx.x;
    int bn = blockIdx.x * NB;
    int srow = tid >> 1, shalf = tid & 1;
    int lane = tid & 63, w = tid >> 6;
    int wr = w >> 1, wc = w & 1;
    int r0 = (lane >> 4) * 4, c0 = lane & 15;
    int kb = (lane >> 4) * 8;

    f32x4 acc[4][4] = {};
    const float* W = W2all + (size_t)e * Dm * Hm;
    bool aval = (mbase + srow) < count;
    for (int kk = 0; kk < Hm; kk += KB) {
        if (SPLIT) {
            stage_tile_split(Ah, Al, heg + (size_t)(base + mbase + srow) * Hm + kk + shalf * 16, aval, srow, shalf);
            stage_tile_split(Bh, Bl, W + (size_t)(bn + srow) * Hm + kk + shalf * 16, true, srow, shalf);
        } else {
            stage_tile(Ah, heg + (size_t)(base + mbase + srow) * Hm + kk + shalf * 16, aval, srow, shalf);
            stage_tile(Bh, W + (size_t)(bn + srow) * Hm + kk + shalf * 16, true, srow, shalf);
        }
        __syncthreads();
        bf16x8 ah[4], bh[4], al[4], bl[4];
        #pragma unroll
        for (int m = 0; m < 4; ++m) {
            int o = (wr * 64 + m * 16 + c0) * LDT + kb;
            ah[m] = *reinterpret_cast<const bf16x8*>(&Ah[o]);
            if (SPLIT) al[m] = *reinterpret_cast<const bf16x8*>(&Al[o]);
        }
        #pragma unroll
        for (int n = 0; n < 4; ++n) {
            int o = (wc * 64 + n * 16 + c0) * LDT + kb;
            bh[n] = *reinterpret_cast<const bf16x8*>(&Bh[o]);
            if (SPLIT) bl[n] = *reinterpret_cast<const bf16x8*>(&Bl[o]);
        }
        #pragma unroll
        for (int m = 0; m < 4; ++m)
            #pragma unroll
            for (int n = 0; n < 4; ++n) {
                if (SPLIT) {
                    acc[m][n] = __builtin_amdgcn_mfma_f32_16x16x32_bf16(al[m], bh[n], acc[m][n], 0, 0, 0);
                    acc[m][n] = __builtin_amdgcn_mfma_f32_16x16x32_bf16(ah[m], bl[n], acc[m][n], 0, 0, 0);
                }
                acc[m][n] = __builtin_amdgcn_mfma_f32_16x16x32_bf16(ah[m], bh[n], acc[m][n], 0, 0, 0);
            }
        __syncthreads();
    }

    const float* b2 = B2all + (size_t)e * Dm;
    #pragma unroll
    for (int n = 0; n < 4; ++n) {
        int col = bn + wc * 64 + n * 16 + c0;
        float bv = b2[col];
        #pragma unroll
        for (int m = 0; m < 4; ++m) {
            #pragma unroll
            for (int r = 0; r < 4; ++r) {
                int p = mbase + wr * 64 + m * 16 + r0 + r;
                if (p < count) {
                    int ts = bucket[base + p];
                    ye[(size_t)ts * Dm + col] = topw[ts] * (acc[m][n][r] + bv);
                }
            }
        }
    }
}

__global__ __launch_bounds__(256) void combine_kernel(float* __restrict__ h,
                                                      const float* __restrict__ ye) {
    int i = blockIdx.x * 256 + threadIdx.x;
    if (i < NT * Dm) {
        int t = i / Dm, d = i - t * Dm;
        h[i] += ye[(size_t)(t * 2) * Dm + d] + ye[(size_t)(t * 2 + 1) * Dm + d];
    }
}

// ---------------- Launch ----------------
extern "C" void kernel_launch(void* const* d_in, const int* in_sizes, int n_in,
                              void* d_out, int out_size, void* d_ws, size_t ws_size,
                              hipStream_t stream) {
    const int*   x    = (const int*)d_in[0];
    const float* emb  = (const float*)d_in[1];
    const float* wqkv = (const float*)d_in[2];
    const float* bqkv = (const float*)d_in[3];
    const float* wo   = (const float*)d_in[4];
    const float* bo   = (const float*)d_in[5];
    const float* ln1g = (const float*)d_in[6];
    const float* ln1b = (const float*)d_in[7];
    const float* ln2g = (const float*)d_in[8];
    const float* ln2b = (const float*)d_in[9];
    const float* sw1  = (const float*)d_in[10];
    const float* sb1  = (const float*)d_in[11];
    const float* sw2  = (const float*)d_in[12];
    const float* sb2  = (const float*)d_in[13];
    const float* gw   = (const float*)d_in[14];
    const float* mw1  = (const float*)d_in[15];
    const float* mb1  = (const float*)d_in[16];
    const float* mw2  = (const float*)d_in[17];
    const float* mb2  = (const float*)d_in[18];
    const float* lnfg = (const float*)d_in[19];
    const float* lnfb = (const float*)d_in[20];

    const size_t n_h   = (size_t)NT * Dm;
    const size_t n_qkv = (size_t)NT * 3 * Dm;
    const size_t n_ffh = (size_t)NT * Hm;
    const size_t n_ye  = (size_t)NAS * Dm;
    const size_t n_heg = (size_t)NAS * Hm;
    const size_t n_xn  = (size_t)NT * Dm;
    const size_t n_embbf = (size_t)Vm * Dm / 2;   // bf16, counted in float slots
    const size_t n_xnbf  = (size_t)NT * Dm / 2;
    const size_t n_big   = n_h + n_qkv + n_h + n_ffh + n_ye + n_heg;

    size_t wsf = ws_size / sizeof(float);

    float* w = (float*)d_ws;
    float* xn   = w;            w += n_xn;
    float* topw = w;            w += NAS;
    int*   topi = (int*)w;      w += NAS;
    int*   bucket = (int*)w;    w += NAS;
    int*   e_cnt = (int*)w;     w += 8;
    int*   e_off = (int*)w;     w += 8;
    size_t used = (size_t)(w - (float*)d_ws);

    // Tier B: bf16 conversion buffers in d_ws (enables lean logits GEMM)
    unsigned short* emb_bf = nullptr;
    unsigned short* xn_bf  = nullptr;
    if (wsf >= used + n_embbf + n_xnbf + 64) {
        emb_bf = (unsigned short*)w;  w += n_embbf;
        xn_bf  = (unsigned short*)w;  w += n_xnbf;
        used = (size_t)(w - (float*)d_ws);
    }

    // Tier A: activation arena also in d_ws; else in front of d_out.
    float *h, *qkv, *attno, *ffh, *ye, *heg;
    if (wsf >= used + n_big + 64) {
        float* a = w;
        h = a;      a += n_h;
        qkv = a;    a += n_qkv;
        attno = a;  a += n_h;
        ffh = a;    a += n_ffh;
        ye = a;     a += n_ye;
        heg = a;
    } else {
        float* a = (float*)d_out;
        h = a;      a += n_h;
        qkv = a;    a += n_qkv;
        attno = a;  a += n_h;
        ffh = a;    a += n_ffh;
        ye = a;     a += n_ye;
        heg = a;
    }

    // One-time: embedding table -> bf16 (reused by logits GEMM; lives in d_ws,
    // so no overlap with the final full-d_out write).
    if (emb_bf) {
        long n = (long)Vm * Dm;
        cvt_bf16_kernel<<<(unsigned)((n / 8 + 255) / 256), 256, 0, stream>>>(emb, emb_bf, n);
    }

    embed_kernel<<<NT, 256, 0, stream>>>(x, emb, h);

    int std_i = 0, moe_i = 0;
    for (int l = 0; l < Lm; ++l) {
        ln_kernel<<<NT, 256, 0, stream>>>(h, ln1g + l * Dm, ln1b + l * Dm, xn);
        mfma_gemm_sp<0,0><<<dim3((3 * Dm) / NB, NT / MB), 256, 0, stream>>>(
            xn, wqkv + (size_t)l * 3 * Dm * Dm, bqkv + (size_t)l * 3 * Dm,
            nullptr, qkv, NT, 3 * Dm, Dm);
        attn_kernel<<<Bm * NHm * Tm, 256, 0, stream>>>(qkv, attno);
        mfma_gemm_sp<0,1><<<dim3(Dm / NB, NT / MB), 256, 0, stream>>>(
            attno, wo + (size_t)l * Dm * Dm, bo + (size_t)l * Dm, h, h, NT, Dm, Dm);

        ln_kernel<<<NT, 256, 0, stream>>>(h, ln2g + l * Dm, ln2b + l * Dm, xn);
        if (l == 1 || l == 3) {
            router_kernel<<<(NT + 255) / 256, 256, 0, stream>>>(
                xn, gw + (size_t)moe_i * Em * Dm, topi, topw);
            route_build_kernel<<<1, 256, 0, stream>>>(topi, e_cnt, e_off, bucket);
            if (l == 3) {
                moe_mfma_gemm1<0><<<dim3(Hm / NB, NAS / MB, Em), 256, 0, stream>>>(
                    xn, mw1 + (size_t)moe_i * Em * Hm * Dm, mb1 + (size_t)moe_i * Em * Hm,
                    bucket, e_cnt, e_off, heg);
                moe_mfma_gemm2<0><<<dim3(Dm / NB, NAS / MB, Em), 256, 0, stream>>>(
                    heg, mw2 + (size_t)moe_i * Em * Dm * Hm, mb2 + (size_t)moe_i * Em * Dm,
                    bucket, e_cnt, e_off, topw, ye);
            } else {
                moe_mfma_gemm1<1><<<dim3(Hm / NB, NAS / MB, Em), 256, 0, stream>>>(
                    xn, mw1 + (size_t)moe_i * Em * Hm * Dm, mb1 + (size_t)moe_i * Em * Hm,
                    bucket, e_cnt, e_off, heg);
                moe_mfma_gemm2<1><<<dim3(Dm / NB, NAS / MB, Em), 256, 0, stream>>>(
                    heg, mw2 + (size_t)moe_i * Em * Dm * Hm, mb2 + (size_t)moe_i * Em * Dm,
                    bucket, e_cnt, e_off, topw, ye);
            }
            combine_kernel<<<(NT * Dm) / 256, 256, 0, stream>>>(h, ye);
            moe_i++;
        } else {
            mfma_gemm_sp<1,0><<<dim3(Hm / NB, NT / MB), 256, 0, stream>>>(
                xn, sw1 + (size_t)std_i * Hm * Dm, sb1 + (size_t)std_i * Hm,
                nullptr, ffh, NT, Hm, Dm);
            mfma_gemm_sp<0,1><<<dim3(Dm / NB, NT / MB), 256, 0, stream>>>(
                ffh, sw2 + (size_t)std_i * Dm * Hm, sb2 + (size_t)std_i * Dm,
                h, h, NT, Dm, Hm);
            std_i++;
        }
    }

    ln_kernel<<<NT, 256, 0, stream>>>(h, lnfg, lnfb, xn);
    if (emb_bf) {
        long n = (long)NT * Dm;
        cvt_bf16_kernel<<<(unsigned)((n / 8 + 255) / 256), 256, 0, stream>>>(xn, xn_bf, n);
        mfma_gemm_bf<<<dim3((Vm + NB - 1) / NB, NT / MB), 256, 0, stream>>>(
            xn_bf, emb_bf, nullptr, (float*)d_out, NT, Vm, Dm);
    } else {
        mfma_gemm<0,0><<<dim3((Vm + NB - 1) / NB, NT / MB), 256, 0, stream>>>(
            xn, emb, nullptr, nullptr, (float*)d_out, NT, Vm, Dm);
    }
}

// Round 10
// 2175.506 us; speedup vs baseline: 5.9477x; 1.3617x over previous
//
#include <hip/hip_runtime.h>
#include <hip/hip_bf16.h>
#include <cstdint>
#include <cstddef>

// ---- Model constants ----
#define Dm   768
#define NHm  12
#define Lm   4
#define Em   8
#define Vm   50257
#define Hm   3072
#define Tm   512
#define Bm   2
#define NT   (Bm*Tm)      // 1024 tokens
#define NAS  (NT*2)       // 2048 expert assignments

typedef float f32x4 __attribute__((ext_vector_type(4)));
typedef short bf16x8 __attribute__((ext_vector_type(8)));

__device__ __forceinline__ float gelu_exact(float x) {
    return 0.5f * x * (1.0f + erff(x * 0.70710678118654752440f));
}

__device__ __forceinline__ unsigned short f2bf(float f) {
    __hip_bfloat16 h = __float2bfloat16(f);
    union { __hip_bfloat16 h; unsigned short s; } c; c.h = h; return c.s;
}
__device__ __forceinline__ float bf2f_bits(unsigned short b) {
    union { unsigned u; float f; } c; c.u = ((unsigned)b) << 16; return c.f;
}

// ---------------- fp32 -> bf16 bulk convert ----------------
__global__ __launch_bounds__(256) void cvt_bf16_kernel(const float* __restrict__ in,
                                                       unsigned short* __restrict__ out,
                                                       long n) {
    long i = ((long)blockIdx.x * 256 + threadIdx.x) * 8;
    if (i + 8 <= n) {
        const float4* s4 = reinterpret_cast<const float4*>(in + i);
        float4 f0 = s4[0], f1 = s4[1];
        union { unsigned short s[8]; uint4 v; } p;
        p.s[0] = f2bf(f0.x); p.s[1] = f2bf(f0.y); p.s[2] = f2bf(f0.z); p.s[3] = f2bf(f0.w);
        p.s[4] = f2bf(f1.x); p.s[5] = f2bf(f1.y); p.s[6] = f2bf(f1.z); p.s[7] = f2bf(f1.w);
        *reinterpret_cast<uint4*>(out + i) = p.v;
    } else {
        for (long j = i; j < n; ++j) out[j] = f2bf(in[j]);
    }
}

// ---------------- Embedding + sinusoidal PE ----------------
__global__ __launch_bounds__(256) void embed_kernel(const int* __restrict__ x,
                                                    const float* __restrict__ emb,
                                                    float* __restrict__ h) {
    int g = blockIdx.x;
    int tid = threadIdx.x;
    int tok = x[g];
    int pos = g % Tm;
    const float* erow = emb + (size_t)tok * Dm;
    for (int d = tid; d < Dm; d += 256) {
        int i2 = (d >> 1) * 2;
        float div = expf(-logf(10000.0f) * (float)i2 / (float)Dm);
        float a = (float)pos * div;
        float pe = (d & 1) ? cosf(a) : sinf(a);
        h[(size_t)g * Dm + d] = erow[d] + pe;
    }
}

// ---------------- LayerNorm ----------------
__global__ __launch_bounds__(256) void ln_kernel(const float* __restrict__ in,
                                                 const float* __restrict__ g,
                                                 const float* __restrict__ b,
                                                 float* __restrict__ out) {
    int t = blockIdx.x, tid = threadIdx.x;
    const float* x = in + (size_t)t * Dm;
    float v0 = x[tid], v1 = x[tid + 256], v2 = x[tid + 512];
    __shared__ float red[256];
    red[tid] = v0 + v1 + v2;
    __syncthreads();
    for (int off = 128; off > 0; off >>= 1) {
        if (tid < off) red[tid] += red[tid + off];
        __syncthreads();
    }
    float mean = red[0] * (1.0f / Dm);
    __syncthreads();
    float d0 = v0 - mean, d1 = v1 - mean, d2 = v2 - mean;
    red[tid] = d0 * d0 + d1 * d1 + d2 * d2;
    __syncthreads();
    for (int off = 128; off > 0; off >>= 1) {
        if (tid < off) red[tid] += red[tid + off];
        __syncthreads();
    }
    float inv = rsqrtf(red[0] * (1.0f / Dm) + 1e-5f);
    float* o = out + (size_t)t * Dm;
    o[tid]       = d0 * inv * g[tid]       + b[tid];
    o[tid + 256] = d1 * inv * g[tid + 256] + b[tid + 256];
    o[tid + 512] = d2 * inv * g[tid + 512] + b[tid + 512];
}

// ============ MFMA GEMM machinery ============
#define MB 128
#define NB 128
#define KB 32
#define LDT 40

__device__ __forceinline__ void stage_tile(unsigned short* lds, const float* src,
                                           bool valid, int srow, int shalf) {
    union { unsigned short s[8]; uint4 v; } p0, p1;
    if (valid) {
        const float4* s4 = reinterpret_cast<const float4*>(src);
        #pragma unroll
        for (int q = 0; q < 4; ++q) {
            float4 f = s4[q];
            float vv[4] = {f.x, f.y, f.z, f.w};
            #pragma unroll
            for (int j = 0; j < 4; ++j) {
                int idx = q * 4 + j;
                unsigned short hb = f2bf(vv[j]);
                if (idx < 8) p0.s[idx] = hb; else p1.s[idx - 8] = hb;
            }
        }
    } else {
        p0.v = make_uint4(0, 0, 0, 0);
        p1.v = make_uint4(0, 0, 0, 0);
    }
    uint4* dst = reinterpret_cast<uint4*>(&lds[srow * LDT + shalf * 16]);
    dst[0] = p0.v; dst[1] = p1.v;
}

__device__ __forceinline__ void stage_tile_split(unsigned short* lds_hi,
                                                 unsigned short* lds_lo,
                                                 const float* src,
                                                 bool valid, int srow, int shalf) {
    union { unsigned short s[8]; uint4 v; } h0, h1, l0, l1;
    if (valid) {
        const float4* s4 = reinterpret_cast<const float4*>(src);
        #pragma unroll
        for (int q = 0; q < 4; ++q) {
            float4 f = s4[q];
            float vv[4] = {f.x, f.y, f.z, f.w};
            #pragma unroll
            for (int j = 0; j < 4; ++j) {
                int idx = q * 4 + j;
                unsigned short hb = f2bf(vv[j]);
                unsigned short lb = f2bf(vv[j] - bf2f_bits(hb));
                if (idx < 8) { h0.s[idx] = hb; l0.s[idx] = lb; }
                else         { h1.s[idx - 8] = hb; l1.s[idx - 8] = lb; }
            }
        }
    } else {
        h0.v = make_uint4(0,0,0,0); h1.v = make_uint4(0,0,0,0);
        l0.v = make_uint4(0,0,0,0); l1.v = make_uint4(0,0,0,0);
    }
    uint4* dh = reinterpret_cast<uint4*>(&lds_hi[srow * LDT + shalf * 16]);
    dh[0] = h0.v; dh[1] = h1.v;
    uint4* dl = reinterpret_cast<uint4*>(&lds_lo[srow * LDT + shalf * 16]);
    dl[0] = l0.v; dl[1] = l1.v;
}

// ---- Lean all-bf16 MFMA GEMM with register prefetch (logits) ----
__global__ __launch_bounds__(256) void mfma_gemm_bf(const unsigned short* __restrict__ A,
                                                    const unsigned short* __restrict__ B,
                                                    const float* __restrict__ bias,
                                                    float* __restrict__ C,
                                                    int M, int N, int K) {
    __shared__ __align__(16) unsigned short As[MB * LDT];
    __shared__ __align__(16) unsigned short Bs[NB * LDT];
    int tid = threadIdx.x;
    int bm = blockIdx.y * MB, bn = blockIdx.x * NB;
    int srow = tid >> 1, shalf = tid & 1;
    int lane = tid & 63, w = tid >> 6;
    int wr = w >> 1, wc = w & 1;
    int r0 = (lane >> 4) * 4, c0 = lane & 15;
    int kb = (lane >> 4) * 8;

    bool bval = (bn + srow) < N;
    const unsigned short* Ap = A + (size_t)(bm + srow) * K + shalf * 16;
    const unsigned short* Bp = B + (size_t)(bn + srow) * K + shalf * 16;

    uint4 ra0, ra1, rb0, rb1;
    ra0 = reinterpret_cast<const uint4*>(Ap)[0];
    ra1 = reinterpret_cast<const uint4*>(Ap)[1];
    rb0 = make_uint4(0,0,0,0); rb1 = make_uint4(0,0,0,0);
    if (bval) {
        rb0 = reinterpret_cast<const uint4*>(Bp)[0];
        rb1 = reinterpret_cast<const uint4*>(Bp)[1];
    }

    f32x4 acc[4][4] = {};

    for (int kk = 0; kk < K; kk += KB) {
        uint4* da = reinterpret_cast<uint4*>(&As[srow * LDT + shalf * 16]);
        da[0] = ra0; da[1] = ra1;
        uint4* db = reinterpret_cast<uint4*>(&Bs[srow * LDT + shalf * 16]);
        db[0] = rb0; db[1] = rb1;
        __syncthreads();
        if (kk + KB < K) {
            const uint4* na = reinterpret_cast<const uint4*>(Ap + kk + KB);
            ra0 = na[0]; ra1 = na[1];
            if (bval) {
                const uint4* nb = reinterpret_cast<const uint4*>(Bp + kk + KB);
                rb0 = nb[0]; rb1 = nb[1];
            }
        }
        bf16x8 af[4], bf[4];
        #pragma unroll
        for (int m = 0; m < 4; ++m)
            af[m] = *reinterpret_cast<const bf16x8*>(&As[(wr * 64 + m * 16 + c0) * LDT + kb]);
        #pragma unroll
        for (int n = 0; n < 4; ++n)
            bf[n] = *reinterpret_cast<const bf16x8*>(&Bs[(wc * 64 + n * 16 + c0) * LDT + kb]);
        #pragma unroll
        for (int m = 0; m < 4; ++m)
            #pragma unroll
            for (int n = 0; n < 4; ++n)
                acc[m][n] = __builtin_amdgcn_mfma_f32_16x16x32_bf16(af[m], bf[n], acc[m][n], 0, 0, 0);
        __syncthreads();
    }

    #pragma unroll
    for (int n = 0; n < 4; ++n) {
        int col = bn + wc * 64 + n * 16 + c0;
        if (col < N) {
            float bv = bias ? bias[col] : 0.f;
            #pragma unroll
            for (int m = 0; m < 4; ++m)
                #pragma unroll
                for (int r = 0; r < 4; ++r) {
                    int row = bm + wr * 64 + m * 16 + r0 + r;
                    C[(size_t)row * N + col] = acc[m][n][r] + bv;
                }
        }
    }
}

// ---- Plain bf16 MFMA GEMM from fp32 (fallback logits) ----
template<int ACT, int RES>
__global__ __launch_bounds__(256) void mfma_gemm(const float* __restrict__ A,
                                                 const float* __restrict__ B,
                                                 const float* __restrict__ bias,
                                                 const float* __restrict__ res,
                                                 float* __restrict__ C,
                                                 int M, int N, int K) {
    __shared__ __align__(16) unsigned short As[MB * LDT];
    __shared__ __align__(16) unsigned short Bs[NB * LDT];
    int tid = threadIdx.x;
    int bm = blockIdx.y * MB, bn = blockIdx.x * NB;
    int srow = tid >> 1, shalf = tid & 1;
    int lane = tid & 63, w = tid >> 6;
    int wr = w >> 1, wc = w & 1;
    int r0 = (lane >> 4) * 4, c0 = lane & 15;
    int kb = (lane >> 4) * 8;

    f32x4 acc[4][4] = {};

    for (int kk = 0; kk < K; kk += KB) {
        stage_tile(As, A + (size_t)(bm + srow) * K + kk + shalf * 16, true, srow, shalf);
        bool bval = (bn + srow) < N;
        stage_tile(Bs, B + (size_t)(bn + srow) * K + kk + shalf * 16, bval, srow, shalf);
        __syncthreads();
        bf16x8 af[4], bf[4];
        #pragma unroll
        for (int m = 0; m < 4; ++m)
            af[m] = *reinterpret_cast<const bf16x8*>(&As[(wr * 64 + m * 16 + c0) * LDT + kb]);
        #pragma unroll
        for (int n = 0; n < 4; ++n)
            bf[n] = *reinterpret_cast<const bf16x8*>(&Bs[(wc * 64 + n * 16 + c0) * LDT + kb]);
        #pragma unroll
        for (int m = 0; m < 4; ++m)
            #pragma unroll
            for (int n = 0; n < 4; ++n)
                acc[m][n] = __builtin_amdgcn_mfma_f32_16x16x32_bf16(af[m], bf[n], acc[m][n], 0, 0, 0);
        __syncthreads();
    }

    #pragma unroll
    for (int n = 0; n < 4; ++n) {
        int col = bn + wc * 64 + n * 16 + c0;
        if (col < N) {
            float bv = bias ? bias[col] : 0.f;
            #pragma unroll
            for (int m = 0; m < 4; ++m) {
                #pragma unroll
                for (int r = 0; r < 4; ++r) {
                    int row = bm + wr * 64 + m * 16 + r0 + r;
                    float v = acc[m][n][r] + bv;
                    if (RES) v += res[(size_t)row * N + col];
                    if (ACT == 1) v = gelu_exact(v);
                    C[(size_t)row * N + col] = v;
                }
            }
        }
    }
}

// ---- Split-bf16 MFMA GEMM, K-SPLIT PARTIAL (dense; M,N %128==0, (K/KSPLIT)%32==0) ----
// part[kc][row][col] = Σ_{k in chunk kc} A·B^T   (no bias/act/res here)
__global__ __launch_bounds__(256) void mfma_gemm_sp_part(const float* __restrict__ A,
                                                         const float* __restrict__ B,
                                                         float* __restrict__ part,
                                                         int M, int N, int K, int KSPLIT) {
    __shared__ __align__(16) unsigned short Ah[MB * LDT];
    __shared__ __align__(16) unsigned short Al[MB * LDT];
    __shared__ __align__(16) unsigned short Bh[NB * LDT];
    __shared__ __align__(16) unsigned short Bl[NB * LDT];
    int tid = threadIdx.x;
    int bm = blockIdx.y * MB, bn = blockIdx.x * NB;
    int kc = blockIdx.z;
    int chunk = K / KSPLIT;
    int kbeg = kc * chunk;
    int srow = tid >> 1, shalf = tid & 1;
    int lane = tid & 63, w = tid >> 6;
    int wr = w >> 1, wc = w & 1;
    int r0 = (lane >> 4) * 4, c0 = lane & 15;
    int kb = (lane >> 4) * 8;

    f32x4 acc[4][4] = {};

    for (int kk = kbeg; kk < kbeg + chunk; kk += KB) {
        stage_tile_split(Ah, Al, A + (size_t)(bm + srow) * K + kk + shalf * 16, true, srow, shalf);
        stage_tile_split(Bh, Bl, B + (size_t)(bn + srow) * K + kk + shalf * 16, true, srow, shalf);
        __syncthreads();
        bf16x8 ah[4], al[4], bh[4], bl[4];
        #pragma unroll
        for (int m = 0; m < 4; ++m) {
            int o = (wr * 64 + m * 16 + c0) * LDT + kb;
            ah[m] = *reinterpret_cast<const bf16x8*>(&Ah[o]);
            al[m] = *reinterpret_cast<const bf16x8*>(&Al[o]);
        }
        #pragma unroll
        for (int n = 0; n < 4; ++n) {
            int o = (wc * 64 + n * 16 + c0) * LDT + kb;
            bh[n] = *reinterpret_cast<const bf16x8*>(&Bh[o]);
            bl[n] = *reinterpret_cast<const bf16x8*>(&Bl[o]);
        }
        #pragma unroll
        for (int m = 0; m < 4; ++m)
            #pragma unroll
            for (int n = 0; n < 4; ++n) {
                acc[m][n] = __builtin_amdgcn_mfma_f32_16x16x32_bf16(al[m], bh[n], acc[m][n], 0, 0, 0);
                acc[m][n] = __builtin_amdgcn_mfma_f32_16x16x32_bf16(ah[m], bl[n], acc[m][n], 0, 0, 0);
                acc[m][n] = __builtin_amdgcn_mfma_f32_16x16x32_bf16(ah[m], bh[n], acc[m][n], 0, 0, 0);
            }
        __syncthreads();
    }

    float* P = part + (size_t)kc * M * N;
    #pragma unroll
    for (int n = 0; n < 4; ++n) {
        int col = bn + wc * 64 + n * 16 + c0;
        #pragma unroll
        for (int m = 0; m < 4; ++m)
            #pragma unroll
            for (int r = 0; r < 4; ++r) {
                int row = bm + wr * 64 + m * 16 + r0 + r;
                P[(size_t)row * N + col] = acc[m][n][r];
            }
    }
}

// ---- Dense reduce: C = act(Σ parts + bias [+ res]) ----
template<int ACT, int RES>
__global__ __launch_bounds__(256) void reduce_dense(const float* __restrict__ part,
                                                    const float* __restrict__ bias,
                                                    const float* __restrict__ res,
                                                    float* __restrict__ C,
                                                    long MN, int N, int KSPLIT) {
    long stride = (long)gridDim.x * 256 * 4;
    for (long i = ((long)blockIdx.x * 256 + threadIdx.x) * 4; i < MN; i += stride) {
        float4 v = *reinterpret_cast<const float4*>(part + i);
        for (int kc = 1; kc < KSPLIT; ++kc) {
            float4 p = *reinterpret_cast<const float4*>(part + (size_t)kc * MN + i);
            v.x += p.x; v.y += p.y; v.z += p.z; v.w += p.w;
        }
        int col = (int)(i % N);
        float4 b = *reinterpret_cast<const float4*>(bias + col);
        v.x += b.x; v.y += b.y; v.z += b.z; v.w += b.w;
        if (RES) {
            float4 r = *reinterpret_cast<const float4*>(res + i);
            v.x += r.x; v.y += r.y; v.z += r.z; v.w += r.w;
        }
        if (ACT == 1) {
            v.x = gelu_exact(v.x); v.y = gelu_exact(v.y);
            v.z = gelu_exact(v.z); v.w = gelu_exact(v.w);
        }
        *reinterpret_cast<float4*>(C + i) = v;
    }
}

// ---------------- Causal attention (fp32), shuffle reductions + float4 ----------------
__global__ __launch_bounds__(256) void attn_kernel(const float* __restrict__ qkv,
                                                   float* __restrict__ o) {
    int idx = blockIdx.x;
    int tq = idx % Tm; idx /= Tm;
    int hh = idx % NHm;
    int b  = idx / NHm;
    int tid = threadIdx.x;
    const int g0 = b * Tm;
    __shared__ float qs[64];
    __shared__ float s[Tm];
    __shared__ float red[4];
    __shared__ float part[4][64];

    const float* qrow = qkv + (size_t)(g0 + tq) * (3 * Dm) + hh * 64;
    if (tid < 64) qs[tid] = qrow[tid];
    __syncthreads();

    int nk = tq + 1;
    const float4* q4 = reinterpret_cast<const float4*>(qs);
    float lmax = -1e30f;
    for (int k = tid; k < nk; k += 256) {
        const float4* kr = reinterpret_cast<const float4*>(
            qkv + (size_t)(g0 + k) * (3 * Dm) + Dm + hh * 64);
        float dot = 0.f;
        #pragma unroll
        for (int d = 0; d < 16; ++d) {
            float4 kv = kr[d], qv = q4[d];
            dot += qv.x * kv.x + qv.y * kv.y + qv.z * kv.z + qv.w * kv.w;
        }
        dot *= 0.125f;
        s[k] = dot;
        lmax = fmaxf(lmax, dot);
    }
    #pragma unroll
    for (int off = 32; off > 0; off >>= 1) lmax = fmaxf(lmax, __shfl_xor(lmax, off));
    if ((tid & 63) == 0) red[tid >> 6] = lmax;
    __syncthreads();
    float mx = fmaxf(fmaxf(red[0], red[1]), fmaxf(red[2], red[3]));

    float lsum = 0.f;
    for (int k = tid; k < nk; k += 256) {
        float e = expf(s[k] - mx);
        s[k] = e;
        lsum += e;
    }
    #pragma unroll
    for (int off = 32; off > 0; off >>= 1) lsum += __shfl_xor(lsum, off);
    __syncthreads();
    if ((tid & 63) == 0) red[tid >> 6] = lsum;
    __syncthreads();
    float inv = 1.0f / (red[0] + red[1] + red[2] + red[3]);

    int grp = tid >> 6;
    int d = tid & 63;
    float acc = 0.f;
    for (int k = grp; k < nk; k += 4) {
        acc += s[k] * qkv[(size_t)(g0 + k) * (3 * Dm) + 2 * Dm + hh * 64 + d];
    }
    part[grp][d] = acc;
    __syncthreads();
    if (tid < 64) {
        float r = (part[0][tid] + part[1][tid] + part[2][tid] + part[3][tid]) * inv;
        o[(size_t)(g0 + tq) * Dm + hh * 64 + tid] = r;
    }
}

// ---------------- MoE router (fp32 exact) ----------------
__global__ __launch_bounds__(256) void router_kernel(const float* __restrict__ xn,
                                                     const float* __restrict__ gw,
                                                     int* __restrict__ topi,
                                                     float* __restrict__ topw) {
    int t = blockIdx.x * 256 + threadIdx.x;
    if (t >= NT) return;
    const float* x = xn + (size_t)t * Dm;
    float l[Em];
    #pragma unroll
    for (int e = 0; e < Em; ++e) {
        const float* w = gw + (size_t)e * Dm;
        float dot = 0.f;
        for (int d = 0; d < Dm; ++d) dot += w[d] * x[d];
        l[e] = dot;
    }
    int i1 = 0;
    #pragma unroll
    for (int e = 1; e < Em; ++e) if (l[e] > l[i1]) i1 = e;
    int i2 = (i1 == 0) ? 1 : 0;
    #pragma unroll
    for (int e = 0; e < Em; ++e) if (e != i1 && l[e] > l[i2]) i2 = e;
    float w1 = 1.0f / (1.0f + expf(l[i2] - l[i1]));
    topi[t * 2] = i1; topi[t * 2 + 1] = i2;
    topw[t * 2] = w1; topw[t * 2 + 1] = 1.0f - w1;
}

// ---------------- Route build ----------------
__global__ __launch_bounds__(256) void route_build_kernel(const int* __restrict__ topi,
                                                          int* __restrict__ g_cnt,
                                                          int* __restrict__ g_off,
                                                          int* __restrict__ bucket) {
    __shared__ int cnt[Em], off[Em], pos[Em];
    int tid = threadIdx.x;
    if (tid < Em) cnt[tid] = 0;
    __syncthreads();
    for (int ts = tid; ts < NAS; ts += 256) atomicAdd(&cnt[topi[ts]], 1);
    __syncthreads();
    if (tid == 0) {
        int acc = 0;
        for (int e = 0; e < Em; ++e) { off[e] = acc; pos[e] = acc; acc += cnt[e]; }
    }
    __syncthreads();
    for (int ts = tid; ts < NAS; ts += 256) {
        int e = topi[ts];
        int p = atomicAdd(&pos[e], 1);
        bucket[p] = ts;
    }
    if (tid < Em) { g_cnt[tid] = cnt[tid]; g_off[tid] = off[tid]; }
}

// ---------------- Grouped MoE GEMM1 (MFMA), SPLIT template ----------------
template<int SPLIT>
__global__ __launch_bounds__(256) void moe_mfma_gemm1(const float* __restrict__ xn,
                                                      const float* __restrict__ W1all,
                                                      const float* __restrict__ B1all,
                                                      const int* __restrict__ bucket,
                                                      const int* __restrict__ cnt,
                                                      const int* __restrict__ off,
                                                      float* __restrict__ heg) {
    int e = blockIdx.z;
    int count = cnt[e];
    int mbase = blockIdx.y * MB;
    if (mbase >= count) return;
    int base = off[e];

    __shared__ __align__(16) unsigned short Ah[MB * LDT];
    __shared__ __align__(16) unsigned short Bh[NB * LDT];
    __shared__ __align__(16) unsigned short Al[SPLIT ? MB * LDT : 8];
    __shared__ __align__(16) unsigned short Bl[SPLIT ? NB * LDT : 8];
    __shared__ int toks[MB];
    int tid = threadIdx.x;
    int bn = blockIdx.x * NB;
    int srow = tid >> 1, shalf = tid & 1;
    int lane = tid & 63, w = tid >> 6;
    int wr = w >> 1, wc = w & 1;
    int r0 = (lane >> 4) * 4, c0 = lane & 15;
    int kb = (lane >> 4) * 8;
    if (tid < MB) {
        int p = mbase + tid;
        toks[tid] = (p < count) ? (bucket[base + p] >> 1) : -1;
    }
    __syncthreads();

    f32x4 acc[4][4] = {};
    const float* W = W1all + (size_t)e * Hm * Dm;
    int t = toks[srow];
    for (int kk = 0; kk < Dm; kk += KB) {
        if (SPLIT) {
            stage_tile_split(Ah, Al, xn + (size_t)t * Dm + kk + shalf * 16, t >= 0, srow, shalf);
            stage_tile_split(Bh, Bl, W + (size_t)(bn + srow) * Dm + kk + shalf * 16, true, srow, shalf);
        } else {
            stage_tile(Ah, xn + (size_t)t * Dm + kk + shalf * 16, t >= 0, srow, shalf);
            stage_tile(Bh, W + (size_t)(bn + srow) * Dm + kk + shalf * 16, true, srow, shalf);
        }
        __syncthreads();
        bf16x8 ah[4], bh[4], al[4], bl[4];
        #pragma unroll
        for (int m = 0; m < 4; ++m) {
            int o = (wr * 64 + m * 16 + c0) * LDT + kb;
            ah[m] = *reinterpret_cast<const bf16x8*>(&Ah[o]);
            if (SPLIT) al[m] = *reinterpret_cast<const bf16x8*>(&Al[o]);
        }
        #pragma unroll
        for (int n = 0; n < 4; ++n) {
            int o = (wc * 64 + n * 16 + c0) * LDT + kb;
            bh[n] = *reinterpret_cast<const bf16x8*>(&Bh[o]);
            if (SPLIT) bl[n] = *reinterpret_cast<const bf16x8*>(&Bl[o]);
        }
        #pragma unroll
        for (int m = 0; m < 4; ++m)
            #pragma unroll
            for (int n = 0; n < 4; ++n) {
                if (SPLIT) {
                    acc[m][n] = __builtin_amdgcn_mfma_f32_16x16x32_bf16(al[m], bh[n], acc[m][n], 0, 0, 0);
                    acc[m][n] = __builtin_amdgcn_mfma_f32_16x16x32_bf16(ah[m], bl[n], acc[m][n], 0, 0, 0);
                }
                acc[m][n] = __builtin_amdgcn_mfma_f32_16x16x32_bf16(ah[m], bh[n], acc[m][n], 0, 0, 0);
            }
        __syncthreads();
    }

    const float* b1 = B1all + (size_t)e * Hm;
    #pragma unroll
    for (int n = 0; n < 4; ++n) {
        int col = bn + wc * 64 + n * 16 + c0;
        float bv = b1[col];
        #pragma unroll
        for (int m = 0; m < 4; ++m) {
            #pragma unroll
            for (int r = 0; r < 4; ++r) {
                int p = mbase + wr * 64 + m * 16 + r0 + r;
                if (p < count)
                    heg[(size_t)(base + p) * Hm + col] = gelu_exact(acc[m][n][r] + bv);
            }
        }
    }
}

// ---------------- Grouped MoE GEMM2, K-SPLIT PARTIAL ----------------
// part[kc][base+p][col] = Σ_{k in chunk} heg·W2^T   (guarded p<count)
template<int SPLIT>
__global__ __launch_bounds__(256) void moe_gemm2_part(const float* __restrict__ heg,
                                                      const float* __restrict__ W2all,
                                                      const int* __restrict__ cnt,
                                                      const int* __restrict__ off,
                                                      float* __restrict__ part,
                                                      int KSPLIT) {
    int e = blockIdx.z;
    int count = cnt[e];
    int my = blockIdx.y;
    int kc = my % KSPLIT, mb = my / KSPLIT;
    int mbase = mb * MB;
    if (mbase >= count) return;
    int base = off[e];
    int chunk = Hm / KSPLIT;
    int kbeg = kc * chunk;

    __shared__ __align__(16) unsigned short Ah[MB * LDT];
    __shared__ __align__(16) unsigned short Bh[NB * LDT];
    __shared__ __align__(16) unsigned short Al[SPLIT ? MB * LDT : 8];
    __shared__ __align__(16) unsigned short Bl[SPLIT ? NB * LDT : 8];
    int tid = threadIdx.x;
    int bn = blockIdx.x * NB;
    int srow = tid >> 1, shalf = tid & 1;
    int lane = tid & 63, w = tid >> 6;
    int wr = w >> 1, wc = w & 1;
    int r0 = (lane >> 4) * 4, c0 = lane & 15;
    int kb = (lane >> 4) * 8;

    f32x4 acc[4][4] = {};
    const float* W = W2all + (size_t)e * Dm * Hm;
    bool aval = (mbase + srow) < count;
    for (int kk = kbeg; kk < kbeg + chunk; kk += KB) {
        if (SPLIT) {
            stage_tile_split(Ah, Al, heg + (size_t)(base + mbase + srow) * Hm + kk + shalf * 16, aval, srow, shalf);
            stage_tile_split(Bh, Bl, W + (size_t)(bn + srow) * Hm + kk + shalf * 16, true, srow, shalf);
        } else {
            stage_tile(Ah, heg + (size_t)(base + mbase + srow) * Hm + kk + shalf * 16, aval, srow, shalf);
            stage_tile(Bh, W + (size_t)(bn + srow) * Hm + kk + shalf * 16, true, srow, shalf);
        }
        __syncthreads();
        bf16x8 ah[4], bh[4], al[4], bl[4];
        #pragma unroll
        for (int m = 0; m < 4; ++m) {
            int o = (wr * 64 + m * 16 + c0) * LDT + kb;
            ah[m] = *reinterpret_cast<const bf16x8*>(&Ah[o]);
            if (SPLIT) al[m] = *reinterpret_cast<const bf16x8*>(&Al[o]);
        }
        #pragma unroll
        for (int n = 0; n < 4; ++n) {
            int o = (wc * 64 + n * 16 + c0) * LDT + kb;
            bh[n] = *reinterpret_cast<const bf16x8*>(&Bh[o]);
            if (SPLIT) bl[n] = *reinterpret_cast<const bf16x8*>(&Bl[o]);
        }
        #pragma unroll
        for (int m = 0; m < 4; ++m)
            #pragma unroll
            for (int n = 0; n < 4; ++n) {
                if (SPLIT) {
                    acc[m][n] = __builtin_amdgcn_mfma_f32_16x16x32_bf16(al[m], bh[n], acc[m][n], 0, 0, 0);
                    acc[m][n] = __builtin_amdgcn_mfma_f32_16x16x32_bf16(ah[m], bl[n], acc[m][n], 0, 0, 0);
                }
                acc[m][n] = __builtin_amdgcn_mfma_f32_16x16x32_bf16(ah[m], bh[n], acc[m][n], 0, 0, 0);
            }
        __syncthreads();
    }

    float* P = part + (size_t)kc * NAS * Dm;
    #pragma unroll
    for (int n = 0; n < 4; ++n) {
        int col = bn + wc * 64 + n * 16 + c0;
        #pragma unroll
        for (int m = 0; m < 4; ++m) {
            #pragma unroll
            for (int r = 0; r < 4; ++r) {
                int p = mbase + wr * 64 + m * 16 + r0 + r;
                if (p < count)
                    P[(size_t)(base + p) * Dm + col] = acc[m][n][r];
            }
        }
    }
}

// ---- MoE reduce: ye[ts] = topw[ts] * (Σ parts + b2[e]) ----
__global__ __launch_bounds__(256) void moe_reduce(const float* __restrict__ part,
                                                  const float* __restrict__ B2all,
                                                  const int* __restrict__ bucket,
                                                  const int* __restrict__ topi,
                                                  const float* __restrict__ topw,
                                                  float* __restrict__ ye, int KSPLIT) {
    const long MN = (long)NAS * Dm;
    long stride = (long)gridDim.x * 256 * 4;
    for (long i = ((long)blockIdx.x * 256 + threadIdx.x) * 4; i < MN; i += stride) {
        int p = (int)(i / Dm), col = (int)(i % Dm);
        int ts = bucket[p];
        int e = topi[ts];
        float wgt = topw[ts];
        float4 v = *reinterpret_cast<const float4*>(part + i);
        for (int kc = 1; kc < KSPLIT; ++kc) {
            float4 q = *reinterpret_cast<const float4*>(part + (size_t)kc * MN + i);
            v.x += q.x; v.y += q.y; v.z += q.z; v.w += q.w;
        }
        float4 b = *reinterpret_cast<const float4*>(B2all + (size_t)e * Dm + col);
        float4 o;
        o.x = wgt * (v.x + b.x); o.y = wgt * (v.y + b.y);
        o.z = wgt * (v.z + b.z); o.w = wgt * (v.w + b.w);
        *reinterpret_cast<float4*>(ye + (size_t)ts * Dm + col) = o;
    }
}

__global__ __launch_bounds__(256) void combine_kernel(float* __restrict__ h,
                                                      const float* __restrict__ ye) {
    int i = blockIdx.x * 256 + threadIdx.x;
    if (i < NT * Dm) {
        int t = i / Dm, d = i - t * Dm;
        h[i] += ye[(size_t)(t * 2) * Dm + d] + ye[(size_t)(t * 2 + 1) * Dm + d];
    }
}

// ---------------- Launch ----------------
extern "C" void kernel_launch(void* const* d_in, const int* in_sizes, int n_in,
                              void* d_out, int out_size, void* d_ws, size_t ws_size,
                              hipStream_t stream) {
    const int*   x    = (const int*)d_in[0];
    const float* emb  = (const float*)d_in[1];
    const float* wqkv = (const float*)d_in[2];
    const float* bqkv = (const float*)d_in[3];
    const float* wo   = (const float*)d_in[4];
    const float* bo   = (const float*)d_in[5];
    const float* ln1g = (const float*)d_in[6];
    const float* ln1b = (const float*)d_in[7];
    const float* ln2g = (const float*)d_in[8];
    const float* ln2b = (const float*)d_in[9];
    const float* sw1  = (const float*)d_in[10];
    const float* sb1  = (const float*)d_in[11];
    const float* sw2  = (const float*)d_in[12];
    const float* sb2  = (const float*)d_in[13];
    const float* gw   = (const float*)d_in[14];
    const float* mw1  = (const float*)d_in[15];
    const float* mb1  = (const float*)d_in[16];
    const float* mw2  = (const float*)d_in[17];
    const float* mb2  = (const float*)d_in[18];
    const float* lnfg = (const float*)d_in[19];
    const float* lnfb = (const float*)d_in[20];

    const size_t n_h    = (size_t)NT * Dm;
    const size_t n_qkv  = (size_t)NT * 3 * Dm;
    const size_t n_ffh  = (size_t)NT * Hm;
    const size_t n_ye   = (size_t)NAS * Dm;
    const size_t n_heg  = (size_t)NAS * Hm;
    const size_t n_xn   = (size_t)NT * Dm;
    const size_t n_part = (size_t)NT * Hm * 2;     // 6.29M floats, max partial use
    const size_t n_embbf = (size_t)Vm * Dm / 2;
    const size_t n_xnbf  = (size_t)NT * Dm / 2;
    const size_t n_big   = n_h + n_qkv + n_h + n_ffh + n_ye + n_heg + n_part;

    size_t wsf = ws_size / sizeof(float);

    float* w = (float*)d_ws;
    float* xn   = w;            w += n_xn;
    float* topw = w;            w += NAS;
    int*   topi = (int*)w;      w += NAS;
    int*   bucket = (int*)w;    w += NAS;
    int*   e_cnt = (int*)w;     w += 8;
    int*   e_off = (int*)w;     w += 8;
    size_t used = (size_t)(w - (float*)d_ws);

    unsigned short* emb_bf = nullptr;
    unsigned short* xn_bf  = nullptr;
    if (wsf >= used + n_embbf + n_xnbf + 64) {
        emb_bf = (unsigned short*)w;  w += n_embbf;
        xn_bf  = (unsigned short*)w;  w += n_xnbf;
        used = (size_t)(w - (float*)d_ws);
    }

    float *h, *qkv, *attno, *ffh, *ye, *heg, *part;
    if (wsf >= used + n_big + 64) {
        float* a = w;
        h = a;      a += n_h;
        qkv = a;    a += n_qkv;
        attno = a;  a += n_h;
        ffh = a;    a += n_ffh;
        ye = a;     a += n_ye;
        heg = a;    a += n_heg;
        part = a;
    } else {
        float* a = (float*)d_out;
        h = a;      a += n_h;
        qkv = a;    a += n_qkv;
        attno = a;  a += n_h;
        ffh = a;    a += n_ffh;
        ye = a;     a += n_ye;
        heg = a;    a += n_heg;
        part = a;
    }

    if (emb_bf) {
        long n = (long)Vm * Dm;
        cvt_bf16_kernel<<<(unsigned)((n / 8 + 255) / 256), 256, 0, stream>>>(emb, emb_bf, n);
    }

    embed_kernel<<<NT, 256, 0, stream>>>(x, emb, h);

    const int RBLK = 2048;
    int std_i = 0, moe_i = 0;
    for (int l = 0; l < Lm; ++l) {
        ln_kernel<<<NT, 256, 0, stream>>>(h, ln1g + l * Dm, ln1b + l * Dm, xn);
        // QKV: K=768, split 2 -> 288 blocks
        mfma_gemm_sp_part<<<dim3((3 * Dm) / NB, NT / MB, 2), 256, 0, stream>>>(
            xn, wqkv + (size_t)l * 3 * Dm * Dm, part, NT, 3 * Dm, Dm, 2);
        reduce_dense<0,0><<<RBLK, 256, 0, stream>>>(
            part, bqkv + (size_t)l * 3 * Dm, nullptr, qkv, (long)NT * 3 * Dm, 3 * Dm, 2);
        attn_kernel<<<Bm * NHm * Tm, 256, 0, stream>>>(qkv, attno);
        // WO: N=768, K=768, split 4 -> 192 blocks
        mfma_gemm_sp_part<<<dim3(Dm / NB, NT / MB, 4), 256, 0, stream>>>(
            attno, wo + (size_t)l * Dm * Dm, part, NT, Dm, Dm, 4);
        reduce_dense<0,1><<<RBLK, 256, 0, stream>>>(
            part, bo + (size_t)l * Dm, h, h, (long)NT * Dm, Dm, 4);

        ln_kernel<<<NT, 256, 0, stream>>>(h, ln2g + l * Dm, ln2b + l * Dm, xn);
        if (l == 1 || l == 3) {
            router_kernel<<<(NT + 255) / 256, 256, 0, stream>>>(
                xn, gw + (size_t)moe_i * Em * Dm, topi, topw);
            route_build_kernel<<<1, 256, 0, stream>>>(topi, e_cnt, e_off, bucket);
            if (l == 3) {
                moe_mfma_gemm1<0><<<dim3(Hm / NB, NAS / MB, Em), 256, 0, stream>>>(
                    xn, mw1 + (size_t)moe_i * Em * Hm * Dm, mb1 + (size_t)moe_i * Em * Hm,
                    bucket, e_cnt, e_off, heg);
                moe_gemm2_part<0><<<dim3(Dm / NB, (NAS / MB) * 4, Em), 256, 0, stream>>>(
                    heg, mw2 + (size_t)moe_i * Em * Dm * Hm, e_cnt, e_off, part, 4);
            } else {
                moe_mfma_gemm1<1><<<dim3(Hm / NB, NAS / MB, Em), 256, 0, stream>>>(
                    xn, mw1 + (size_t)moe_i * Em * Hm * Dm, mb1 + (size_t)moe_i * Em * Hm,
                    bucket, e_cnt, e_off, heg);
                moe_gemm2_part<1><<<dim3(Dm / NB, (NAS / MB) * 4, Em), 256, 0, stream>>>(
                    heg, mw2 + (size_t)moe_i * Em * Dm * Hm, e_cnt, e_off, part, 4);
            }
            moe_reduce<<<RBLK, 256, 0, stream>>>(
                part, mb2 + (size_t)moe_i * Em * Dm, bucket, topi, topw, ye, 4);
            combine_kernel<<<(NT * Dm) / 256, 256, 0, stream>>>(h, ye);
            moe_i++;
        } else {
            // FFN1: N=3072, K=768, split 2 -> 384 blocks
            mfma_gemm_sp_part<<<dim3(Hm / NB, NT / MB, 2), 256, 0, stream>>>(
                xn, sw1 + (size_t)std_i * Hm * Dm, part, NT, Hm, Dm, 2);
            reduce_dense<1,0><<<RBLK, 256, 0, stream>>>(
                part, sb1 + (size_t)std_i * Hm, nullptr, ffh, (long)NT * Hm, Hm, 2);
            // FFN2: N=768, K=3072, split 8 -> 384 blocks
            mfma_gemm_sp_part<<<dim3(Dm / NB, NT / MB, 8), 256, 0, stream>>>(
                ffh, sw2 + (size_t)std_i * Dm * Hm, part, NT, Dm, Hm, 8);
            reduce_dense<0,1><<<RBLK, 256, 0, stream>>>(
                part, sb2 + (size_t)std_i * Dm, h, h, (long)NT * Dm, Dm, 8);
            std_i++;
        }
    }

    ln_kernel<<<NT, 256, 0, stream>>>(h, lnfg, lnfb, xn);
    if (emb_bf) {
        long n = (long)NT * Dm;
        cvt_bf16_kernel<<<(unsigned)((n / 8 + 255) / 256), 256, 0, stream>>>(xn, xn_bf, n);
        mfma_gemm_bf<<<dim3((Vm + NB - 1) / NB, NT / MB), 256, 0, stream>>>(
            xn_bf, emb_bf, nullptr, (float*)d_out, NT, Vm, Dm);
    } else {
        mfma_gemm<0,0><<<dim3((Vm + NB - 1) / NB, NT / MB), 256, 0, stream>>>(
            xn, emb, nullptr, nullptr, (float*)d_out, NT, Vm, Dm);
    }
}

// Round 11
// 1497.084 us; speedup vs baseline: 8.6430x; 1.4532x over previous
//
#include <hip/hip_runtime.h>
#include <hip/hip_bf16.h>
#include <cstdint>
#include <cstddef>

// ---- Model constants ----
#define Dm   768
#define NHm  12
#define Lm   4
#define Em   8
#define Vm   50257
#define Hm   3072
#define Tm   512
#define Bm   2
#define NT   (Bm*Tm)      // 1024 tokens
#define NAS  (NT*2)       // 2048 expert assignments

typedef float f32x4 __attribute__((ext_vector_type(4)));
typedef short bf16x8 __attribute__((ext_vector_type(8)));

__device__ __forceinline__ float gelu_exact(float x) {
    return 0.5f * x * (1.0f + erff(x * 0.70710678118654752440f));
}

__device__ __forceinline__ unsigned short f2bf(float f) {
    __hip_bfloat16 h = __float2bfloat16(f);
    union { __hip_bfloat16 h; unsigned short s; } c; c.h = h; return c.s;
}
__device__ __forceinline__ float bf2f_bits(unsigned short b) {
    union { unsigned u; float f; } c; c.u = ((unsigned)b) << 16; return c.f;
}

// ---------------- fp32 -> bf16 bulk convert ----------------
__global__ __launch_bounds__(256) void cvt_bf16_kernel(const float* __restrict__ in,
                                                       unsigned short* __restrict__ out,
                                                       long n) {
    long i = ((long)blockIdx.x * 256 + threadIdx.x) * 8;
    if (i + 8 <= n) {
        const float4* s4 = reinterpret_cast<const float4*>(in + i);
        float4 f0 = s4[0], f1 = s4[1];
        union { unsigned short s[8]; uint4 v; } p;
        p.s[0] = f2bf(f0.x); p.s[1] = f2bf(f0.y); p.s[2] = f2bf(f0.z); p.s[3] = f2bf(f0.w);
        p.s[4] = f2bf(f1.x); p.s[5] = f2bf(f1.y); p.s[6] = f2bf(f1.z); p.s[7] = f2bf(f1.w);
        *reinterpret_cast<uint4*>(out + i) = p.v;
    } else {
        for (long j = i; j < n; ++j) out[j] = f2bf(in[j]);
    }
}

// ---------------- Embedding + sinusoidal PE ----------------
__global__ __launch_bounds__(256) void embed_kernel(const int* __restrict__ x,
                                                    const float* __restrict__ emb,
                                                    float* __restrict__ h) {
    int g = blockIdx.x;
    int tid = threadIdx.x;
    int tok = x[g];
    int pos = g % Tm;
    const float* erow = emb + (size_t)tok * Dm;
    for (int d = tid; d < Dm; d += 256) {
        int i2 = (d >> 1) * 2;
        float div = expf(-logf(10000.0f) * (float)i2 / (float)Dm);
        float a = (float)pos * div;
        float pe = (d & 1) ? cosf(a) : sinf(a);
        h[(size_t)g * Dm + d] = erow[d] + pe;
    }
}

// ---------------- LayerNorm ----------------
__global__ __launch_bounds__(256) void ln_kernel(const float* __restrict__ in,
                                                 const float* __restrict__ g,
                                                 const float* __restrict__ b,
                                                 float* __restrict__ out) {
    int t = blockIdx.x, tid = threadIdx.x;
    const float* x = in + (size_t)t * Dm;
    float v0 = x[tid], v1 = x[tid + 256], v2 = x[tid + 512];
    __shared__ float red[256];
    red[tid] = v0 + v1 + v2;
    __syncthreads();
    for (int off = 128; off > 0; off >>= 1) {
        if (tid < off) red[tid] += red[tid + off];
        __syncthreads();
    }
    float mean = red[0] * (1.0f / Dm);
    __syncthreads();
    float d0 = v0 - mean, d1 = v1 - mean, d2 = v2 - mean;
    red[tid] = d0 * d0 + d1 * d1 + d2 * d2;
    __syncthreads();
    for (int off = 128; off > 0; off >>= 1) {
        if (tid < off) red[tid] += red[tid + off];
        __syncthreads();
    }
    float inv = rsqrtf(red[0] * (1.0f / Dm) + 1e-5f);
    float* o = out + (size_t)t * Dm;
    o[tid]       = d0 * inv * g[tid]       + b[tid];
    o[tid + 256] = d1 * inv * g[tid + 256] + b[tid + 256];
    o[tid + 512] = d2 * inv * g[tid + 512] + b[tid + 512];
}

// ============ MFMA GEMM machinery ============
#define MB 128
#define NB 128
#define KB 32
#define LDT 40

__device__ __forceinline__ void stage_tile(unsigned short* lds, const float* src,
                                           bool valid, int srow, int shalf) {
    union { unsigned short s[8]; uint4 v; } p0, p1;
    if (valid) {
        const float4* s4 = reinterpret_cast<const float4*>(src);
        #pragma unroll
        for (int q = 0; q < 4; ++q) {
            float4 f = s4[q];
            float vv[4] = {f.x, f.y, f.z, f.w};
            #pragma unroll
            for (int j = 0; j < 4; ++j) {
                int idx = q * 4 + j;
                unsigned short hb = f2bf(vv[j]);
                if (idx < 8) p0.s[idx] = hb; else p1.s[idx - 8] = hb;
            }
        }
    } else {
        p0.v = make_uint4(0, 0, 0, 0);
        p1.v = make_uint4(0, 0, 0, 0);
    }
    uint4* dst = reinterpret_cast<uint4*>(&lds[srow * LDT + shalf * 16]);
    dst[0] = p0.v; dst[1] = p1.v;
}

__device__ __forceinline__ void stage_tile_split(unsigned short* lds_hi,
                                                 unsigned short* lds_lo,
                                                 const float* src,
                                                 bool valid, int srow, int shalf) {
    union { unsigned short s[8]; uint4 v; } h0, h1, l0, l1;
    if (valid) {
        const float4* s4 = reinterpret_cast<const float4*>(src);
        #pragma unroll
        for (int q = 0; q < 4; ++q) {
            float4 f = s4[q];
            float vv[4] = {f.x, f.y, f.z, f.w};
            #pragma unroll
            for (int j = 0; j < 4; ++j) {
                int idx = q * 4 + j;
                unsigned short hb = f2bf(vv[j]);
                unsigned short lb = f2bf(vv[j] - bf2f_bits(hb));
                if (idx < 8) { h0.s[idx] = hb; l0.s[idx] = lb; }
                else         { h1.s[idx - 8] = hb; l1.s[idx - 8] = lb; }
            }
        }
    } else {
        h0.v = make_uint4(0,0,0,0); h1.v = make_uint4(0,0,0,0);
        l0.v = make_uint4(0,0,0,0); l1.v = make_uint4(0,0,0,0);
    }
    uint4* dh = reinterpret_cast<uint4*>(&lds_hi[srow * LDT + shalf * 16]);
    dh[0] = h0.v; dh[1] = h1.v;
    uint4* dl = reinterpret_cast<uint4*>(&lds_lo[srow * LDT + shalf * 16]);
    dl[0] = l0.v; dl[1] = l1.v;
}

// ---- Lean all-bf16 MFMA GEMM with register prefetch (logits) ----
__global__ __launch_bounds__(256) void mfma_gemm_bf(const unsigned short* __restrict__ A,
                                                    const unsigned short* __restrict__ B,
                                                    const float* __restrict__ bias,
                                                    float* __restrict__ C,
                                                    int M, int N, int K) {
    __shared__ __align__(16) unsigned short As[MB * LDT];
    __shared__ __align__(16) unsigned short Bs[NB * LDT];
    int tid = threadIdx.x;
    int bm = blockIdx.y * MB, bn = blockIdx.x * NB;
    int srow = tid >> 1, shalf = tid & 1;
    int lane = tid & 63, w = tid >> 6;
    int wr = w >> 1, wc = w & 1;
    int r0 = (lane >> 4) * 4, c0 = lane & 15;
    int kb = (lane >> 4) * 8;

    bool bval = (bn + srow) < N;
    const unsigned short* Ap = A + (size_t)(bm + srow) * K + shalf * 16;
    const unsigned short* Bp = B + (size_t)(bn + srow) * K + shalf * 16;

    uint4 ra0, ra1, rb0, rb1;
    ra0 = reinterpret_cast<const uint4*>(Ap)[0];
    ra1 = reinterpret_cast<const uint4*>(Ap)[1];
    rb0 = make_uint4(0,0,0,0); rb1 = make_uint4(0,0,0,0);
    if (bval) {
        rb0 = reinterpret_cast<const uint4*>(Bp)[0];
        rb1 = reinterpret_cast<const uint4*>(Bp)[1];
    }

    f32x4 acc[4][4] = {};

    for (int kk = 0; kk < K; kk += KB) {
        uint4* da = reinterpret_cast<uint4*>(&As[srow * LDT + shalf * 16]);
        da[0] = ra0; da[1] = ra1;
        uint4* db = reinterpret_cast<uint4*>(&Bs[srow * LDT + shalf * 16]);
        db[0] = rb0; db[1] = rb1;
        __syncthreads();
        if (kk + KB < K) {
            const uint4* na = reinterpret_cast<const uint4*>(Ap + kk + KB);
            ra0 = na[0]; ra1 = na[1];
            if (bval) {
                const uint4* nb = reinterpret_cast<const uint4*>(Bp + kk + KB);
                rb0 = nb[0]; rb1 = nb[1];
            }
        }
        bf16x8 af[4], bf[4];
        #pragma unroll
        for (int m = 0; m < 4; ++m)
            af[m] = *reinterpret_cast<const bf16x8*>(&As[(wr * 64 + m * 16 + c0) * LDT + kb]);
        #pragma unroll
        for (int n = 0; n < 4; ++n)
            bf[n] = *reinterpret_cast<const bf16x8*>(&Bs[(wc * 64 + n * 16 + c0) * LDT + kb]);
        #pragma unroll
        for (int m = 0; m < 4; ++m)
            #pragma unroll
            for (int n = 0; n < 4; ++n)
                acc[m][n] = __builtin_amdgcn_mfma_f32_16x16x32_bf16(af[m], bf[n], acc[m][n], 0, 0, 0);
        __syncthreads();
    }

    #pragma unroll
    for (int n = 0; n < 4; ++n) {
        int col = bn + wc * 64 + n * 16 + c0;
        if (col < N) {
            float bv = bias ? bias[col] : 0.f;
            #pragma unroll
            for (int m = 0; m < 4; ++m)
                #pragma unroll
                for (int r = 0; r < 4; ++r) {
                    int row = bm + wr * 64 + m * 16 + r0 + r;
                    C[(size_t)row * N + col] = acc[m][n][r] + bv;
                }
        }
    }
}

// ---- Plain bf16 MFMA GEMM from fp32 (fallback logits) ----
template<int ACT, int RES>
__global__ __launch_bounds__(256) void mfma_gemm(const float* __restrict__ A,
                                                 const float* __restrict__ B,
                                                 const float* __restrict__ bias,
                                                 const float* __restrict__ res,
                                                 float* __restrict__ C,
                                                 int M, int N, int K) {
    __shared__ __align__(16) unsigned short As[MB * LDT];
    __shared__ __align__(16) unsigned short Bs[NB * LDT];
    int tid = threadIdx.x;
    int bm = blockIdx.y * MB, bn = blockIdx.x * NB;
    int srow = tid >> 1, shalf = tid & 1;
    int lane = tid & 63, w = tid >> 6;
    int wr = w >> 1, wc = w & 1;
    int r0 = (lane >> 4) * 4, c0 = lane & 15;
    int kb = (lane >> 4) * 8;

    f32x4 acc[4][4] = {};

    for (int kk = 0; kk < K; kk += KB) {
        stage_tile(As, A + (size_t)(bm + srow) * K + kk + shalf * 16, true, srow, shalf);
        bool bval = (bn + srow) < N;
        stage_tile(Bs, B + (size_t)(bn + srow) * K + kk + shalf * 16, bval, srow, shalf);
        __syncthreads();
        bf16x8 af[4], bf[4];
        #pragma unroll
        for (int m = 0; m < 4; ++m)
            af[m] = *reinterpret_cast<const bf16x8*>(&As[(wr * 64 + m * 16 + c0) * LDT + kb]);
        #pragma unroll
        for (int n = 0; n < 4; ++n)
            bf[n] = *reinterpret_cast<const bf16x8*>(&Bs[(wc * 64 + n * 16 + c0) * LDT + kb]);
        #pragma unroll
        for (int m = 0; m < 4; ++m)
            #pragma unroll
            for (int n = 0; n < 4; ++n)
                acc[m][n] = __builtin_amdgcn_mfma_f32_16x16x32_bf16(af[m], bf[n], acc[m][n], 0, 0, 0);
        __syncthreads();
    }

    #pragma unroll
    for (int n = 0; n < 4; ++n) {
        int col = bn + wc * 64 + n * 16 + c0;
        if (col < N) {
            float bv = bias ? bias[col] : 0.f;
            #pragma unroll
            for (int m = 0; m < 4; ++m) {
                #pragma unroll
                for (int r = 0; r < 4; ++r) {
                    int row = bm + wr * 64 + m * 16 + r0 + r;
                    float v = acc[m][n][r] + bv;
                    if (RES) v += res[(size_t)row * N + col];
                    if (ACT == 1) v = gelu_exact(v);
                    C[(size_t)row * N + col] = v;
                }
            }
        }
    }
}

// ---- Split-bf16 MFMA GEMM, K-SPLIT PARTIAL (dense) ----
__global__ __launch_bounds__(256) void mfma_gemm_sp_part(const float* __restrict__ A,
                                                         const float* __restrict__ B,
                                                         float* __restrict__ part,
                                                         int M, int N, int K, int KSPLIT) {
    __shared__ __align__(16) unsigned short Ah[MB * LDT];
    __shared__ __align__(16) unsigned short Al[MB * LDT];
    __shared__ __align__(16) unsigned short Bh[NB * LDT];
    __shared__ __align__(16) unsigned short Bl[NB * LDT];
    int tid = threadIdx.x;
    int bm = blockIdx.y * MB, bn = blockIdx.x * NB;
    int kc = blockIdx.z;
    int chunk = K / KSPLIT;
    int kbeg = kc * chunk;
    int srow = tid >> 1, shalf = tid & 1;
    int lane = tid & 63, w = tid >> 6;
    int wr = w >> 1, wc = w & 1;
    int r0 = (lane >> 4) * 4, c0 = lane & 15;
    int kb = (lane >> 4) * 8;

    f32x4 acc[4][4] = {};

    for (int kk = kbeg; kk < kbeg + chunk; kk += KB) {
        stage_tile_split(Ah, Al, A + (size_t)(bm + srow) * K + kk + shalf * 16, true, srow, shalf);
        stage_tile_split(Bh, Bl, B + (size_t)(bn + srow) * K + kk + shalf * 16, true, srow, shalf);
        __syncthreads();
        bf16x8 ah[4], al[4], bh[4], bl[4];
        #pragma unroll
        for (int m = 0; m < 4; ++m) {
            int o = (wr * 64 + m * 16 + c0) * LDT + kb;
            ah[m] = *reinterpret_cast<const bf16x8*>(&Ah[o]);
            al[m] = *reinterpret_cast<const bf16x8*>(&Al[o]);
        }
        #pragma unroll
        for (int n = 0; n < 4; ++n) {
            int o = (wc * 64 + n * 16 + c0) * LDT + kb;
            bh[n] = *reinterpret_cast<const bf16x8*>(&Bh[o]);
            bl[n] = *reinterpret_cast<const bf16x8*>(&Bl[o]);
        }
        #pragma unroll
        for (int m = 0; m < 4; ++m)
            #pragma unroll
            for (int n = 0; n < 4; ++n) {
                acc[m][n] = __builtin_amdgcn_mfma_f32_16x16x32_bf16(al[m], bh[n], acc[m][n], 0, 0, 0);
                acc[m][n] = __builtin_amdgcn_mfma_f32_16x16x32_bf16(ah[m], bl[n], acc[m][n], 0, 0, 0);
                acc[m][n] = __builtin_amdgcn_mfma_f32_16x16x32_bf16(ah[m], bh[n], acc[m][n], 0, 0, 0);
            }
        __syncthreads();
    }

    float* P = part + (size_t)kc * M * N;
    #pragma unroll
    for (int n = 0; n < 4; ++n) {
        int col = bn + wc * 64 + n * 16 + c0;
        #pragma unroll
        for (int m = 0; m < 4; ++m)
            #pragma unroll
            for (int r = 0; r < 4; ++r) {
                int row = bm + wr * 64 + m * 16 + r0 + r;
                P[(size_t)row * N + col] = acc[m][n][r];
            }
    }
}

// ---- Dense reduce: C = act(Σ parts + bias [+ res]) ----
template<int ACT, int RES>
__global__ __launch_bounds__(256) void reduce_dense(const float* __restrict__ part,
                                                    const float* __restrict__ bias,
                                                    const float* __restrict__ res,
                                                    float* __restrict__ C,
                                                    long MN, int N, int KSPLIT) {
    long stride = (long)gridDim.x * 256 * 4;
    for (long i = ((long)blockIdx.x * 256 + threadIdx.x) * 4; i < MN; i += stride) {
        float4 v = *reinterpret_cast<const float4*>(part + i);
        for (int kc = 1; kc < KSPLIT; ++kc) {
            float4 p = *reinterpret_cast<const float4*>(part + (size_t)kc * MN + i);
            v.x += p.x; v.y += p.y; v.z += p.z; v.w += p.w;
        }
        int col = (int)(i % N);
        float4 b = *reinterpret_cast<const float4*>(bias + col);
        v.x += b.x; v.y += b.y; v.z += b.z; v.w += b.w;
        if (RES) {
            float4 r = *reinterpret_cast<const float4*>(res + i);
            v.x += r.x; v.y += r.y; v.z += r.z; v.w += r.w;
        }
        if (ACT == 1) {
            v.x = gelu_exact(v.x); v.y = gelu_exact(v.y);
            v.z = gelu_exact(v.z); v.w = gelu_exact(v.w);
        }
        *reinterpret_cast<float4*>(C + i) = v;
    }
}

// ---------------- Flash attention, split-bf16 MFMA (router-safe) ----------------
// Block: (qt in [0,8), bh in [0,24)). 4 waves, wave w owns q-rows qt*64+w*16..+15.
#define LDA 72
__device__ __forceinline__ void stage16a(unsigned short* dh, unsigned short* dl,
                                         const float* src) {
    union { unsigned short s[8]; uint4 v; } h0, h1, l0, l1;
    const float4* s4 = reinterpret_cast<const float4*>(src);
    #pragma unroll
    for (int q = 0; q < 4; ++q) {
        float4 f = s4[q];
        float vv[4] = {f.x, f.y, f.z, f.w};
        #pragma unroll
        for (int j = 0; j < 4; ++j) {
            int idx = q * 4 + j;
            unsigned short hb = f2bf(vv[j]);
            unsigned short lb = f2bf(vv[j] - bf2f_bits(hb));
            if (idx < 8) { h0.s[idx] = hb; l0.s[idx] = lb; }
            else         { h1.s[idx - 8] = hb; l1.s[idx - 8] = lb; }
        }
    }
    reinterpret_cast<uint4*>(dh)[0] = h0.v; reinterpret_cast<uint4*>(dh)[1] = h1.v;
    reinterpret_cast<uint4*>(dl)[0] = l0.v; reinterpret_cast<uint4*>(dl)[1] = l1.v;
}

__global__ __launch_bounds__(256) void attn_flash(const float* __restrict__ qkv,
                                                  float* __restrict__ o_out) {
    int qt = blockIdx.x;
    int bh = blockIdx.y;
    int b = bh / NHm, hh = bh % NHm;
    const int g0 = b * Tm;
    const int hoff = hh * 64;
    int tid = threadIdx.x;
    int lane = tid & 63, w = tid >> 6;
    int c0 = lane & 15, hi4 = lane >> 4;
    int kb = hi4 * 8;

    __shared__ __align__(16) unsigned short Qh[64 * LDA], Ql[64 * LDA];
    __shared__ __align__(16) unsigned short KVh[64 * LDA], KVl[64 * LDA];
    __shared__ __align__(16) unsigned short Ph[4][16 * LDA], Pl[4][16 * LDA];

    // Stage Q tile (64 rows x 64 d) once
    {
        int srow = tid >> 2, q = tid & 3;
        stage16a(&Qh[srow * LDA + q * 16], &Ql[srow * LDA + q * 16],
                 qkv + (size_t)(g0 + qt * 64 + srow) * (3 * Dm) + hoff + q * 16);
    }
    __syncthreads();

    f32x4 acc_o[4] = {};
    float m_r[4] = {-1e30f, -1e30f, -1e30f, -1e30f};
    float l_r[4] = {0.f, 0.f, 0.f, 0.f};

    for (int kt = 0; kt <= qt; ++kt) {
        // stage K tile (64 k-rows x 64 d)
        {
            int srow = tid >> 2, q = tid & 3;
            stage16a(&KVh[srow * LDA + q * 16], &KVl[srow * LDA + q * 16],
                     qkv + (size_t)(g0 + kt * 64 + srow) * (3 * Dm) + Dm + hoff + q * 16);
        }
        __syncthreads();

        // S = Q·K^T (split-bf16)
        f32x4 sAcc[4] = {};
        #pragma unroll
        for (int kk2 = 0; kk2 < 64; kk2 += 32) {
            bf16x8 ah = *reinterpret_cast<const bf16x8*>(&Qh[(w * 16 + c0) * LDA + kk2 + kb]);
            bf16x8 al = *reinterpret_cast<const bf16x8*>(&Ql[(w * 16 + c0) * LDA + kk2 + kb]);
            #pragma unroll
            for (int n = 0; n < 4; ++n) {
                bf16x8 bh_ = *reinterpret_cast<const bf16x8*>(&KVh[(n * 16 + c0) * LDA + kk2 + kb]);
                bf16x8 bl_ = *reinterpret_cast<const bf16x8*>(&KVl[(n * 16 + c0) * LDA + kk2 + kb]);
                sAcc[n] = __builtin_amdgcn_mfma_f32_16x16x32_bf16(al, bh_, sAcc[n], 0, 0, 0);
                sAcc[n] = __builtin_amdgcn_mfma_f32_16x16x32_bf16(ah, bl_, sAcc[n], 0, 0, 0);
                sAcc[n] = __builtin_amdgcn_mfma_f32_16x16x32_bf16(ah, bh_, sAcc[n], 0, 0, 0);
            }
        }

        // scale + causal mask + online softmax
        float p[4][4];
        float smax[4] = {-3e38f, -3e38f, -3e38f, -3e38f};
        #pragma unroll
        for (int n = 0; n < 4; ++n)
            #pragma unroll
            for (int r = 0; r < 4; ++r) {
                float s = sAcc[n][r] * 0.125f;
                if (kt == qt) {
                    int kg = n * 16 + c0;
                    int qg = w * 16 + hi4 * 4 + r;
                    if (kg > qg) s = -3e38f;
                }
                p[n][r] = s;
                smax[r] = fmaxf(smax[r], s);
            }
        #pragma unroll
        for (int off = 1; off < 16; off <<= 1)
            #pragma unroll
            for (int r = 0; r < 4; ++r)
                smax[r] = fmaxf(smax[r], __shfl_xor(smax[r], off));
        float f_r[4], lsum[4];
        #pragma unroll
        for (int r = 0; r < 4; ++r) {
            float mn = fmaxf(m_r[r], smax[r]);
            f_r[r] = expf(m_r[r] - mn);
            m_r[r] = mn;
        }
        #pragma unroll
        for (int n = 0; n < 4; ++n)
            #pragma unroll
            for (int r = 0; r < 4; ++r)
                p[n][r] = expf(p[n][r] - m_r[r]);
        #pragma unroll
        for (int r = 0; r < 4; ++r)
            lsum[r] = p[0][r] + p[1][r] + p[2][r] + p[3][r];
        #pragma unroll
        for (int off = 1; off < 16; off <<= 1)
            #pragma unroll
            for (int r = 0; r < 4; ++r)
                lsum[r] += __shfl_xor(lsum[r], off);
        #pragma unroll
        for (int r = 0; r < 4; ++r)
            l_r[r] = l_r[r] * f_r[r] + lsum[r];
        #pragma unroll
        for (int n = 0; n < 4; ++n)
            #pragma unroll
            for (int r = 0; r < 4; ++r)
                acc_o[n][r] *= f_r[r];
        // write P (hi/lo) to wave-private LDS in A-operand layout
        #pragma unroll
        for (int n = 0; n < 4; ++n)
            #pragma unroll
            for (int r = 0; r < 4; ++r) {
                unsigned short hb = f2bf(p[n][r]);
                int o = (hi4 * 4 + r) * LDA + n * 16 + c0;
                Ph[w][o] = hb;
                Pl[w][o] = f2bf(p[n][r] - bf2f_bits(hb));
            }
        __syncthreads();

        // stage V^T tile (d-major, k-contiguous) into KV buffers
        {
            int d = lane, kg = w;
            #pragma unroll
            for (int k2 = 0; k2 < 16; ++k2) {
                float v = qkv[(size_t)(g0 + kt * 64 + kg * 16 + k2) * (3 * Dm) + 2 * Dm + hoff + d];
                unsigned short hb = f2bf(v);
                KVh[d * LDA + kg * 16 + k2] = hb;
                KVl[d * LDA + kg * 16 + k2] = f2bf(v - bf2f_bits(hb));
            }
        }
        __syncthreads();

        // O += P·V (split-bf16)
        #pragma unroll
        for (int kk2 = 0; kk2 < 64; kk2 += 32) {
            bf16x8 pah = *reinterpret_cast<const bf16x8*>(&Ph[w][c0 * LDA + kk2 + kb]);
            bf16x8 pal = *reinterpret_cast<const bf16x8*>(&Pl[w][c0 * LDA + kk2 + kb]);
            #pragma unroll
            for (int n = 0; n < 4; ++n) {
                bf16x8 vbh = *reinterpret_cast<const bf16x8*>(&KVh[(n * 16 + c0) * LDA + kk2 + kb]);
                bf16x8 vbl = *reinterpret_cast<const bf16x8*>(&KVl[(n * 16 + c0) * LDA + kk2 + kb]);
                acc_o[n] = __builtin_amdgcn_mfma_f32_16x16x32_bf16(pal, vbh, acc_o[n], 0, 0, 0);
                acc_o[n] = __builtin_amdgcn_mfma_f32_16x16x32_bf16(pah, vbl, acc_o[n], 0, 0, 0);
                acc_o[n] = __builtin_amdgcn_mfma_f32_16x16x32_bf16(pah, vbh, acc_o[n], 0, 0, 0);
            }
        }
        __syncthreads();   // KV reused next iteration
    }

    float inv[4];
    #pragma unroll
    for (int r = 0; r < 4; ++r) inv[r] = 1.0f / l_r[r];
    #pragma unroll
    for (int n = 0; n < 4; ++n)
        #pragma unroll
        for (int r = 0; r < 4; ++r) {
            int row = g0 + qt * 64 + w * 16 + hi4 * 4 + r;
            o_out[(size_t)row * Dm + hoff + n * 16 + c0] = acc_o[n][r] * inv[r];
        }
}

// ---------------- MoE router (fp32 exact) ----------------
__global__ __launch_bounds__(256) void router_kernel(const float* __restrict__ xn,
                                                     const float* __restrict__ gw,
                                                     int* __restrict__ topi,
                                                     float* __restrict__ topw) {
    int t = blockIdx.x * 256 + threadIdx.x;
    if (t >= NT) return;
    const float* x = xn + (size_t)t * Dm;
    float l[Em];
    #pragma unroll
    for (int e = 0; e < Em; ++e) {
        const float* w = gw + (size_t)e * Dm;
        float dot = 0.f;
        for (int d = 0; d < Dm; ++d) dot += w[d] * x[d];
        l[e] = dot;
    }
    int i1 = 0;
    #pragma unroll
    for (int e = 1; e < Em; ++e) if (l[e] > l[i1]) i1 = e;
    int i2 = (i1 == 0) ? 1 : 0;
    #pragma unroll
    for (int e = 0; e < Em; ++e) if (e != i1 && l[e] > l[i2]) i2 = e;
    float w1 = 1.0f / (1.0f + expf(l[i2] - l[i1]));
    topi[t * 2] = i1; topi[t * 2 + 1] = i2;
    topw[t * 2] = w1; topw[t * 2 + 1] = 1.0f - w1;
}

// ---------------- Route build ----------------
__global__ __launch_bounds__(256) void route_build_kernel(const int* __restrict__ topi,
                                                          int* __restrict__ g_cnt,
                                                          int* __restrict__ g_off,
                                                          int* __restrict__ bucket) {
    __shared__ int cnt[Em], off[Em], pos[Em];
    int tid = threadIdx.x;
    if (tid < Em) cnt[tid] = 0;
    __syncthreads();
    for (int ts = tid; ts < NAS; ts += 256) atomicAdd(&cnt[topi[ts]], 1);
    __syncthreads();
    if (tid == 0) {
        int acc = 0;
        for (int e = 0; e < Em; ++e) { off[e] = acc; pos[e] = acc; acc += cnt[e]; }
    }
    __syncthreads();
    for (int ts = tid; ts < NAS; ts += 256) {
        int e = topi[ts];
        int p = atomicAdd(&pos[e], 1);
        bucket[p] = ts;
    }
    if (tid < Em) { g_cnt[tid] = cnt[tid]; g_off[tid] = off[tid]; }
}

// ---------------- Grouped MoE GEMM1 (MFMA), SPLIT template ----------------
template<int SPLIT>
__global__ __launch_bounds__(256) void moe_mfma_gemm1(const float* __restrict__ xn,
                                                      const float* __restrict__ W1all,
                                                      const float* __restrict__ B1all,
                                                      const int* __restrict__ bucket,
                                                      const int* __restrict__ cnt,
                                                      const int* __restrict__ off,
                                                      float* __restrict__ heg) {
    int e = blockIdx.z;
    int count = cnt[e];
    int mbase = blockIdx.y * MB;
    if (mbase >= count) return;
    int base = off[e];

    __shared__ __align__(16) unsigned short Ah[MB * LDT];
    __shared__ __align__(16) unsigned short Bh[NB * LDT];
    __shared__ __align__(16) unsigned short Al[SPLIT ? MB * LDT : 8];
    __shared__ __align__(16) unsigned short Bl[SPLIT ? NB * LDT : 8];
    __shared__ int toks[MB];
    int tid = threadIdx.x;
    int bn = blockIdx.x * NB;
    int srow = tid >> 1, shalf = tid & 1;
    int lane = tid & 63, w = tid >> 6;
    int wr = w >> 1, wc = w & 1;
    int r0 = (lane >> 4) * 4, c0 = lane & 15;
    int kb = (lane >> 4) * 8;
    if (tid < MB) {
        int p = mbase + tid;
        toks[tid] = (p < count) ? (bucket[base + p] >> 1) : -1;
    }
    __syncthreads();

    f32x4 acc[4][4] = {};
    const float* W = W1all + (size_t)e * Hm * Dm;
    int t = toks[srow];
    for (int kk = 0; kk < Dm; kk += KB) {
        if (SPLIT) {
            stage_tile_split(Ah, Al, xn + (size_t)t * Dm + kk + shalf * 16, t >= 0, srow, shalf);
            stage_tile_split(Bh, Bl, W + (size_t)(bn + srow) * Dm + kk + shalf * 16, true, srow, shalf);
        } else {
            stage_tile(Ah, xn + (size_t)t * Dm + kk + shalf * 16, t >= 0, srow, shalf);
            stage_tile(Bh, W + (size_t)(bn + srow) * Dm + kk + shalf * 16, true, srow, shalf);
        }
        __syncthreads();
        bf16x8 ah[4], bh[4], al[4], bl[4];
        #pragma unroll
        for (int m = 0; m < 4; ++m) {
            int o = (wr * 64 + m * 16 + c0) * LDT + kb;
            ah[m] = *reinterpret_cast<const bf16x8*>(&Ah[o]);
            if (SPLIT) al[m] = *reinterpret_cast<const bf16x8*>(&Al[o]);
        }
        #pragma unroll
        for (int n = 0; n < 4; ++n) {
            int o = (wc * 64 + n * 16 + c0) * LDT + kb;
            bh[n] = *reinterpret_cast<const bf16x8*>(&Bh[o]);
            if (SPLIT) bl[n] = *reinterpret_cast<const bf16x8*>(&Bl[o]);
        }
        #pragma unroll
        for (int m = 0; m < 4; ++m)
            #pragma unroll
            for (int n = 0; n < 4; ++n) {
                if (SPLIT) {
                    acc[m][n] = __builtin_amdgcn_mfma_f32_16x16x32_bf16(al[m], bh[n], acc[m][n], 0, 0, 0);
                    acc[m][n] = __builtin_amdgcn_mfma_f32_16x16x32_bf16(ah[m], bl[n], acc[m][n], 0, 0, 0);
                }
                acc[m][n] = __builtin_amdgcn_mfma_f32_16x16x32_bf16(ah[m], bh[n], acc[m][n], 0, 0, 0);
            }
        __syncthreads();
    }

    const float* b1 = B1all + (size_t)e * Hm;
    #pragma unroll
    for (int n = 0; n < 4; ++n) {
        int col = bn + wc * 64 + n * 16 + c0;
        float bv = b1[col];
        #pragma unroll
        for (int m = 0; m < 4; ++m) {
            #pragma unroll
            for (int r = 0; r < 4; ++r) {
                int p = mbase + wr * 64 + m * 16 + r0 + r;
                if (p < count)
                    heg[(size_t)(base + p) * Hm + col] = gelu_exact(acc[m][n][r] + bv);
            }
        }
    }
}

// ---------------- Grouped MoE GEMM2, K-SPLIT PARTIAL ----------------
template<int SPLIT>
__global__ __launch_bounds__(256) void moe_gemm2_part(const float* __restrict__ heg,
                                                      const float* __restrict__ W2all,
                                                      const int* __restrict__ cnt,
                                                      const int* __restrict__ off,
                                                      float* __restrict__ part,
                                                      int KSPLIT) {
    int e = blockIdx.z;
    int count = cnt[e];
    int my = blockIdx.y;
    int kc = my % KSPLIT, mb = my / KSPLIT;
    int mbase = mb * MB;
    if (mbase >= count) return;
    int base = off[e];
    int chunk = Hm / KSPLIT;
    int kbeg = kc * chunk;

    __shared__ __align__(16) unsigned short Ah[MB * LDT];
    __shared__ __align__(16) unsigned short Bh[NB * LDT];
    __shared__ __align__(16) unsigned short Al[SPLIT ? MB * LDT : 8];
    __shared__ __align__(16) unsigned short Bl[SPLIT ? NB * LDT : 8];
    int tid = threadIdx.x;
    int bn = blockIdx.x * NB;
    int srow = tid >> 1, shalf = tid & 1;
    int lane = tid & 63, w = tid >> 6;
    int wr = w >> 1, wc = w & 1;
    int r0 = (lane >> 4) * 4, c0 = lane & 15;
    int kb = (lane >> 4) * 8;

    f32x4 acc[4][4] = {};
    const float* W = W2all + (size_t)e * Dm * Hm;
    bool aval = (mbase + srow) < count;
    for (int kk = kbeg; kk < kbeg + chunk; kk += KB) {
        if (SPLIT) {
            stage_tile_split(Ah, Al, heg + (size_t)(base + mbase + srow) * Hm + kk + shalf * 16, aval, srow, shalf);
            stage_tile_split(Bh, Bl, W + (size_t)(bn + srow) * Hm + kk + shalf * 16, true, srow, shalf);
        } else {
            stage_tile(Ah, heg + (size_t)(base + mbase + srow) * Hm + kk + shalf * 16, aval, srow, shalf);
            stage_tile(Bh, W + (size_t)(bn + srow) * Hm + kk + shalf * 16, true, srow, shalf);
        }
        __syncthreads();
        bf16x8 ah[4], bh[4], al[4], bl[4];
        #pragma unroll
        for (int m = 0; m < 4; ++m) {
            int o = (wr * 64 + m * 16 + c0) * LDT + kb;
            ah[m] = *reinterpret_cast<const bf16x8*>(&Ah[o]);
            if (SPLIT) al[m] = *reinterpret_cast<const bf16x8*>(&Al[o]);
        }
        #pragma unroll
        for (int n = 0; n < 4; ++n) {
            int o = (wc * 64 + n * 16 + c0) * LDT + kb;
            bh[n] = *reinterpret_cast<const bf16x8*>(&Bh[o]);
            if (SPLIT) bl[n] = *reinterpret_cast<const bf16x8*>(&Bl[o]);
        }
        #pragma unroll
        for (int m = 0; m < 4; ++m)
            #pragma unroll
            for (int n = 0; n < 4; ++n) {
                if (SPLIT) {
                    acc[m][n] = __builtin_amdgcn_mfma_f32_16x16x32_bf16(al[m], bh[n], acc[m][n], 0, 0, 0);
                    acc[m][n] = __builtin_amdgcn_mfma_f32_16x16x32_bf16(ah[m], bl[n], acc[m][n], 0, 0, 0);
                }
                acc[m][n] = __builtin_amdgcn_mfma_f32_16x16x32_bf16(ah[m], bh[n], acc[m][n], 0, 0, 0);
            }
        __syncthreads();
    }

    float* P = part + (size_t)kc * NAS * Dm;
    #pragma unroll
    for (int n = 0; n < 4; ++n) {
        int col = bn + wc * 64 + n * 16 + c0;
        #pragma unroll
        for (int m = 0; m < 4; ++m) {
            #pragma unroll
            for (int r = 0; r < 4; ++r) {
                int p = mbase + wr * 64 + m * 16 + r0 + r;
                if (p < count)
                    P[(size_t)(base + p) * Dm + col] = acc[m][n][r];
            }
        }
    }
}

// ---- MoE reduce: ye[ts] = topw[ts] * (Σ parts + b2[e]) ----
__global__ __launch_bounds__(256) void moe_reduce(const float* __restrict__ part,
                                                  const float* __restrict__ B2all,
                                                  const int* __restrict__ bucket,
                                                  const int* __restrict__ topi,
                                                  const float* __restrict__ topw,
                                                  float* __restrict__ ye, int KSPLIT) {
    const long MN = (long)NAS * Dm;
    long stride = (long)gridDim.x * 256 * 4;
    for (long i = ((long)blockIdx.x * 256 + threadIdx.x) * 4; i < MN; i += stride) {
        int p = (int)(i / Dm), col = (int)(i % Dm);
        int ts = bucket[p];
        int e = topi[ts];
        float wgt = topw[ts];
        float4 v = *reinterpret_cast<const float4*>(part + i);
        for (int kc = 1; kc < KSPLIT; ++kc) {
            float4 q = *reinterpret_cast<const float4*>(part + (size_t)kc * MN + i);
            v.x += q.x; v.y += q.y; v.z += q.z; v.w += q.w;
        }
        float4 b = *reinterpret_cast<const float4*>(B2all + (size_t)e * Dm + col);
        float4 o;
        o.x = wgt * (v.x + b.x); o.y = wgt * (v.y + b.y);
        o.z = wgt * (v.z + b.z); o.w = wgt * (v.w + b.w);
        *reinterpret_cast<float4*>(ye + (size_t)ts * Dm + col) = o;
    }
}

__global__ __launch_bounds__(256) void combine_kernel(float* __restrict__ h,
                                                      const float* __restrict__ ye) {
    int i = blockIdx.x * 256 + threadIdx.x;
    if (i < NT * Dm) {
        int t = i / Dm, d = i - t * Dm;
        h[i] += ye[(size_t)(t * 2) * Dm + d] + ye[(size_t)(t * 2 + 1) * Dm + d];
    }
}

// ---------------- Launch ----------------
extern "C" void kernel_launch(void* const* d_in, const int* in_sizes, int n_in,
                              void* d_out, int out_size, void* d_ws, size_t ws_size,
                              hipStream_t stream) {
    const int*   x    = (const int*)d_in[0];
    const float* emb  = (const float*)d_in[1];
    const float* wqkv = (const float*)d_in[2];
    const float* bqkv = (const float*)d_in[3];
    const float* wo   = (const float*)d_in[4];
    const float* bo   = (const float*)d_in[5];
    const float* ln1g = (const float*)d_in[6];
    const float* ln1b = (const float*)d_in[7];
    const float* ln2g = (const float*)d_in[8];
    const float* ln2b = (const float*)d_in[9];
    const float* sw1  = (const float*)d_in[10];
    const float* sb1  = (const float*)d_in[11];
    const float* sw2  = (const float*)d_in[12];
    const float* sb2  = (const float*)d_in[13];
    const float* gw   = (const float*)d_in[14];
    const float* mw1  = (const float*)d_in[15];
    const float* mb1  = (const float*)d_in[16];
    const float* mw2  = (const float*)d_in[17];
    const float* mb2  = (const float*)d_in[18];
    const float* lnfg = (const float*)d_in[19];
    const float* lnfb = (const float*)d_in[20];

    const size_t n_h    = (size_t)NT * Dm;
    const size_t n_qkv  = (size_t)NT * 3 * Dm;
    const size_t n_ffh  = (size_t)NT * Hm;
    const size_t n_ye   = (size_t)NAS * Dm;
    const size_t n_heg  = (size_t)NAS * Hm;
    const size_t n_xn   = (size_t)NT * Dm;
    const size_t n_part = (size_t)NT * Hm * 2;
    const size_t n_embbf = (size_t)Vm * Dm / 2;
    const size_t n_xnbf  = (size_t)NT * Dm / 2;
    const size_t n_big   = n_h + n_qkv + n_h + n_ffh + n_ye + n_heg + n_part;

    size_t wsf = ws_size / sizeof(float);

    float* w = (float*)d_ws;
    float* xn   = w;            w += n_xn;
    float* topw = w;            w += NAS;
    int*   topi = (int*)w;      w += NAS;
    int*   bucket = (int*)w;    w += NAS;
    int*   e_cnt = (int*)w;     w += 8;
    int*   e_off = (int*)w;     w += 8;
    size_t used = (size_t)(w - (float*)d_ws);

    unsigned short* emb_bf = nullptr;
    unsigned short* xn_bf  = nullptr;
    if (wsf >= used + n_embbf + n_xnbf + 64) {
        emb_bf = (unsigned short*)w;  w += n_embbf;
        xn_bf  = (unsigned short*)w;  w += n_xnbf;
        used = (size_t)(w - (float*)d_ws);
    }

    float *h, *qkv, *attno, *ffh, *ye, *heg, *part;
    if (wsf >= used + n_big + 64) {
        float* a = w;
        h = a;      a += n_h;
        qkv = a;    a += n_qkv;
        attno = a;  a += n_h;
        ffh = a;    a += n_ffh;
        ye = a;     a += n_ye;
        heg = a;    a += n_heg;
        part = a;
    } else {
        float* a = (float*)d_out;
        h = a;      a += n_h;
        qkv = a;    a += n_qkv;
        attno = a;  a += n_h;
        ffh = a;    a += n_ffh;
        ye = a;     a += n_ye;
        heg = a;    a += n_heg;
        part = a;
    }

    if (emb_bf) {
        long n = (long)Vm * Dm;
        cvt_bf16_kernel<<<(unsigned)((n / 8 + 255) / 256), 256, 0, stream>>>(emb, emb_bf, n);
    }

    embed_kernel<<<NT, 256, 0, stream>>>(x, emb, h);

    const int RBLK = 2048;
    int std_i = 0, moe_i = 0;
    for (int l = 0; l < Lm; ++l) {
        ln_kernel<<<NT, 256, 0, stream>>>(h, ln1g + l * Dm, ln1b + l * Dm, xn);
        mfma_gemm_sp_part<<<dim3((3 * Dm) / NB, NT / MB, 2), 256, 0, stream>>>(
            xn, wqkv + (size_t)l * 3 * Dm * Dm, part, NT, 3 * Dm, Dm, 2);
        reduce_dense<0,0><<<RBLK, 256, 0, stream>>>(
            part, bqkv + (size_t)l * 3 * Dm, nullptr, qkv, (long)NT * 3 * Dm, 3 * Dm, 2);
        attn_flash<<<dim3(Tm / 64, Bm * NHm), 256, 0, stream>>>(qkv, attno);
        mfma_gemm_sp_part<<<dim3(Dm / NB, NT / MB, 4), 256, 0, stream>>>(
            attno, wo + (size_t)l * Dm * Dm, part, NT, Dm, Dm, 4);
        reduce_dense<0,1><<<RBLK, 256, 0, stream>>>(
            part, bo + (size_t)l * Dm, h, h, (long)NT * Dm, Dm, 4);

        ln_kernel<<<NT, 256, 0, stream>>>(h, ln2g + l * Dm, ln2b + l * Dm, xn);
        if (l == 1 || l == 3) {
            router_kernel<<<(NT + 255) / 256, 256, 0, stream>>>(
                xn, gw + (size_t)moe_i * Em * Dm, topi, topw);
            route_build_kernel<<<1, 256, 0, stream>>>(topi, e_cnt, e_off, bucket);
            if (l == 3) {
                moe_mfma_gemm1<0><<<dim3(Hm / NB, NAS / MB, Em), 256, 0, stream>>>(
                    xn, mw1 + (size_t)moe_i * Em * Hm * Dm, mb1 + (size_t)moe_i * Em * Hm,
                    bucket, e_cnt, e_off, heg);
                moe_gemm2_part<0><<<dim3(Dm / NB, (NAS / MB) * 4, Em), 256, 0, stream>>>(
                    heg, mw2 + (size_t)moe_i * Em * Dm * Hm, e_cnt, e_off, part, 4);
            } else {
                moe_mfma_gemm1<1><<<dim3(Hm / NB, NAS / MB, Em), 256, 0, stream>>>(
                    xn, mw1 + (size_t)moe_i * Em * Hm * Dm, mb1 + (size_t)moe_i * Em * Hm,
                    bucket, e_cnt, e_off, heg);
                moe_gemm2_part<1><<<dim3(Dm / NB, (NAS / MB) * 4, Em), 256, 0, stream>>>(
                    heg, mw2 + (size_t)moe_i * Em * Dm * Hm, e_cnt, e_off, part, 4);
            }
            moe_reduce<<<RBLK, 256, 0, stream>>>(
                part, mb2 + (size_t)moe_i * Em * Dm, bucket, topi, topw, ye, 4);
            combine_kernel<<<(NT * Dm) / 256, 256, 0, stream>>>(h, ye);
            moe_i++;
        } else {
            mfma_gemm_sp_part<<<dim3(Hm / NB, NT / MB, 2), 256, 0, stream>>>(
                xn, sw1 + (size_t)std_i * Hm * Dm, part, NT, Hm, Dm, 2);
            reduce_dense<1,0><<<RBLK, 256, 0, stream>>>(
                part, sb1 + (size_t)std_i * Hm, nullptr, ffh, (long)NT * Hm, Hm, 2);
            mfma_gemm_sp_part<<<dim3(Dm / NB, NT / MB, 8), 256, 0, stream>>>(
                ffh, sw2 + (size_t)std_i * Dm * Hm, part, NT, Dm, Hm, 8);
            reduce_dense<0,1><<<RBLK, 256, 0, stream>>>(
                part, sb2 + (size_t)std_i * Dm, h, h, (long)NT * Dm, Dm, 8);
            std_i++;
        }
    }

    ln_kernel<<<NT, 256, 0, stream>>>(h, lnfg, lnfb, xn);
    if (emb_bf) {
        long n = (long)NT * Dm;
        cvt_bf16_kernel<<<(unsigned)((n / 8 + 255) / 256), 256, 0, stream>>>(xn, xn_bf, n);
        mfma_gemm_bf<<<dim3((Vm + NB - 1) / NB, NT / MB), 256, 0, stream>>>(
            xn_bf, emb_bf, nullptr, (float*)d_out, NT, Vm, Dm);
    } else {
        mfma_gemm<0,0><<<dim3((Vm + NB - 1) / NB, NT / MB), 256, 0, stream>>>(
            xn, emb, nullptr, nullptr, (float*)d_out, NT, Vm, Dm);
    }
}

// Round 12
// 1493.804 us; speedup vs baseline: 8.6620x; 1.0022x over previous
//
#include <hip/hip_runtime.h>
#include <hip/hip_bf16.h>
#include <cstdint>
#include <cstddef>

// ---- Model constants ----
#define Dm   768
#define NHm  12
#define Lm   4
#define Em   8
#define Vm   50257
#define Hm   3072
#define Tm   512
#define Bm   2
#define NT   (Bm*Tm)      // 1024 tokens
#define NAS  (NT*2)       // 2048 expert assignments

typedef float f32x4 __attribute__((ext_vector_type(4)));
typedef short bf16x8 __attribute__((ext_vector_type(8)));

__device__ __forceinline__ float gelu_exact(float x) {
    return 0.5f * x * (1.0f + erff(x * 0.70710678118654752440f));
}

__device__ __forceinline__ unsigned short f2bf(float f) {
    __hip_bfloat16 h = __float2bfloat16(f);
    union { __hip_bfloat16 h; unsigned short s; } c; c.h = h; return c.s;
}
__device__ __forceinline__ float bf2f_bits(unsigned short b) {
    union { unsigned u; float f; } c; c.u = ((unsigned)b) << 16; return c.f;
}

// ---------------- fp32 -> bf16 bulk convert ----------------
__global__ __launch_bounds__(256) void cvt_bf16_kernel(const float* __restrict__ in,
                                                       unsigned short* __restrict__ out,
                                                       long n) {
    long i = ((long)blockIdx.x * 256 + threadIdx.x) * 8;
    if (i + 8 <= n) {
        const float4* s4 = reinterpret_cast<const float4*>(in + i);
        float4 f0 = s4[0], f1 = s4[1];
        union { unsigned short s[8]; uint4 v; } p;
        p.s[0] = f2bf(f0.x); p.s[1] = f2bf(f0.y); p.s[2] = f2bf(f0.z); p.s[3] = f2bf(f0.w);
        p.s[4] = f2bf(f1.x); p.s[5] = f2bf(f1.y); p.s[6] = f2bf(f1.z); p.s[7] = f2bf(f1.w);
        *reinterpret_cast<uint4*>(out + i) = p.v;
    } else {
        for (long j = i; j < n; ++j) out[j] = f2bf(in[j]);
    }
}

// ---------------- Embedding + sinusoidal PE ----------------
__global__ __launch_bounds__(256) void embed_kernel(const int* __restrict__ x,
                                                    const float* __restrict__ emb,
                                                    float* __restrict__ h) {
    int g = blockIdx.x;
    int tid = threadIdx.x;
    int tok = x[g];
    int pos = g % Tm;
    const float* erow = emb + (size_t)tok * Dm;
    for (int d = tid; d < Dm; d += 256) {
        int i2 = (d >> 1) * 2;
        float div = expf(-logf(10000.0f) * (float)i2 / (float)Dm);
        float a = (float)pos * div;
        float pe = (d & 1) ? cosf(a) : sinf(a);
        h[(size_t)g * Dm + d] = erow[d] + pe;
    }
}

// ---------------- LayerNorm ----------------
__global__ __launch_bounds__(256) void ln_kernel(const float* __restrict__ in,
                                                 const float* __restrict__ g,
                                                 const float* __restrict__ b,
                                                 float* __restrict__ out) {
    int t = blockIdx.x, tid = threadIdx.x;
    const float* x = in + (size_t)t * Dm;
    float v0 = x[tid], v1 = x[tid + 256], v2 = x[tid + 512];
    __shared__ float red[256];
    red[tid] = v0 + v1 + v2;
    __syncthreads();
    for (int off = 128; off > 0; off >>= 1) {
        if (tid < off) red[tid] += red[tid + off];
        __syncthreads();
    }
    float mean = red[0] * (1.0f / Dm);
    __syncthreads();
    float d0 = v0 - mean, d1 = v1 - mean, d2 = v2 - mean;
    red[tid] = d0 * d0 + d1 * d1 + d2 * d2;
    __syncthreads();
    for (int off = 128; off > 0; off >>= 1) {
        if (tid < off) red[tid] += red[tid + off];
        __syncthreads();
    }
    float inv = rsqrtf(red[0] * (1.0f / Dm) + 1e-5f);
    float* o = out + (size_t)t * Dm;
    o[tid]       = d0 * inv * g[tid]       + b[tid];
    o[tid + 256] = d1 * inv * g[tid + 256] + b[tid + 256];
    o[tid + 512] = d2 * inv * g[tid + 512] + b[tid + 512];
}

// ============ MFMA GEMM machinery ============
#define MB 128
#define NB 128
#define KB 32
#define LDT 40

__device__ __forceinline__ void stage_tile(unsigned short* lds, const float* src,
                                           bool valid, int srow, int shalf) {
    union { unsigned short s[8]; uint4 v; } p0, p1;
    if (valid) {
        const float4* s4 = reinterpret_cast<const float4*>(src);
        #pragma unroll
        for (int q = 0; q < 4; ++q) {
            float4 f = s4[q];
            float vv[4] = {f.x, f.y, f.z, f.w};
            #pragma unroll
            for (int j = 0; j < 4; ++j) {
                int idx = q * 4 + j;
                unsigned short hb = f2bf(vv[j]);
                if (idx < 8) p0.s[idx] = hb; else p1.s[idx - 8] = hb;
            }
        }
    } else {
        p0.v = make_uint4(0, 0, 0, 0);
        p1.v = make_uint4(0, 0, 0, 0);
    }
    uint4* dst = reinterpret_cast<uint4*>(&lds[srow * LDT + shalf * 16]);
    dst[0] = p0.v; dst[1] = p1.v;
}

__device__ __forceinline__ void stage_tile_split(unsigned short* lds_hi,
                                                 unsigned short* lds_lo,
                                                 const float* src,
                                                 bool valid, int srow, int shalf) {
    union { unsigned short s[8]; uint4 v; } h0, h1, l0, l1;
    if (valid) {
        const float4* s4 = reinterpret_cast<const float4*>(src);
        #pragma unroll
        for (int q = 0; q < 4; ++q) {
            float4 f = s4[q];
            float vv[4] = {f.x, f.y, f.z, f.w};
            #pragma unroll
            for (int j = 0; j < 4; ++j) {
                int idx = q * 4 + j;
                unsigned short hb = f2bf(vv[j]);
                unsigned short lb = f2bf(vv[j] - bf2f_bits(hb));
                if (idx < 8) { h0.s[idx] = hb; l0.s[idx] = lb; }
                else         { h1.s[idx - 8] = hb; l1.s[idx - 8] = lb; }
            }
        }
    } else {
        h0.v = make_uint4(0,0,0,0); h1.v = make_uint4(0,0,0,0);
        l0.v = make_uint4(0,0,0,0); l1.v = make_uint4(0,0,0,0);
    }
    uint4* dh = reinterpret_cast<uint4*>(&lds_hi[srow * LDT + shalf * 16]);
    dh[0] = h0.v; dh[1] = h1.v;
    uint4* dl = reinterpret_cast<uint4*>(&lds_lo[srow * LDT + shalf * 16]);
    dl[0] = l0.v; dl[1] = l1.v;
}

// ---- Lean all-bf16 MFMA GEMM with register prefetch (logits) ----
// Grid: x = m-tiles (innermost, 8) so concurrent blocks share the B panel
// (L2/L3 locality); y = n-tiles.
__global__ __launch_bounds__(256) void mfma_gemm_bf(const unsigned short* __restrict__ A,
                                                    const unsigned short* __restrict__ B,
                                                    const float* __restrict__ bias,
                                                    float* __restrict__ C,
                                                    int M, int N, int K) {
    __shared__ __align__(16) unsigned short As[MB * LDT];
    __shared__ __align__(16) unsigned short Bs[NB * LDT];
    int tid = threadIdx.x;
    int bm = blockIdx.x * MB, bn = blockIdx.y * NB;
    int srow = tid >> 1, shalf = tid & 1;
    int lane = tid & 63, w = tid >> 6;
    int wr = w >> 1, wc = w & 1;
    int r0 = (lane >> 4) * 4, c0 = lane & 15;
    int kb = (lane >> 4) * 8;

    bool bval = (bn + srow) < N;
    const unsigned short* Ap = A + (size_t)(bm + srow) * K + shalf * 16;
    const unsigned short* Bp = B + (size_t)(bn + srow) * K + shalf * 16;

    uint4 ra0, ra1, rb0, rb1;
    ra0 = reinterpret_cast<const uint4*>(Ap)[0];
    ra1 = reinterpret_cast<const uint4*>(Ap)[1];
    rb0 = make_uint4(0,0,0,0); rb1 = make_uint4(0,0,0,0);
    if (bval) {
        rb0 = reinterpret_cast<const uint4*>(Bp)[0];
        rb1 = reinterpret_cast<const uint4*>(Bp)[1];
    }

    f32x4 acc[4][4] = {};

    for (int kk = 0; kk < K; kk += KB) {
        uint4* da = reinterpret_cast<uint4*>(&As[srow * LDT + shalf * 16]);
        da[0] = ra0; da[1] = ra1;
        uint4* db = reinterpret_cast<uint4*>(&Bs[srow * LDT + shalf * 16]);
        db[0] = rb0; db[1] = rb1;
        __syncthreads();
        if (kk + KB < K) {
            const uint4* na = reinterpret_cast<const uint4*>(Ap + kk + KB);
            ra0 = na[0]; ra1 = na[1];
            if (bval) {
                const uint4* nb = reinterpret_cast<const uint4*>(Bp + kk + KB);
                rb0 = nb[0]; rb1 = nb[1];
            }
        }
        bf16x8 af[4], bf[4];
        #pragma unroll
        for (int m = 0; m < 4; ++m)
            af[m] = *reinterpret_cast<const bf16x8*>(&As[(wr * 64 + m * 16 + c0) * LDT + kb]);
        #pragma unroll
        for (int n = 0; n < 4; ++n)
            bf[n] = *reinterpret_cast<const bf16x8*>(&Bs[(wc * 64 + n * 16 + c0) * LDT + kb]);
        #pragma unroll
        for (int m = 0; m < 4; ++m)
            #pragma unroll
            for (int n = 0; n < 4; ++n)
                acc[m][n] = __builtin_amdgcn_mfma_f32_16x16x32_bf16(af[m], bf[n], acc[m][n], 0, 0, 0);
        __syncthreads();
    }

    #pragma unroll
    for (int n = 0; n < 4; ++n) {
        int col = bn + wc * 64 + n * 16 + c0;
        if (col < N) {
            float bv = bias ? bias[col] : 0.f;
            #pragma unroll
            for (int m = 0; m < 4; ++m)
                #pragma unroll
                for (int r = 0; r < 4; ++r) {
                    int row = bm + wr * 64 + m * 16 + r0 + r;
                    C[(size_t)row * N + col] = acc[m][n][r] + bv;
                }
        }
    }
}

// ---- Plain bf16 MFMA GEMM from fp32 (fallback logits) ----
template<int ACT, int RES>
__global__ __launch_bounds__(256) void mfma_gemm(const float* __restrict__ A,
                                                 const float* __restrict__ B,
                                                 const float* __restrict__ bias,
                                                 const float* __restrict__ res,
                                                 float* __restrict__ C,
                                                 int M, int N, int K) {
    __shared__ __align__(16) unsigned short As[MB * LDT];
    __shared__ __align__(16) unsigned short Bs[NB * LDT];
    int tid = threadIdx.x;
    int bm = blockIdx.y * MB, bn = blockIdx.x * NB;
    int srow = tid >> 1, shalf = tid & 1;
    int lane = tid & 63, w = tid >> 6;
    int wr = w >> 1, wc = w & 1;
    int r0 = (lane >> 4) * 4, c0 = lane & 15;
    int kb = (lane >> 4) * 8;

    f32x4 acc[4][4] = {};

    for (int kk = 0; kk < K; kk += KB) {
        stage_tile(As, A + (size_t)(bm + srow) * K + kk + shalf * 16, true, srow, shalf);
        bool bval = (bn + srow) < N;
        stage_tile(Bs, B + (size_t)(bn + srow) * K + kk + shalf * 16, bval, srow, shalf);
        __syncthreads();
        bf16x8 af[4], bf[4];
        #pragma unroll
        for (int m = 0; m < 4; ++m)
            af[m] = *reinterpret_cast<const bf16x8*>(&As[(wr * 64 + m * 16 + c0) * LDT + kb]);
        #pragma unroll
        for (int n = 0; n < 4; ++n)
            bf[n] = *reinterpret_cast<const bf16x8*>(&Bs[(wc * 64 + n * 16 + c0) * LDT + kb]);
        #pragma unroll
        for (int m = 0; m < 4; ++m)
            #pragma unroll
            for (int n = 0; n < 4; ++n)
                acc[m][n] = __builtin_amdgcn_mfma_f32_16x16x32_bf16(af[m], bf[n], acc[m][n], 0, 0, 0);
        __syncthreads();
    }

    #pragma unroll
    for (int n = 0; n < 4; ++n) {
        int col = bn + wc * 64 + n * 16 + c0;
        if (col < N) {
            float bv = bias ? bias[col] : 0.f;
            #pragma unroll
            for (int m = 0; m < 4; ++m) {
                #pragma unroll
                for (int r = 0; r < 4; ++r) {
                    int row = bm + wr * 64 + m * 16 + r0 + r;
                    float v = acc[m][n][r] + bv;
                    if (RES) v += res[(size_t)row * N + col];
                    if (ACT == 1) v = gelu_exact(v);
                    C[(size_t)row * N + col] = v;
                }
            }
        }
    }
}

// ---- Split-bf16 MFMA GEMM, K-SPLIT PARTIAL (dense) ----
__global__ __launch_bounds__(256) void mfma_gemm_sp_part(const float* __restrict__ A,
                                                         const float* __restrict__ B,
                                                         float* __restrict__ part,
                                                         int M, int N, int K, int KSPLIT) {
    __shared__ __align__(16) unsigned short Ah[MB * LDT];
    __shared__ __align__(16) unsigned short Al[MB * LDT];
    __shared__ __align__(16) unsigned short Bh[NB * LDT];
    __shared__ __align__(16) unsigned short Bl[NB * LDT];
    int tid = threadIdx.x;
    int bm = blockIdx.y * MB, bn = blockIdx.x * NB;
    int kc = blockIdx.z;
    int chunk = K / KSPLIT;
    int kbeg = kc * chunk;
    int srow = tid >> 1, shalf = tid & 1;
    int lane = tid & 63, w = tid >> 6;
    int wr = w >> 1, wc = w & 1;
    int r0 = (lane >> 4) * 4, c0 = lane & 15;
    int kb = (lane >> 4) * 8;

    f32x4 acc[4][4] = {};

    for (int kk = kbeg; kk < kbeg + chunk; kk += KB) {
        stage_tile_split(Ah, Al, A + (size_t)(bm + srow) * K + kk + shalf * 16, true, srow, shalf);
        stage_tile_split(Bh, Bl, B + (size_t)(bn + srow) * K + kk + shalf * 16, true, srow, shalf);
        __syncthreads();
        bf16x8 ah[4], al[4], bh[4], bl[4];
        #pragma unroll
        for (int m = 0; m < 4; ++m) {
            int o = (wr * 64 + m * 16 + c0) * LDT + kb;
            ah[m] = *reinterpret_cast<const bf16x8*>(&Ah[o]);
            al[m] = *reinterpret_cast<const bf16x8*>(&Al[o]);
        }
        #pragma unroll
        for (int n = 0; n < 4; ++n) {
            int o = (wc * 64 + n * 16 + c0) * LDT + kb;
            bh[n] = *reinterpret_cast<const bf16x8*>(&Bh[o]);
            bl[n] = *reinterpret_cast<const bf16x8*>(&Bl[o]);
        }
        #pragma unroll
        for (int m = 0; m < 4; ++m)
            #pragma unroll
            for (int n = 0; n < 4; ++n) {
                acc[m][n] = __builtin_amdgcn_mfma_f32_16x16x32_bf16(al[m], bh[n], acc[m][n], 0, 0, 0);
                acc[m][n] = __builtin_amdgcn_mfma_f32_16x16x32_bf16(ah[m], bl[n], acc[m][n], 0, 0, 0);
                acc[m][n] = __builtin_amdgcn_mfma_f32_16x16x32_bf16(ah[m], bh[n], acc[m][n], 0, 0, 0);
            }
        __syncthreads();
    }

    float* P = part + (size_t)kc * M * N;
    #pragma unroll
    for (int n = 0; n < 4; ++n) {
        int col = bn + wc * 64 + n * 16 + c0;
        #pragma unroll
        for (int m = 0; m < 4; ++m)
            #pragma unroll
            for (int r = 0; r < 4; ++r) {
                int row = bm + wr * 64 + m * 16 + r0 + r;
                P[(size_t)row * N + col] = acc[m][n][r];
            }
    }
}

// ---- Dense reduce: C = act(Σ parts + bias [+ res]) ----
template<int ACT, int RES>
__global__ __launch_bounds__(256) void reduce_dense(const float* __restrict__ part,
                                                    const float* __restrict__ bias,
                                                    const float* __restrict__ res,
                                                    float* __restrict__ C,
                                                    long MN, int N, int KSPLIT) {
    long stride = (long)gridDim.x * 256 * 4;
    for (long i = ((long)blockIdx.x * 256 + threadIdx.x) * 4; i < MN; i += stride) {
        float4 v = *reinterpret_cast<const float4*>(part + i);
        for (int kc = 1; kc < KSPLIT; ++kc) {
            float4 p = *reinterpret_cast<const float4*>(part + (size_t)kc * MN + i);
            v.x += p.x; v.y += p.y; v.z += p.z; v.w += p.w;
        }
        int col = (int)(i % N);
        float4 b = *reinterpret_cast<const float4*>(bias + col);
        v.x += b.x; v.y += b.y; v.z += b.z; v.w += b.w;
        if (RES) {
            float4 r = *reinterpret_cast<const float4*>(res + i);
            v.x += r.x; v.y += r.y; v.z += r.z; v.w += r.w;
        }
        if (ACT == 1) {
            v.x = gelu_exact(v.x); v.y = gelu_exact(v.y);
            v.z = gelu_exact(v.z); v.w = gelu_exact(v.w);
        }
        *reinterpret_cast<float4*>(C + i) = v;
    }
}

// ---------------- Flash attention, split-bf16 MFMA, 2 barriers/tile ----------------
#define LDA 72
__device__ __forceinline__ void stage16a(unsigned short* dh, unsigned short* dl,
                                         const float* src) {
    union { unsigned short s[8]; uint4 v; } h0, h1, l0, l1;
    const float4* s4 = reinterpret_cast<const float4*>(src);
    #pragma unroll
    for (int q = 0; q < 4; ++q) {
        float4 f = s4[q];
        float vv[4] = {f.x, f.y, f.z, f.w};
        #pragma unroll
        for (int j = 0; j < 4; ++j) {
            int idx = q * 4 + j;
            unsigned short hb = f2bf(vv[j]);
            unsigned short lb = f2bf(vv[j] - bf2f_bits(hb));
            if (idx < 8) { h0.s[idx] = hb; l0.s[idx] = lb; }
            else         { h1.s[idx - 8] = hb; l1.s[idx - 8] = lb; }
        }
    }
    reinterpret_cast<uint4*>(dh)[0] = h0.v; reinterpret_cast<uint4*>(dh)[1] = h1.v;
    reinterpret_cast<uint4*>(dl)[0] = l0.v; reinterpret_cast<uint4*>(dl)[1] = l1.v;
}

__global__ __launch_bounds__(256) void attn_flash(const float* __restrict__ qkv,
                                                  float* __restrict__ o_out) {
    int qt = blockIdx.x;
    int bh = blockIdx.y;
    int b = bh / NHm, hh = bh % NHm;
    const int g0 = b * Tm;
    const int hoff = hh * 64;
    int tid = threadIdx.x;
    int lane = tid & 63, w = tid >> 6;
    int c0 = lane & 15, hi4 = lane >> 4;
    int kb = hi4 * 8;

    __shared__ __align__(16) unsigned short Qh[64 * LDA], Ql[64 * LDA];
    __shared__ __align__(16) unsigned short Kh[64 * LDA], Kl[64 * LDA];
    __shared__ __align__(16) unsigned short Vh[64 * LDA], Vl[64 * LDA];
    __shared__ __align__(16) unsigned short Ph[4][16 * LDA], Pl[4][16 * LDA];

    // Stage Q tile (64 rows x 64 d) once
    {
        int srow = tid >> 2, q = tid & 3;
        stage16a(&Qh[srow * LDA + q * 16], &Ql[srow * LDA + q * 16],
                 qkv + (size_t)(g0 + qt * 64 + srow) * (3 * Dm) + hoff + q * 16);
    }
    __syncthreads();

    f32x4 acc_o[4] = {};
    float m_r[4] = {-1e30f, -1e30f, -1e30f, -1e30f};
    float l_r[4] = {0.f, 0.f, 0.f, 0.f};

    for (int kt = 0; kt <= qt; ++kt) {
        // stage K tile (row-major) AND V^T tile (d-major) together
        {
            int srow = tid >> 2, q = tid & 3;
            stage16a(&Kh[srow * LDA + q * 16], &Kl[srow * LDA + q * 16],
                     qkv + (size_t)(g0 + kt * 64 + srow) * (3 * Dm) + Dm + hoff + q * 16);
        }
        {
            int d = lane, kg = w;
            const float* vbase = qkv + (size_t)(g0 + kt * 64 + kg * 16) * (3 * Dm) + 2 * Dm + hoff + d;
            #pragma unroll
            for (int k2 = 0; k2 < 16; ++k2) {
                float v = vbase[(size_t)k2 * (3 * Dm)];
                unsigned short hb = f2bf(v);
                Vh[d * LDA + kg * 16 + k2] = hb;
                Vl[d * LDA + kg * 16 + k2] = f2bf(v - bf2f_bits(hb));
            }
        }
        __syncthreads();

        // S = Q·K^T (split-bf16)
        f32x4 sAcc[4] = {};
        #pragma unroll
        for (int kk2 = 0; kk2 < 64; kk2 += 32) {
            bf16x8 ah = *reinterpret_cast<const bf16x8*>(&Qh[(w * 16 + c0) * LDA + kk2 + kb]);
            bf16x8 al = *reinterpret_cast<const bf16x8*>(&Ql[(w * 16 + c0) * LDA + kk2 + kb]);
            #pragma unroll
            for (int n = 0; n < 4; ++n) {
                bf16x8 bh_ = *reinterpret_cast<const bf16x8*>(&Kh[(n * 16 + c0) * LDA + kk2 + kb]);
                bf16x8 bl_ = *reinterpret_cast<const bf16x8*>(&Kl[(n * 16 + c0) * LDA + kk2 + kb]);
                sAcc[n] = __builtin_amdgcn_mfma_f32_16x16x32_bf16(al, bh_, sAcc[n], 0, 0, 0);
                sAcc[n] = __builtin_amdgcn_mfma_f32_16x16x32_bf16(ah, bl_, sAcc[n], 0, 0, 0);
                sAcc[n] = __builtin_amdgcn_mfma_f32_16x16x32_bf16(ah, bh_, sAcc[n], 0, 0, 0);
            }
        }

        // scale + causal mask + online softmax
        float p[4][4];
        float smax[4] = {-3e38f, -3e38f, -3e38f, -3e38f};
        #pragma unroll
        for (int n = 0; n < 4; ++n)
            #pragma unroll
            for (int r = 0; r < 4; ++r) {
                float s = sAcc[n][r] * 0.125f;
                if (kt == qt) {
                    int kg = n * 16 + c0;
                    int qg = w * 16 + hi4 * 4 + r;
                    if (kg > qg) s = -3e38f;
                }
                p[n][r] = s;
                smax[r] = fmaxf(smax[r], s);
            }
        #pragma unroll
        for (int off = 1; off < 16; off <<= 1)
            #pragma unroll
            for (int r = 0; r < 4; ++r)
                smax[r] = fmaxf(smax[r], __shfl_xor(smax[r], off));
        float f_r[4], lsum[4];
        #pragma unroll
        for (int r = 0; r < 4; ++r) {
            float mn = fmaxf(m_r[r], smax[r]);
            f_r[r] = expf(m_r[r] - mn);
            m_r[r] = mn;
        }
        #pragma unroll
        for (int n = 0; n < 4; ++n)
            #pragma unroll
            for (int r = 0; r < 4; ++r)
                p[n][r] = expf(p[n][r] - m_r[r]);
        #pragma unroll
        for (int r = 0; r < 4; ++r)
            lsum[r] = p[0][r] + p[1][r] + p[2][r] + p[3][r];
        #pragma unroll
        for (int off = 1; off < 16; off <<= 1)
            #pragma unroll
            for (int r = 0; r < 4; ++r)
                lsum[r] += __shfl_xor(lsum[r], off);
        #pragma unroll
        for (int r = 0; r < 4; ++r)
            l_r[r] = l_r[r] * f_r[r] + lsum[r];
        #pragma unroll
        for (int n = 0; n < 4; ++n)
            #pragma unroll
            for (int r = 0; r < 4; ++r)
                acc_o[n][r] *= f_r[r];

        // write P (hi/lo) to WAVE-PRIVATE LDS (no barrier needed: same-wave
        // ds_write -> ds_read ordering is enforced by lgkmcnt)
        #pragma unroll
        for (int n = 0; n < 4; ++n)
            #pragma unroll
            for (int r = 0; r < 4; ++r) {
                unsigned short hb = f2bf(p[n][r]);
                int o = (hi4 * 4 + r) * LDA + n * 16 + c0;
                Ph[w][o] = hb;
                Pl[w][o] = f2bf(p[n][r] - bf2f_bits(hb));
            }

        // O += P·V (split-bf16)
        #pragma unroll
        for (int kk2 = 0; kk2 < 64; kk2 += 32) {
            bf16x8 pah = *reinterpret_cast<const bf16x8*>(&Ph[w][c0 * LDA + kk2 + kb]);
            bf16x8 pal = *reinterpret_cast<const bf16x8*>(&Pl[w][c0 * LDA + kk2 + kb]);
            #pragma unroll
            for (int n = 0; n < 4; ++n) {
                bf16x8 vbh = *reinterpret_cast<const bf16x8*>(&Vh[(n * 16 + c0) * LDA + kk2 + kb]);
                bf16x8 vbl = *reinterpret_cast<const bf16x8*>(&Vl[(n * 16 + c0) * LDA + kk2 + kb]);
                acc_o[n] = __builtin_amdgcn_mfma_f32_16x16x32_bf16(pal, vbh, acc_o[n], 0, 0, 0);
                acc_o[n] = __builtin_amdgcn_mfma_f32_16x16x32_bf16(pah, vbl, acc_o[n], 0, 0, 0);
                acc_o[n] = __builtin_amdgcn_mfma_f32_16x16x32_bf16(pah, vbh, acc_o[n], 0, 0, 0);
            }
        }
        __syncthreads();   // K/V overwritten next iteration
    }

    float inv[4];
    #pragma unroll
    for (int r = 0; r < 4; ++r) inv[r] = 1.0f / l_r[r];
    #pragma unroll
    for (int n = 0; n < 4; ++n)
        #pragma unroll
        for (int r = 0; r < 4; ++r) {
            int row = g0 + qt * 64 + w * 16 + hi4 * 4 + r;
            o_out[(size_t)row * Dm + hoff + n * 16 + c0] = acc_o[n][r] * inv[r];
        }
}

// ---------------- MoE router (fp32 exact) ----------------
__global__ __launch_bounds__(256) void router_kernel(const float* __restrict__ xn,
                                                     const float* __restrict__ gw,
                                                     int* __restrict__ topi,
                                                     float* __restrict__ topw) {
    int t = blockIdx.x * 256 + threadIdx.x;
    if (t >= NT) return;
    const float* x = xn + (size_t)t * Dm;
    float l[Em];
    #pragma unroll
    for (int e = 0; e < Em; ++e) {
        const float* w = gw + (size_t)e * Dm;
        float dot = 0.f;
        for (int d = 0; d < Dm; ++d) dot += w[d] * x[d];
        l[e] = dot;
    }
    int i1 = 0;
    #pragma unroll
    for (int e = 1; e < Em; ++e) if (l[e] > l[i1]) i1 = e;
    int i2 = (i1 == 0) ? 1 : 0;
    #pragma unroll
    for (int e = 0; e < Em; ++e) if (e != i1 && l[e] > l[i2]) i2 = e;
    float w1 = 1.0f / (1.0f + expf(l[i2] - l[i1]));
    topi[t * 2] = i1; topi[t * 2 + 1] = i2;
    topw[t * 2] = w1; topw[t * 2 + 1] = 1.0f - w1;
}

// ---------------- Route build ----------------
__global__ __launch_bounds__(256) void route_build_kernel(const int* __restrict__ topi,
                                                          int* __restrict__ g_cnt,
                                                          int* __restrict__ g_off,
                                                          int* __restrict__ bucket) {
    __shared__ int cnt[Em], off[Em], pos[Em];
    int tid = threadIdx.x;
    if (tid < Em) cnt[tid] = 0;
    __syncthreads();
    for (int ts = tid; ts < NAS; ts += 256) atomicAdd(&cnt[topi[ts]], 1);
    __syncthreads();
    if (tid == 0) {
        int acc = 0;
        for (int e = 0; e < Em; ++e) { off[e] = acc; pos[e] = acc; acc += cnt[e]; }
    }
    __syncthreads();
    for (int ts = tid; ts < NAS; ts += 256) {
        int e = topi[ts];
        int p = atomicAdd(&pos[e], 1);
        bucket[p] = ts;
    }
    if (tid < Em) { g_cnt[tid] = cnt[tid]; g_off[tid] = off[tid]; }
}

// ---------------- Grouped MoE GEMM1 (MFMA), SPLIT template ----------------
template<int SPLIT>
__global__ __launch_bounds__(256) void moe_mfma_gemm1(const float* __restrict__ xn,
                                                      const float* __restrict__ W1all,
                                                      const float* __restrict__ B1all,
                                                      const int* __restrict__ bucket,
                                                      const int* __restrict__ cnt,
                                                      const int* __restrict__ off,
                                                      float* __restrict__ heg) {
    int e = blockIdx.z;
    int count = cnt[e];
    int mbase = blockIdx.y * MB;
    if (mbase >= count) return;
    int base = off[e];

    __shared__ __align__(16) unsigned short Ah[MB * LDT];
    __shared__ __align__(16) unsigned short Bh[NB * LDT];
    __shared__ __align__(16) unsigned short Al[SPLIT ? MB * LDT : 8];
    __shared__ __align__(16) unsigned short Bl[SPLIT ? NB * LDT : 8];
    __shared__ int toks[MB];
    int tid = threadIdx.x;
    int bn = blockIdx.x * NB;
    int srow = tid >> 1, shalf = tid & 1;
    int lane = tid & 63, w = tid >> 6;
    int wr = w >> 1, wc = w & 1;
    int r0 = (lane >> 4) * 4, c0 = lane & 15;
    int kb = (lane >> 4) * 8;
    if (tid < MB) {
        int p = mbase + tid;
        toks[tid] = (p < count) ? (bucket[base + p] >> 1) : -1;
    }
    __syncthreads();

    f32x4 acc[4][4] = {};
    const float* W = W1all + (size_t)e * Hm * Dm;
    int t = toks[srow];
    for (int kk = 0; kk < Dm; kk += KB) {
        if (SPLIT) {
            stage_tile_split(Ah, Al, xn + (size_t)t * Dm + kk + shalf * 16, t >= 0, srow, shalf);
            stage_tile_split(Bh, Bl, W + (size_t)(bn + srow) * Dm + kk + shalf * 16, true, srow, shalf);
        } else {
            stage_tile(Ah, xn + (size_t)t * Dm + kk + shalf * 16, t >= 0, srow, shalf);
            stage_tile(Bh, W + (size_t)(bn + srow) * Dm + kk + shalf * 16, true, srow, shalf);
        }
        __syncthreads();
        bf16x8 ah[4], bh[4], al[4], bl[4];
        #pragma unroll
        for (int m = 0; m < 4; ++m) {
            int o = (wr * 64 + m * 16 + c0) * LDT + kb;
            ah[m] = *reinterpret_cast<const bf16x8*>(&Ah[o]);
            if (SPLIT) al[m] = *reinterpret_cast<const bf16x8*>(&Al[o]);
        }
        #pragma unroll
        for (int n = 0; n < 4; ++n) {
            int o = (wc * 64 + n * 16 + c0) * LDT + kb;
            bh[n] = *reinterpret_cast<const bf16x8*>(&Bh[o]);
            if (SPLIT) bl[n] = *reinterpret_cast<const bf16x8*>(&Bl[o]);
        }
        #pragma unroll
        for (int m = 0; m < 4; ++m)
            #pragma unroll
            for (int n = 0; n < 4; ++n) {
                if (SPLIT) {
                    acc[m][n] = __builtin_amdgcn_mfma_f32_16x16x32_bf16(al[m], bh[n], acc[m][n], 0, 0, 0);
                    acc[m][n] = __builtin_amdgcn_mfma_f32_16x16x32_bf16(ah[m], bl[n], acc[m][n], 0, 0, 0);
                }
                acc[m][n] = __builtin_amdgcn_mfma_f32_16x16x32_bf16(ah[m], bh[n], acc[m][n], 0, 0, 0);
            }
        __syncthreads();
    }

    const float* b1 = B1all + (size_t)e * Hm;
    #pragma unroll
    for (int n = 0; n < 4; ++n) {
        int col = bn + wc * 64 + n * 16 + c0;
        float bv = b1[col];
        #pragma unroll
        for (int m = 0; m < 4; ++m) {
            #pragma unroll
            for (int r = 0; r < 4; ++r) {
                int p = mbase + wr * 64 + m * 16 + r0 + r;
                if (p < count)
                    heg[(size_t)(base + p) * Hm + col] = gelu_exact(acc[m][n][r] + bv);
            }
        }
    }
}

// ---------------- Grouped MoE GEMM2, K-SPLIT PARTIAL ----------------
template<int SPLIT>
__global__ __launch_bounds__(256) void moe_gemm2_part(const float* __restrict__ heg,
                                                      const float* __restrict__ W2all,
                                                      const int* __restrict__ cnt,
                                                      const int* __restrict__ off,
                                                      float* __restrict__ part,
                                                      int KSPLIT) {
    int e = blockIdx.z;
    int count = cnt[e];
    int my = blockIdx.y;
    int kc = my % KSPLIT, mb = my / KSPLIT;
    int mbase = mb * MB;
    if (mbase >= count) return;
    int base = off[e];
    int chunk = Hm / KSPLIT;
    int kbeg = kc * chunk;

    __shared__ __align__(16) unsigned short Ah[MB * LDT];
    __shared__ __align__(16) unsigned short Bh[NB * LDT];
    __shared__ __align__(16) unsigned short Al[SPLIT ? MB * LDT : 8];
    __shared__ __align__(16) unsigned short Bl[SPLIT ? NB * LDT : 8];
    int tid = threadIdx.x;
    int bn = blockIdx.x * NB;
    int srow = tid >> 1, shalf = tid & 1;
    int lane = tid & 63, w = tid >> 6;
    int wr = w >> 1, wc = w & 1;
    int r0 = (lane >> 4) * 4, c0 = lane & 15;
    int kb = (lane >> 4) * 8;

    f32x4 acc[4][4] = {};
    const float* W = W2all + (size_t)e * Dm * Hm;
    bool aval = (mbase + srow) < count;
    for (int kk = kbeg; kk < kbeg + chunk; kk += KB) {
        if (SPLIT) {
            stage_tile_split(Ah, Al, heg + (size_t)(base + mbase + srow) * Hm + kk + shalf * 16, aval, srow, shalf);
            stage_tile_split(Bh, Bl, W + (size_t)(bn + srow) * Hm + kk + shalf * 16, true, srow, shalf);
        } else {
            stage_tile(Ah, heg + (size_t)(base + mbase + srow) * Hm + kk + shalf * 16, aval, srow, shalf);
            stage_tile(Bh, W + (size_t)(bn + srow) * Hm + kk + shalf * 16, true, srow, shalf);
        }
        __syncthreads();
        bf16x8 ah[4], bh[4], al[4], bl[4];
        #pragma unroll
        for (int m = 0; m < 4; ++m) {
            int o = (wr * 64 + m * 16 + c0) * LDT + kb;
            ah[m] = *reinterpret_cast<const bf16x8*>(&Ah[o]);
            if (SPLIT) al[m] = *reinterpret_cast<const bf16x8*>(&Al[o]);
        }
        #pragma unroll
        for (int n = 0; n < 4; ++n) {
            int o = (wc * 64 + n * 16 + c0) * LDT + kb;
            bh[n] = *reinterpret_cast<const bf16x8*>(&Bh[o]);
            if (SPLIT) bl[n] = *reinterpret_cast<const bf16x8*>(&Bl[o]);
        }
        #pragma unroll
        for (int m = 0; m < 4; ++m)
            #pragma unroll
            for (int n = 0; n < 4; ++n) {
                if (SPLIT) {
                    acc[m][n] = __builtin_amdgcn_mfma_f32_16x16x32_bf16(al[m], bh[n], acc[m][n], 0, 0, 0);
                    acc[m][n] = __builtin_amdgcn_mfma_f32_16x16x32_bf16(ah[m], bl[n], acc[m][n], 0, 0, 0);
                }
                acc[m][n] = __builtin_amdgcn_mfma_f32_16x16x32_bf16(ah[m], bh[n], acc[m][n], 0, 0, 0);
            }
        __syncthreads();
    }

    float* P = part + (size_t)kc * NAS * Dm;
    #pragma unroll
    for (int n = 0; n < 4; ++n) {
        int col = bn + wc * 64 + n * 16 + c0;
        #pragma unroll
        for (int m = 0; m < 4; ++m) {
            #pragma unroll
            for (int r = 0; r < 4; ++r) {
                int p = mbase + wr * 64 + m * 16 + r0 + r;
                if (p < count)
                    P[(size_t)(base + p) * Dm + col] = acc[m][n][r];
            }
        }
    }
}

// ---- MoE reduce: ye[ts] = topw[ts] * (Σ parts + b2[e]) ----
__global__ __launch_bounds__(256) void moe_reduce(const float* __restrict__ part,
                                                  const float* __restrict__ B2all,
                                                  const int* __restrict__ bucket,
                                                  const int* __restrict__ topi,
                                                  const float* __restrict__ topw,
                                                  float* __restrict__ ye, int KSPLIT) {
    const long MN = (long)NAS * Dm;
    long stride = (long)gridDim.x * 256 * 4;
    for (long i = ((long)blockIdx.x * 256 + threadIdx.x) * 4; i < MN; i += stride) {
        int p = (int)(i / Dm), col = (int)(i % Dm);
        int ts = bucket[p];
        int e = topi[ts];
        float wgt = topw[ts];
        float4 v = *reinterpret_cast<const float4*>(part + i);
        for (int kc = 1; kc < KSPLIT; ++kc) {
            float4 q = *reinterpret_cast<const float4*>(part + (size_t)kc * MN + i);
            v.x += q.x; v.y += q.y; v.z += q.z; v.w += q.w;
        }
        float4 b = *reinterpret_cast<const float4*>(B2all + (size_t)e * Dm + col);
        float4 o;
        o.x = wgt * (v.x + b.x); o.y = wgt * (v.y + b.y);
        o.z = wgt * (v.z + b.z); o.w = wgt * (v.w + b.w);
        *reinterpret_cast<float4*>(ye + (size_t)ts * Dm + col) = o;
    }
}

__global__ __launch_bounds__(256) void combine_kernel(float* __restrict__ h,
                                                      const float* __restrict__ ye) {
    int i = blockIdx.x * 256 + threadIdx.x;
    if (i < NT * Dm) {
        int t = i / Dm, d = i - t * Dm;
        h[i] += ye[(size_t)(t * 2) * Dm + d] + ye[(size_t)(t * 2 + 1) * Dm + d];
    }
}

// ---------------- Launch ----------------
extern "C" void kernel_launch(void* const* d_in, const int* in_sizes, int n_in,
                              void* d_out, int out_size, void* d_ws, size_t ws_size,
                              hipStream_t stream) {
    const int*   x    = (const int*)d_in[0];
    const float* emb  = (const float*)d_in[1];
    const float* wqkv = (const float*)d_in[2];
    const float* bqkv = (const float*)d_in[3];
    const float* wo   = (const float*)d_in[4];
    const float* bo   = (const float*)d_in[5];
    const float* ln1g = (const float*)d_in[6];
    const float* ln1b = (const float*)d_in[7];
    const float* ln2g = (const float*)d_in[8];
    const float* ln2b = (const float*)d_in[9];
    const float* sw1  = (const float*)d_in[10];
    const float* sb1  = (const float*)d_in[11];
    const float* sw2  = (const float*)d_in[12];
    const float* sb2  = (const float*)d_in[13];
    const float* gw   = (const float*)d_in[14];
    const float* mw1  = (const float*)d_in[15];
    const float* mb1  = (const float*)d_in[16];
    const float* mw2  = (const float*)d_in[17];
    const float* mb2  = (const float*)d_in[18];
    const float* lnfg = (const float*)d_in[19];
    const float* lnfb = (const float*)d_in[20];

    const size_t n_h    = (size_t)NT * Dm;
    const size_t n_qkv  = (size_t)NT * 3 * Dm;
    const size_t n_ffh  = (size_t)NT * Hm;
    const size_t n_ye   = (size_t)NAS * Dm;
    const size_t n_heg  = (size_t)NAS * Hm;
    const size_t n_xn   = (size_t)NT * Dm;
    const size_t n_part = (size_t)NT * Hm * 2;
    const size_t n_embbf = (size_t)Vm * Dm / 2;
    const size_t n_xnbf  = (size_t)NT * Dm / 2;
    const size_t n_big   = n_h + n_qkv + n_h + n_ffh + n_ye + n_heg + n_part;

    size_t wsf = ws_size / sizeof(float);

    float* w = (float*)d_ws;
    float* xn   = w;            w += n_xn;
    float* topw = w;            w += NAS;
    int*   topi = (int*)w;      w += NAS;
    int*   bucket = (int*)w;    w += NAS;
    int*   e_cnt = (int*)w;     w += 8;
    int*   e_off = (int*)w;     w += 8;
    size_t used = (size_t)(w - (float*)d_ws);

    unsigned short* emb_bf = nullptr;
    unsigned short* xn_bf  = nullptr;
    if (wsf >= used + n_embbf + n_xnbf + 64) {
        emb_bf = (unsigned short*)w;  w += n_embbf;
        xn_bf  = (unsigned short*)w;  w += n_xnbf;
        used = (size_t)(w - (float*)d_ws);
    }

    float *h, *qkv, *attno, *ffh, *ye, *heg, *part;
    if (wsf >= used + n_big + 64) {
        float* a = w;
        h = a;      a += n_h;
        qkv = a;    a += n_qkv;
        attno = a;  a += n_h;
        ffh = a;    a += n_ffh;
        ye = a;     a += n_ye;
        heg = a;    a += n_heg;
        part = a;
    } else {
        float* a = (float*)d_out;
        h = a;      a += n_h;
        qkv = a;    a += n_qkv;
        attno = a;  a += n_h;
        ffh = a;    a += n_ffh;
        ye = a;     a += n_ye;
        heg = a;    a += n_heg;
        part = a;
    }

    if (emb_bf) {
        long n = (long)Vm * Dm;
        cvt_bf16_kernel<<<(unsigned)((n / 8 + 255) / 256), 256, 0, stream>>>(emb, emb_bf, n);
    }

    embed_kernel<<<NT, 256, 0, stream>>>(x, emb, h);

    const int RBLK = 2048;
    int std_i = 0, moe_i = 0;
    for (int l = 0; l < Lm; ++l) {
        ln_kernel<<<NT, 256, 0, stream>>>(h, ln1g + l * Dm, ln1b + l * Dm, xn);
        mfma_gemm_sp_part<<<dim3((3 * Dm) / NB, NT / MB, 2), 256, 0, stream>>>(
            xn, wqkv + (size_t)l * 3 * Dm * Dm, part, NT, 3 * Dm, Dm, 2);
        reduce_dense<0,0><<<RBLK, 256, 0, stream>>>(
            part, bqkv + (size_t)l * 3 * Dm, nullptr, qkv, (long)NT * 3 * Dm, 3 * Dm, 2);
        attn_flash<<<dim3(Tm / 64, Bm * NHm), 256, 0, stream>>>(qkv, attno);
        mfma_gemm_sp_part<<<dim3(Dm / NB, NT / MB, 4), 256, 0, stream>>>(
            attno, wo + (size_t)l * Dm * Dm, part, NT, Dm, Dm, 4);
        reduce_dense<0,1><<<RBLK, 256, 0, stream>>>(
            part, bo + (size_t)l * Dm, h, h, (long)NT * Dm, Dm, 4);

        ln_kernel<<<NT, 256, 0, stream>>>(h, ln2g + l * Dm, ln2b + l * Dm, xn);
        if (l == 1 || l == 3) {
            router_kernel<<<(NT + 255) / 256, 256, 0, stream>>>(
                xn, gw + (size_t)moe_i * Em * Dm, topi, topw);
            route_build_kernel<<<1, 256, 0, stream>>>(topi, e_cnt, e_off, bucket);
            if (l == 3) {
                moe_mfma_gemm1<0><<<dim3(Hm / NB, NAS / MB, Em), 256, 0, stream>>>(
                    xn, mw1 + (size_t)moe_i * Em * Hm * Dm, mb1 + (size_t)moe_i * Em * Hm,
                    bucket, e_cnt, e_off, heg);
                moe_gemm2_part<0><<<dim3(Dm / NB, (NAS / MB) * 4, Em), 256, 0, stream>>>(
                    heg, mw2 + (size_t)moe_i * Em * Dm * Hm, e_cnt, e_off, part, 4);
            } else {
                moe_mfma_gemm1<1><<<dim3(Hm / NB, NAS / MB, Em), 256, 0, stream>>>(
                    xn, mw1 + (size_t)moe_i * Em * Hm * Dm, mb1 + (size_t)moe_i * Em * Hm,
                    bucket, e_cnt, e_off, heg);
                moe_gemm2_part<1><<<dim3(Dm / NB, (NAS / MB) * 4, Em), 256, 0, stream>>>(
                    heg, mw2 + (size_t)moe_i * Em * Dm * Hm, e_cnt, e_off, part, 4);
            }
            moe_reduce<<<RBLK, 256, 0, stream>>>(
                part, mb2 + (size_t)moe_i * Em * Dm, bucket, topi, topw, ye, 4);
            combine_kernel<<<(NT * Dm) / 256, 256, 0, stream>>>(h, ye);
            moe_i++;
        } else {
            mfma_gemm_sp_part<<<dim3(Hm / NB, NT / MB, 2), 256, 0, stream>>>(
                xn, sw1 + (size_t)std_i * Hm * Dm, part, NT, Hm, Dm, 2);
            reduce_dense<1,0><<<RBLK, 256, 0, stream>>>(
                part, sb1 + (size_t)std_i * Hm, nullptr, ffh, (long)NT * Hm, Hm, 2);
            mfma_gemm_sp_part<<<dim3(Dm / NB, NT / MB, 8), 256, 0, stream>>>(
                ffh, sw2 + (size_t)std_i * Dm * Hm, part, NT, Dm, Hm, 8);
            reduce_dense<0,1><<<RBLK, 256, 0, stream>>>(
                part, sb2 + (size_t)std_i * Dm, h, h, (long)NT * Dm, Dm, 8);
            std_i++;
        }
    }

    ln_kernel<<<NT, 256, 0, stream>>>(h, lnfg, lnfb, xn);
    if (emb_bf) {
        long n = (long)NT * Dm;
        cvt_bf16_kernel<<<(unsigned)((n / 8 + 255) / 256), 256, 0, stream>>>(xn, xn_bf, n);
        // grid: x = m-tiles innermost (B-panel L2/L3 reuse across XCDs)
        mfma_gemm_bf<<<dim3(NT / MB, (Vm + NB - 1) / NB), 256, 0, stream>>>(
            xn_bf, emb_bf, nullptr, (float*)d_out, NT, Vm, Dm);
    } else {
        mfma_gemm<0,0><<<dim3((Vm + NB - 1) / NB, NT / MB), 256, 0, stream>>>(
            xn, emb, nullptr, nullptr, (float*)d_out, NT, Vm, Dm);
    }
}